// Round 1
// baseline (1078.738 us; speedup 1.0000x reference)
//
#include <hip/hip_runtime.h>
#include <cstdint>

#define SLOPE 0.33f

static constexpr int B_   = 64;
static constexpr int E1_  = 8978;
static constexpr int E2_  = 4489;
static constexpr int N1_  = B_ * E1_;      // 574592
static constexpr int N2_  = B_ * E2_;      // 287296
static constexpr int DEG_ = 16;
static constexpr int QTR_ = 2245;          // ceil(E1_/4)
static constexpr int MVGRID = (N2_ * 32) / 256;   // 35912 (exact)
static constexpr int NBLK8  = N2_ / 8;            // 35912 (exact)
static constexpr double EPS_ = 1e-5;

__device__ __forceinline__ float lrelu(float v) { return v > 0.f ? v : SLOPE * v; }

// =====================================================================
// Layer 0: 1 channel. Per-graph x slab staged in LDS; edges of node g are
// [g*16, g*16+16) by construction (dst sorted). grid = 64 graphs * 4 quarters.
// =====================================================================
__global__ __launch_bounds__(256) void k0_mv1(const float* __restrict__ x,
    const int* __restrict__ src, const float* __restrict__ ew, float* __restrict__ T1) {
  __shared__ float sx[E1_];
  int g = blockIdx.x >> 2, q = blockIdx.x & 3;
  int gbase = g * E1_;
  for (int j = threadIdx.x; j < E1_; j += 256) sx[j] = x[gbase + j];
  __syncthreads();
  int start = q * QTR_, end = min(start + QTR_, E1_);
  for (int i = start + (int)threadIdx.x; i < end; i += 256) {
    int node = gbase + i;
    const int4* s4 = (const int4*)(src + (size_t)node * DEG_);
    const float4* w4 = (const float4*)(ew + (size_t)node * DEG_);
    float acc = 0.f;
#pragma unroll
    for (int j = 0; j < 4; ++j) {
      int4 s = s4[j]; float4 w = w4[j];
      acc += w.x * sx[s.x - gbase] + w.y * sx[s.y - gbase]
           + w.z * sx[s.z - gbase] + w.w * sx[s.w - gbase];
    }
    T1[node] = sx[i] - acc;   // T1 = x - L x
  }
}

__global__ __launch_bounds__(256) void k0_mv2(const float* __restrict__ x,
    const int* __restrict__ src, const float* __restrict__ ew,
    const float* __restrict__ T1, float* __restrict__ T2) {
  __shared__ float sT[E1_];
  int g = blockIdx.x >> 2, q = blockIdx.x & 3;
  int gbase = g * E1_;
  for (int j = threadIdx.x; j < E1_; j += 256) sT[j] = T1[gbase + j];
  __syncthreads();
  int start = q * QTR_, end = min(start + QTR_, E1_);
  for (int i = start + (int)threadIdx.x; i < end; i += 256) {
    int node = gbase + i;
    const int4* s4 = (const int4*)(src + (size_t)node * DEG_);
    const float4* w4 = (const float4*)(ew + (size_t)node * DEG_);
    float acc = 0.f;
#pragma unroll
    for (int j = 0; j < 4; ++j) {
      int4 s = s4[j]; float4 w = w4[j];
      acc += w.x * sT[s.x - gbase] + w.y * sT[s.y - gbase]
           + w.z * sT[s.z - gbase] + w.w * sT[s.w - gbase];
    }
    T2[node] = (3.f * sT[i] - acc - x[node]) * 0.5f;  // T2 = (3T1 - L T1 - T0)/2
  }
}

// T3 = (5T2 - L T2 - 2T1)/3, plus moment accumulation for layer-0 BN:
// mom[0..3] = sum T_k ; mom[4..13] = sum T_k*T_l upper-tri (00,01,02,03,11,12,13,22,23,33)
__global__ __launch_bounds__(256) void k0_mv3(const float* __restrict__ x,
    const int* __restrict__ src, const float* __restrict__ ew,
    const float* __restrict__ T1, const float* __restrict__ T2,
    float* __restrict__ T3, double* mom) {
  __shared__ float sT[E1_];
  __shared__ double sred[4 * 14];
  int g = blockIdx.x >> 2, q = blockIdx.x & 3;
  int gbase = g * E1_;
  for (int j = threadIdx.x; j < E1_; j += 256) sT[j] = T2[gbase + j];
  __syncthreads();
  double m[14];
#pragma unroll
  for (int j = 0; j < 14; ++j) m[j] = 0.0;
  int start = q * QTR_, end = min(start + QTR_, E1_);
  for (int i = start + (int)threadIdx.x; i < end; i += 256) {
    int node = gbase + i;
    const int4* s4 = (const int4*)(src + (size_t)node * DEG_);
    const float4* w4 = (const float4*)(ew + (size_t)node * DEG_);
    float acc = 0.f;
#pragma unroll
    for (int j = 0; j < 4; ++j) {
      int4 s = s4[j]; float4 w = w4[j];
      acc += w.x * sT[s.x - gbase] + w.y * sT[s.y - gbase]
           + w.z * sT[s.z - gbase] + w.w * sT[s.w - gbase];
    }
    float t1 = T1[node];
    float t2 = sT[i];
    float t3 = (5.f * t2 - acc - 2.f * t1) * (1.f / 3.f);
    T3[node] = t3;
    double d0 = x[node], d1 = t1, d2 = t2, d3 = t3;
    m[0] += d0; m[1] += d1; m[2] += d2; m[3] += d3;
    m[4] += d0 * d0; m[5] += d0 * d1; m[6] += d0 * d2; m[7] += d0 * d3;
    m[8] += d1 * d1; m[9] += d1 * d2; m[10] += d1 * d3;
    m[11] += d2 * d2; m[12] += d2 * d3; m[13] += d3 * d3;
  }
  int lane = threadIdx.x & 63, wid = threadIdx.x >> 6;
#pragma unroll
  for (int j = 0; j < 14; ++j) {
    double v = m[j];
    for (int o = 32; o; o >>= 1) v += __shfl_down(v, o);
    if (lane == 0) sred[wid * 14 + j] = v;
  }
  __syncthreads();
  if (threadIdx.x < 14) {
    double s = sred[threadIdx.x] + sred[14 + threadIdx.x] + sred[28 + threadIdx.x] + sred[42 + threadIdx.x];
    atomicAdd(&mom[threadIdx.x], s);
  }
}

// BN params for layer 0: out_c = dot_c + b0 ; bias cancels in BN exactly.
__global__ void k0_params(const double* __restrict__ mom, const float* __restrict__ W0,
    const float* __restrict__ g0, const float* __restrict__ be0,
    float* __restrict__ scale0, float* __restrict__ shiftE0) {
  int c = threadIdx.x;
  if (c >= 32) return;
  double inv = 1.0 / (double)N1_;
  double mm[4];
#pragma unroll
  for (int k = 0; k < 4; ++k) mm[k] = mom[k] * inv;
  double M[4][4];
  M[0][0] = mom[4] * inv;  M[0][1] = mom[5] * inv;  M[0][2] = mom[6] * inv;  M[0][3] = mom[7] * inv;
  M[1][1] = mom[8] * inv;  M[1][2] = mom[9] * inv;  M[1][3] = mom[10] * inv;
  M[2][2] = mom[11] * inv; M[2][3] = mom[12] * inv; M[3][3] = mom[13] * inv;
  M[1][0] = M[0][1]; M[2][0] = M[0][2]; M[3][0] = M[0][3];
  M[2][1] = M[1][2]; M[3][1] = M[1][3]; M[3][2] = M[2][3];
  double w[4];
#pragma unroll
  for (int k = 0; k < 4; ++k) w[k] = W0[k * 32 + c];
  double mean = 0.0;
#pragma unroll
  for (int k = 0; k < 4; ++k) mean += w[k] * mm[k];
  double e2 = 0.0;
#pragma unroll
  for (int k = 0; k < 4; ++k)
#pragma unroll
    for (int l = 0; l < 4; ++l) e2 += M[k][l] * w[k] * w[l];
  double var = e2 - mean * mean;
  double sc = (double)g0[c] / sqrt(var + EPS_);
  scale0[c] = (float)sc;
  shiftE0[c] = (float)((double)be0[c] - sc * mean);
}

// fused: project to 32ch + BN + LeakyReLU + Graclus pair-max pool -> x1 (N2,32)
__global__ __launch_bounds__(256) void k0_pool(const float* __restrict__ x,
    const float* __restrict__ T1, const float* __restrict__ T2, const float* __restrict__ T3,
    const float* __restrict__ W0, const float* __restrict__ scale0,
    const float* __restrict__ shiftE0, float* __restrict__ x1) {
  int gid = blockIdx.x * 256 + threadIdx.x;
  int grp = gid >> 5, c = gid & 31;
  if (grp >= N2_) return;
  int b = grp / E2_, j = grp - b * E2_;
  int ga = b * E1_ + 2 * j, gb = ga + 1;
  float w0 = W0[c], w1 = W0[32 + c], w2 = W0[64 + c], w3 = W0[96 + c];
  float da = x[ga] * w0 + T1[ga] * w1 + T2[ga] * w2 + T3[ga] * w3;
  float db = x[gb] * w0 + T1[gb] * w1 + T2[gb] * w2 + T3[gb] * w3;
  float sc = scale0[c], sh = shiftE0[c];
  float ya = lrelu(sc * da + sh), yb = lrelu(sc * db + sh);
  x1[grp * 32 + c] = fmaxf(ya, yb);
}

// =====================================================================
// 32-channel matvecs, thread = (node, channel); gathers are 128B row reads.
// =====================================================================
__global__ __launch_bounds__(256) void k_mv_a(const float* __restrict__ X,
    const int* __restrict__ src, const float* __restrict__ ew, float* __restrict__ T1) {
  int gid = blockIdx.x * 256 + threadIdx.x;
  int i = gid >> 5, c = gid & 31;
  if (i >= N2_) return;
  const int4* s4 = (const int4*)(src + (size_t)i * DEG_);
  const float4* w4 = (const float4*)(ew + (size_t)i * DEG_);
  float acc = 0.f;
#pragma unroll
  for (int j = 0; j < 4; ++j) {
    int4 s = s4[j]; float4 w = w4[j];
    acc += w.x * X[s.x * 32 + c] + w.y * X[s.y * 32 + c]
         + w.z * X[s.z * 32 + c] + w.w * X[s.w * 32 + c];
  }
  T1[i * 32 + c] = X[i * 32 + c] - acc;
}

__global__ __launch_bounds__(256) void k_mv_b(const float* __restrict__ X,
    const float* __restrict__ T1, const int* __restrict__ src,
    const float* __restrict__ ew, float* __restrict__ T2) {
  int gid = blockIdx.x * 256 + threadIdx.x;
  int i = gid >> 5, c = gid & 31;
  if (i >= N2_) return;
  const int4* s4 = (const int4*)(src + (size_t)i * DEG_);
  const float4* w4 = (const float4*)(ew + (size_t)i * DEG_);
  float acc = 0.f;
#pragma unroll
  for (int j = 0; j < 4; ++j) {
    int4 s = s4[j]; float4 w = w4[j];
    acc += w.x * T1[s.x * 32 + c] + w.y * T1[s.y * 32 + c]
         + w.z * T1[s.z * 32 + c] + w.w * T1[s.w * 32 + c];
  }
  T2[i * 32 + c] = (3.f * T1[i * 32 + c] - acc - X[i * 32 + c]) * 0.5f;
}

__global__ __launch_bounds__(256) void k_mv_c(const float* __restrict__ T1,
    const float* __restrict__ T2, const int* __restrict__ src,
    const float* __restrict__ ew, float* __restrict__ T3) {
  int gid = blockIdx.x * 256 + threadIdx.x;
  int i = gid >> 5, c = gid & 31;
  if (i >= N2_) return;
  const int4* s4 = (const int4*)(src + (size_t)i * DEG_);
  const float4* w4 = (const float4*)(ew + (size_t)i * DEG_);
  float acc = 0.f;
#pragma unroll
  for (int j = 0; j < 4; ++j) {
    int4 s = s4[j]; float4 w = w4[j];
    acc += w.x * T2[s.x * 32 + c] + w.y * T2[s.y * 32 + c]
         + w.z * T2[s.z * 32 + c] + w.w * T2[s.w * 32 + c];
  }
  T3[i * 32 + c] = (5.f * T2[i * 32 + c] - acc - 2.f * T1[i * 32 + c]) * (1.f / 3.f);
}

// out1 = [x1|T1|T2|T3] @ Wcat(128,32) + b1. Thread per node, Wcat in LDS
// (uniform-address b128 broadcast reads). `out` aliases `Xa` (read-then-write,
// each row touched by exactly one thread) -> no __restrict__ on those two.
__global__ __launch_bounds__(256) void k1_gemm(const float* Xa,
    const float* __restrict__ Xb, const float* __restrict__ Xc, const float* __restrict__ Xd,
    const float* __restrict__ W1, const float* __restrict__ b1, float* out) {
  __shared__ float4 sW[32 * 32];   // [c][q], q over dcat/4
  for (int t = threadIdx.x; t < 4096; t += 256) {
    int c = t >> 7, dcat = t & 127;
    int k = dcat >> 5, d = dcat & 31;
    ((float*)sW)[t] = W1[k * 1024 + d * 32 + c];
  }
  __syncthreads();
  int i = blockIdx.x * 256 + threadIdx.x;
  if (i >= N2_) return;
  int base = i * 32;
  float4 R[32];
  const float4* a4 = (const float4*)(Xa + base);
  const float4* b4 = (const float4*)(Xb + base);
  const float4* c4 = (const float4*)(Xc + base);
  const float4* d4 = (const float4*)(Xd + base);
#pragma unroll
  for (int j = 0; j < 8; ++j) { R[j] = a4[j]; R[8 + j] = b4[j]; R[16 + j] = c4[j]; R[24 + j] = d4[j]; }
  for (int c0 = 0; c0 < 32; c0 += 4) {
    float o[4];
#pragma unroll
    for (int cc = 0; cc < 4; ++cc) {
      int c = c0 + cc;
      float acc = b1[c];
#pragma unroll
      for (int qq = 0; qq < 32; ++qq) {
        float4 w = sW[c * 32 + qq];
        float4 r = R[qq];
        acc += r.x * w.x + r.y * w.y + r.z * w.z + r.w * w.w;
      }
      o[cc] = acc;
    }
    float4 ov = { o[0], o[1], o[2], o[3] };
    *(float4*)(out + base + c0) = ov;
  }
}

// per-channel sum/sumsq of a (N2,32) array (for layer-1 BN)
__global__ __launch_bounds__(256) void k_stats32(const float* __restrict__ X,
    double* sum, double* sq) {
  __shared__ double s1[256], s2[256];
  const long total = (long)N2_ * 32;
  double a = 0.0, b = 0.0;
  for (long idx = (long)blockIdx.x * 256 + threadIdx.x; idx < total; idx += (long)gridDim.x * 256) {
    double v = X[idx]; a += v; b += v * v;
  }
  s1[threadIdx.x] = a; s2[threadIdx.x] = b;
  __syncthreads();
  int c = threadIdx.x;
  if (c < 32) {
    double sa = 0.0, sb = 0.0;
    for (int j = c; j < 256; j += 32) { sa += s1[j]; sb += s2[j]; }
    atomicAdd(&sum[c], sa); atomicAdd(&sq[c], sb);
  }
}

__global__ void k1_params(const double* __restrict__ sum, const double* __restrict__ sq,
    const float* __restrict__ g1, const float* __restrict__ be1,
    float* __restrict__ scale1, float* __restrict__ shiftE1) {
  int c = threadIdx.x;
  if (c >= 32) return;
  double mean = sum[c] / (double)N2_;
  double var = sq[c] / (double)N2_ - mean * mean;
  double sc = (double)g1[c] / sqrt(var + EPS_);
  scale1[c] = (float)sc;
  shiftE1[c] = (float)((double)be1[c] - sc * mean);
}

// layer-2 matvecs: input is f(out1) with f = lrelu(scale1*v + shiftE1), applied on the fly
__global__ __launch_bounds__(256) void k2_mv_a(const float* __restrict__ X,
    const int* __restrict__ src, const float* __restrict__ ew,
    const float* __restrict__ scale1, const float* __restrict__ shiftE1,
    float* __restrict__ T1) {
  int gid = blockIdx.x * 256 + threadIdx.x;
  int i = gid >> 5, c = gid & 31;
  if (i >= N2_) return;
  float sc = scale1[c], sh = shiftE1[c];
  const int4* s4 = (const int4*)(src + (size_t)i * DEG_);
  const float4* w4 = (const float4*)(ew + (size_t)i * DEG_);
  float acc = 0.f;
#pragma unroll
  for (int j = 0; j < 4; ++j) {
    int4 s = s4[j]; float4 w = w4[j];
    acc += w.x * lrelu(sc * X[s.x * 32 + c] + sh) + w.y * lrelu(sc * X[s.y * 32 + c] + sh)
         + w.z * lrelu(sc * X[s.z * 32 + c] + sh) + w.w * lrelu(sc * X[s.w * 32 + c] + sh);
  }
  T1[i * 32 + c] = lrelu(sc * X[i * 32 + c] + sh) - acc;
}

__global__ __launch_bounds__(256) void k2_mv_b(const float* __restrict__ X,
    const float* __restrict__ T1, const int* __restrict__ src, const float* __restrict__ ew,
    const float* __restrict__ scale1, const float* __restrict__ shiftE1,
    float* __restrict__ T2) {
  int gid = blockIdx.x * 256 + threadIdx.x;
  int i = gid >> 5, c = gid & 31;
  if (i >= N2_) return;
  float sc = scale1[c], sh = shiftE1[c];
  const int4* s4 = (const int4*)(src + (size_t)i * DEG_);
  const float4* w4 = (const float4*)(ew + (size_t)i * DEG_);
  float acc = 0.f;
#pragma unroll
  for (int j = 0; j < 4; ++j) {
    int4 s = s4[j]; float4 w = w4[j];
    acc += w.x * T1[s.x * 32 + c] + w.y * T1[s.y * 32 + c]
         + w.z * T1[s.z * 32 + c] + w.w * T1[s.w * 32 + c];
  }
  T2[i * 32 + c] = (3.f * T1[i * 32 + c] - acc - lrelu(sc * X[i * 32 + c] + sh)) * 0.5f;
}

// T3 + projection to 1 channel (reduce over 32 lanes) + global sum/sumsq stats
__global__ __launch_bounds__(256) void k2_mv3out(const float* __restrict__ Xout1,
    const float* __restrict__ T1, const float* __restrict__ T2,
    const int* __restrict__ src, const float* __restrict__ ew,
    const float* __restrict__ W2, const float* __restrict__ b2,
    const float* __restrict__ scale1, const float* __restrict__ shiftE1,
    float* __restrict__ out2, double* st2) {
  __shared__ double sds[8], sss[8];
  int c = threadIdx.x & 31, g = threadIdx.x >> 5;
  float w0 = W2[c], w1 = W2[32 + c], w2c = W2[64 + c], w3 = W2[96 + c];
  float sc = scale1[c], sh = shiftE1[c];
  double accS = 0.0, accQ = 0.0;
  for (int nb = blockIdx.x; nb < NBLK8; nb += gridDim.x) {
    int i = nb * 8 + g;                 // always < N2_ (exact tiling)
    int base = i * 32;
    const int4* s4 = (const int4*)(src + (size_t)i * DEG_);
    const float4* w4 = (const float4*)(ew + (size_t)i * DEG_);
    float acc = 0.f;
#pragma unroll
    for (int j = 0; j < 4; ++j) {
      int4 s = s4[j]; float4 w = w4[j];
      acc += w.x * T2[s.x * 32 + c] + w.y * T2[s.y * 32 + c]
           + w.z * T2[s.z * 32 + c] + w.w * T2[s.w * 32 + c];
    }
    float t1r = T1[base + c], t2r = T2[base + c];
    float xr = lrelu(sc * Xout1[base + c] + sh);
    float t3 = (5.f * t2r - acc - 2.f * t1r) * (1.f / 3.f);
    float contrib = xr * w0 + t1r * w1 + t2r * w2c + t3 * w3;
    for (int o = 16; o; o >>= 1) contrib += __shfl_down(contrib, o, 32);
    if (c == 0) {
      float ov = contrib + b2[0];
      out2[i] = ov;
      accS += ov; accQ += (double)ov * (double)ov;
    }
  }
  if (c == 0) { sds[g] = accS; sss[g] = accQ; }
  __syncthreads();
  if (threadIdx.x == 0) {
    double a = 0.0, b = 0.0;
    for (int j = 0; j < 8; ++j) { a += sds[j]; b += sss[j]; }
    atomicAdd(&st2[0], a); atomicAdd(&st2[1], b);
  }
}

__global__ void k2_params(const double* __restrict__ st2, const float* __restrict__ g2,
    const float* __restrict__ be2, float* __restrict__ p /* [128]=scale2 [129]=shiftE2 */) {
  if (threadIdx.x != 0) return;
  double mean = st2[0] / (double)N2_;
  double var = st2[1] / (double)N2_ - mean * mean;
  double sc = (double)g2[0] / sqrt(var + EPS_);
  p[128] = (float)sc;
  p[129] = (float)((double)be2[0] - sc * mean);
}

// MLP: h1pre[b,c] = sum_r f2(out2[b*E2+r]) * lin1_W[r,c]   (256 blocks: 16 colgroups x 16 rsplits)
__global__ __launch_bounds__(256) void k3_gemm1(const float* __restrict__ out2,
    const float* __restrict__ lin1W, const float* __restrict__ p, float* h1pre) {
  float sc = p[128], sh = p[129];
  int cg = blockIdx.x & 15, rs = blockIdx.x >> 4;
  int c = cg * 16 + (threadIdx.x & 15);
  int bq = threadIdx.x >> 4;          // 0..15 -> 4 batches each
  int b0 = bq * 4;
  int r0 = rs * 281, r1 = min(r0 + 281, E2_);
  float a0 = 0.f, a1 = 0.f, a2 = 0.f, a3 = 0.f;
  for (int r = r0; r < r1; ++r) {
    float w = lin1W[r * 256 + c];
    a0 += lrelu(sc * out2[(b0 + 0) * E2_ + r] + sh) * w;
    a1 += lrelu(sc * out2[(b0 + 1) * E2_ + r] + sh) * w;
    a2 += lrelu(sc * out2[(b0 + 2) * E2_ + r] + sh) * w;
    a3 += lrelu(sc * out2[(b0 + 3) * E2_ + r] + sh) * w;
  }
  atomicAdd(&h1pre[(b0 + 0) * 256 + c], a0);
  atomicAdd(&h1pre[(b0 + 1) * 256 + c], a1);
  atomicAdd(&h1pre[(b0 + 2) * 256 + c], a2);
  atomicAdd(&h1pre[(b0 + 3) * 256 + c], a3);
}

// BN1 (bias cancels) + ReLU -> h1 (64,256). one block, thread = column.
__global__ __launch_bounds__(256) void k4_bn1(const float* __restrict__ h1pre,
    const float* __restrict__ g, const float* __restrict__ be, float* __restrict__ h1) {
  int c = threadIdx.x;
  float vs[64];
  double s = 0.0, q = 0.0;
  for (int b = 0; b < 64; ++b) { float v = h1pre[b * 256 + c]; vs[b] = v; s += v; q += (double)v * v; }
  double mean = s / 64.0, var = q / 64.0 - mean * mean;
  double scd = (double)g[c] / sqrt(var + EPS_);
  double shd = (double)be[c] - scd * mean;
  for (int b = 0; b < 64; ++b) {
    float y = (float)(scd * vs[b] + shd);
    h1[b * 256 + c] = y > 0.f ? y : 0.f;
  }
}

// gemm2: 128 blocks, block = output column
__global__ __launch_bounds__(256) void k5_gemm2(const float* __restrict__ h1,
    const float* __restrict__ lin2W, float* __restrict__ h2pre) {
  __shared__ float sred[256];
  int c = blockIdx.x;
  int b = threadIdx.x & 63, q = threadIdx.x >> 6;
  float acc = 0.f;
  for (int r = q; r < 256; r += 4) acc += h1[b * 256 + r] * lin2W[r * 128 + c];
  sred[threadIdx.x] = acc;
  __syncthreads();
  if (threadIdx.x < 64)
    h2pre[threadIdx.x * 128 + c] = sred[threadIdx.x] + sred[64 + threadIdx.x]
                                 + sred[128 + threadIdx.x] + sred[192 + threadIdx.x];
}

// BN2 + ReLU + final linear -> out[64]
__global__ __launch_bounds__(256) void k6_final(const float* __restrict__ h2pre,
    const float* __restrict__ g, const float* __restrict__ be,
    const float* __restrict__ W3, const float* __restrict__ b3, float* __restrict__ outp) {
  __shared__ float sh2[64 * 129];
  __shared__ float sred[256];
  int tid = threadIdx.x;
  if (tid < 128) {
    int c = tid;
    float vs[64];
    double s = 0.0, q = 0.0;
    for (int b = 0; b < 64; ++b) { float v = h2pre[b * 128 + c]; vs[b] = v; s += v; q += (double)v * v; }
    double mean = s / 64.0, var = q / 64.0 - mean * mean;
    double scd = (double)g[c] / sqrt(var + EPS_);
    double shd = (double)be[c] - scd * mean;
    for (int b = 0; b < 64; ++b) {
      float y = (float)(scd * vs[b] + shd);
      sh2[b * 129 + c] = y > 0.f ? y : 0.f;
    }
  }
  __syncthreads();
  int b = tid & 63, q = tid >> 6;
  float acc = 0.f;
  for (int r = q; r < 128; r += 4) acc += sh2[b * 129 + r] * W3[r];
  sred[tid] = acc;
  __syncthreads();
  if (tid < 64)
    outp[tid] = sred[tid] + sred[64 + tid] + sred[128 + tid] + sred[192 + tid] + b3[0];
}

// =====================================================================
extern "C" void kernel_launch(void* const* d_in, const int* in_sizes, int n_in,
                              void* d_out, int out_size, void* d_ws, size_t ws_size,
                              hipStream_t stream) {
  const float* x    = (const float*)d_in[0];
  const int*   ei1  = (const int*)d_in[1];     // src = ei1[0:NE1]
  const float* ew1  = (const float*)d_in[2];
  const int*   ei2  = (const int*)d_in[3];
  const float* ew2  = (const float*)d_in[4];
  const float* W0   = (const float*)d_in[5];
  // b0 (d_in[6]) cancels through BN exactly — unused
  const float* g0   = (const float*)d_in[7];
  const float* be0  = (const float*)d_in[8];
  const float* W1   = (const float*)d_in[9];
  const float* b1   = (const float*)d_in[10];
  const float* g1   = (const float*)d_in[11];
  const float* be1  = (const float*)d_in[12];
  const float* W2   = (const float*)d_in[13];
  const float* b2   = (const float*)d_in[14];
  const float* g2   = (const float*)d_in[15];
  const float* be2  = (const float*)d_in[16];
  const float* lin1W = (const float*)d_in[17];
  // lin1_b (18) cancels through BN
  const float* bn1g = (const float*)d_in[19];
  const float* bn1b = (const float*)d_in[20];
  const float* lin2W = (const float*)d_in[21];
  // lin2_b (22) cancels through BN
  const float* bn2g = (const float*)d_in[23];
  const float* bn2b = (const float*)d_in[24];
  const float* lin3W = (const float*)d_in[25];
  const float* lin3b = (const float*)d_in[26];

  char* ws = (char*)d_ws;
  double* stats  = (double*)ws;                 // [0..13] mom0, [14..45] s1sum, [46..77] s1sq, [78..79] st2
  float*  params = (float*)(ws + 1024);         // scale0[32] shiftE0[32] scale1[32] shiftE1[32] scale2 shiftE2
  float*  h1pre  = (float*)(ws + 4096);
  float*  h1     = (float*)(ws + 4096 + 65536);
  float*  h2pre  = (float*)(ws + 4096 + 131072);
  float*  big    = (float*)(ws + 262144);
  float* T1_0 = big;
  float* T2_0 = big + N1_;
  float* T3_0 = big + 2 * (size_t)N1_;
  float* bufA = big + 3 * (size_t)N1_;          // x1, later aliased as out1
  float* bufB = bufA + 32 * (size_t)N2_;        // T1
  float* bufC = bufB + 32 * (size_t)N2_;        // T2
  float* bufD = bufC + 32 * (size_t)N2_;        // T3 (layer 1 only)
  float* out2 = bufD + 32 * (size_t)N2_;        // (N2,)

  hipMemsetAsync(stats, 0, 80 * sizeof(double), stream);
  hipMemsetAsync(h1pre, 0, 65536, stream);

  // ---- layer 0 ----
  k0_mv1<<<256, 256, 0, stream>>>(x, ei1, ew1, T1_0);
  k0_mv2<<<256, 256, 0, stream>>>(x, ei1, ew1, T1_0, T2_0);
  k0_mv3<<<256, 256, 0, stream>>>(x, ei1, ew1, T1_0, T2_0, T3_0, stats);
  k0_params<<<1, 32, 0, stream>>>(stats, W0, g0, be0, params, params + 32);
  k0_pool<<<MVGRID, 256, 0, stream>>>(x, T1_0, T2_0, T3_0, W0, params, params + 32, bufA);

  // ---- layer 1 ----
  k_mv_a<<<MVGRID, 256, 0, stream>>>(bufA, ei2, ew2, bufB);
  k_mv_b<<<MVGRID, 256, 0, stream>>>(bufA, bufB, ei2, ew2, bufC);
  k_mv_c<<<MVGRID, 256, 0, stream>>>(bufB, bufC, ei2, ew2, bufD);
  k1_gemm<<<(N2_ + 255) / 256, 256, 0, stream>>>(bufA, bufB, bufC, bufD, W1, b1, bufA);
  k_stats32<<<2048, 256, 0, stream>>>(bufA, stats + 14, stats + 46);
  k1_params<<<1, 32, 0, stream>>>(stats + 14, stats + 46, g1, be1, params + 64, params + 96);

  // ---- layer 2 (input = f(out1), applied on the fly) ----
  k2_mv_a<<<MVGRID, 256, 0, stream>>>(bufA, ei2, ew2, params + 64, params + 96, bufB);
  k2_mv_b<<<MVGRID, 256, 0, stream>>>(bufA, bufB, ei2, ew2, params + 64, params + 96, bufC);
  k2_mv3out<<<2048, 256, 0, stream>>>(bufA, bufB, bufC, ei2, ew2, W2, b2,
                                      params + 64, params + 96, out2, stats + 78);
  k2_params<<<1, 64, 0, stream>>>(stats + 78, g2, be2, params);

  // ---- MLP head ----
  k3_gemm1<<<256, 256, 0, stream>>>(out2, lin1W, params, h1pre);
  k4_bn1<<<1, 256, 0, stream>>>(h1pre, bn1g, bn1b, h1);
  k5_gemm2<<<128, 256, 0, stream>>>(h1, lin2W, h2pre);
  k6_final<<<1, 256, 0, stream>>>(h2pre, bn2g, bn2b, lin3W, lin3b, (float*)d_out);
}

// Round 2
// 935.929 us; speedup vs baseline: 1.1526x; 1.1526x over previous
//
#include <hip/hip_runtime.h>
#include <cstdint>

#define SLOPE 0.33f

static constexpr int B_   = 64;
static constexpr int E1_  = 8978;
static constexpr int E2_  = 4489;
static constexpr int N1_  = B_ * E1_;      // 574592
static constexpr int N2_  = B_ * E2_;      // 287296
static constexpr int DEG_ = 16;
static constexpr int QTR_ = 2245;          // ceil(E1_/4)
static constexpr int MVGRID = (N2_ * 32) / 256;   // 35912 (exact)
static constexpr int NBLK8  = N2_ / 8;            // 35912 (exact)
static constexpr int GEMM_BLOCKS = N2_ / 64;      // 4489 (exact)
static constexpr double EPS_ = 1e-5;

__device__ __forceinline__ float lrelu(float v) { return v > 0.f ? v : SLOPE * v; }

// =====================================================================
// Layer 0: 1 channel. Per-graph x slab staged in LDS; edges of node g are
// [g*16, g*16+16) by construction (dst sorted). grid = 64 graphs * 4 quarters.
// =====================================================================
__global__ __launch_bounds__(256) void k0_mv1(const float* __restrict__ x,
    const int* __restrict__ src, const float* __restrict__ ew, float* __restrict__ T1) {
  __shared__ float sx[E1_];
  int g = blockIdx.x >> 2, q = blockIdx.x & 3;
  int gbase = g * E1_;
  for (int j = threadIdx.x; j < E1_; j += 256) sx[j] = x[gbase + j];
  __syncthreads();
  int start = q * QTR_, end = min(start + QTR_, E1_);
  for (int i = start + (int)threadIdx.x; i < end; i += 256) {
    int node = gbase + i;
    const int4* s4 = (const int4*)(src + (size_t)node * DEG_);
    const float4* w4 = (const float4*)(ew + (size_t)node * DEG_);
    float acc = 0.f;
#pragma unroll
    for (int j = 0; j < 4; ++j) {
      int4 s = s4[j]; float4 w = w4[j];
      acc += w.x * sx[s.x - gbase] + w.y * sx[s.y - gbase]
           + w.z * sx[s.z - gbase] + w.w * sx[s.w - gbase];
    }
    T1[node] = sx[i] - acc;   // T1 = x - L x
  }
}

__global__ __launch_bounds__(256) void k0_mv2(const float* __restrict__ x,
    const int* __restrict__ src, const float* __restrict__ ew,
    const float* __restrict__ T1, float* __restrict__ T2) {
  __shared__ float sT[E1_];
  int g = blockIdx.x >> 2, q = blockIdx.x & 3;
  int gbase = g * E1_;
  for (int j = threadIdx.x; j < E1_; j += 256) sT[j] = T1[gbase + j];
  __syncthreads();
  int start = q * QTR_, end = min(start + QTR_, E1_);
  for (int i = start + (int)threadIdx.x; i < end; i += 256) {
    int node = gbase + i;
    const int4* s4 = (const int4*)(src + (size_t)node * DEG_);
    const float4* w4 = (const float4*)(ew + (size_t)node * DEG_);
    float acc = 0.f;
#pragma unroll
    for (int j = 0; j < 4; ++j) {
      int4 s = s4[j]; float4 w = w4[j];
      acc += w.x * sT[s.x - gbase] + w.y * sT[s.y - gbase]
           + w.z * sT[s.z - gbase] + w.w * sT[s.w - gbase];
    }
    T2[node] = (3.f * sT[i] - acc - x[node]) * 0.5f;  // T2 = (3T1 - L T1 - T0)/2
  }
}

// T3 = (5T2 - L T2 - 2T1)/3, plus moment accumulation for layer-0 BN:
// mom[0..3] = sum T_k ; mom[4..13] = sum T_k*T_l upper-tri (00,01,02,03,11,12,13,22,23,33)
__global__ __launch_bounds__(256) void k0_mv3(const float* __restrict__ x,
    const int* __restrict__ src, const float* __restrict__ ew,
    const float* __restrict__ T1, const float* __restrict__ T2,
    float* __restrict__ T3, double* mom) {
  __shared__ float sT[E1_];
  __shared__ double sred[4 * 14];
  int g = blockIdx.x >> 2, q = blockIdx.x & 3;
  int gbase = g * E1_;
  for (int j = threadIdx.x; j < E1_; j += 256) sT[j] = T2[gbase + j];
  __syncthreads();
  double m[14];
#pragma unroll
  for (int j = 0; j < 14; ++j) m[j] = 0.0;
  int start = q * QTR_, end = min(start + QTR_, E1_);
  for (int i = start + (int)threadIdx.x; i < end; i += 256) {
    int node = gbase + i;
    const int4* s4 = (const int4*)(src + (size_t)node * DEG_);
    const float4* w4 = (const float4*)(ew + (size_t)node * DEG_);
    float acc = 0.f;
#pragma unroll
    for (int j = 0; j < 4; ++j) {
      int4 s = s4[j]; float4 w = w4[j];
      acc += w.x * sT[s.x - gbase] + w.y * sT[s.y - gbase]
           + w.z * sT[s.z - gbase] + w.w * sT[s.w - gbase];
    }
    float t1 = T1[node];
    float t2 = sT[i];
    float t3 = (5.f * t2 - acc - 2.f * t1) * (1.f / 3.f);
    T3[node] = t3;
    double d0 = x[node], d1 = t1, d2 = t2, d3 = t3;
    m[0] += d0; m[1] += d1; m[2] += d2; m[3] += d3;
    m[4] += d0 * d0; m[5] += d0 * d1; m[6] += d0 * d2; m[7] += d0 * d3;
    m[8] += d1 * d1; m[9] += d1 * d2; m[10] += d1 * d3;
    m[11] += d2 * d2; m[12] += d2 * d3; m[13] += d3 * d3;
  }
  int lane = threadIdx.x & 63, wid = threadIdx.x >> 6;
#pragma unroll
  for (int j = 0; j < 14; ++j) {
    double v = m[j];
    for (int o = 32; o; o >>= 1) v += __shfl_down(v, o);
    if (lane == 0) sred[wid * 14 + j] = v;
  }
  __syncthreads();
  if (threadIdx.x < 14) {
    double s = sred[threadIdx.x] + sred[14 + threadIdx.x] + sred[28 + threadIdx.x] + sred[42 + threadIdx.x];
    atomicAdd(&mom[threadIdx.x], s);
  }
}

// BN params for layer 0: out_c = dot_c + b0 ; bias cancels in BN exactly.
__global__ void k0_params(const double* __restrict__ mom, const float* __restrict__ W0,
    const float* __restrict__ g0, const float* __restrict__ be0,
    float* __restrict__ scale0, float* __restrict__ shiftE0) {
  int c = threadIdx.x;
  if (c >= 32) return;
  double inv = 1.0 / (double)N1_;
  double mm[4];
#pragma unroll
  for (int k = 0; k < 4; ++k) mm[k] = mom[k] * inv;
  double M[4][4];
  M[0][0] = mom[4] * inv;  M[0][1] = mom[5] * inv;  M[0][2] = mom[6] * inv;  M[0][3] = mom[7] * inv;
  M[1][1] = mom[8] * inv;  M[1][2] = mom[9] * inv;  M[1][3] = mom[10] * inv;
  M[2][2] = mom[11] * inv; M[2][3] = mom[12] * inv; M[3][3] = mom[13] * inv;
  M[1][0] = M[0][1]; M[2][0] = M[0][2]; M[3][0] = M[0][3];
  M[2][1] = M[1][2]; M[3][1] = M[1][3]; M[3][2] = M[2][3];
  double w[4];
#pragma unroll
  for (int k = 0; k < 4; ++k) w[k] = W0[k * 32 + c];
  double mean = 0.0;
#pragma unroll
  for (int k = 0; k < 4; ++k) mean += w[k] * mm[k];
  double e2 = 0.0;
#pragma unroll
  for (int k = 0; k < 4; ++k)
#pragma unroll
    for (int l = 0; l < 4; ++l) e2 += M[k][l] * w[k] * w[l];
  double var = e2 - mean * mean;
  double sc = (double)g0[c] / sqrt(var + EPS_);
  scale0[c] = (float)sc;
  shiftE0[c] = (float)((double)be0[c] - sc * mean);
}

// fused: project to 32ch + BN + LeakyReLU + Graclus pair-max pool -> x1 (N2,32)
__global__ __launch_bounds__(256) void k0_pool(const float* __restrict__ x,
    const float* __restrict__ T1, const float* __restrict__ T2, const float* __restrict__ T3,
    const float* __restrict__ W0, const float* __restrict__ scale0,
    const float* __restrict__ shiftE0, float* __restrict__ x1) {
  int gid = blockIdx.x * 256 + threadIdx.x;
  int grp = gid >> 5, c = gid & 31;
  if (grp >= N2_) return;
  int b = grp / E2_, j = grp - b * E2_;
  int ga = b * E1_ + 2 * j, gb = ga + 1;
  float w0 = W0[c], w1 = W0[32 + c], w2 = W0[64 + c], w3 = W0[96 + c];
  float da = x[ga] * w0 + T1[ga] * w1 + T2[ga] * w2 + T3[ga] * w3;
  float db = x[gb] * w0 + T1[gb] * w1 + T2[gb] * w2 + T3[gb] * w3;
  float sc = scale0[c], sh = shiftE0[c];
  float ya = lrelu(sc * da + sh), yb = lrelu(sc * db + sh);
  x1[grp * 32 + c] = fmaxf(ya, yb);
}

// =====================================================================
// 32-channel matvecs, thread = (node, channel); gathers are 128B row reads.
// =====================================================================
__global__ __launch_bounds__(256) void k_mv_a(const float* __restrict__ X,
    const int* __restrict__ src, const float* __restrict__ ew, float* __restrict__ T1) {
  int gid = blockIdx.x * 256 + threadIdx.x;
  int i = gid >> 5, c = gid & 31;
  if (i >= N2_) return;
  const int4* s4 = (const int4*)(src + (size_t)i * DEG_);
  const float4* w4 = (const float4*)(ew + (size_t)i * DEG_);
  float acc = 0.f;
#pragma unroll
  for (int j = 0; j < 4; ++j) {
    int4 s = s4[j]; float4 w = w4[j];
    acc += w.x * X[s.x * 32 + c] + w.y * X[s.y * 32 + c]
         + w.z * X[s.z * 32 + c] + w.w * X[s.w * 32 + c];
  }
  T1[i * 32 + c] = X[i * 32 + c] - acc;
}

__global__ __launch_bounds__(256) void k_mv_b(const float* __restrict__ X,
    const float* __restrict__ T1, const int* __restrict__ src,
    const float* __restrict__ ew, float* __restrict__ T2) {
  int gid = blockIdx.x * 256 + threadIdx.x;
  int i = gid >> 5, c = gid & 31;
  if (i >= N2_) return;
  const int4* s4 = (const int4*)(src + (size_t)i * DEG_);
  const float4* w4 = (const float4*)(ew + (size_t)i * DEG_);
  float acc = 0.f;
#pragma unroll
  for (int j = 0; j < 4; ++j) {
    int4 s = s4[j]; float4 w = w4[j];
    acc += w.x * T1[s.x * 32 + c] + w.y * T1[s.y * 32 + c]
         + w.z * T1[s.z * 32 + c] + w.w * T1[s.w * 32 + c];
  }
  T2[i * 32 + c] = (3.f * T1[i * 32 + c] - acc - X[i * 32 + c]) * 0.5f;
}

// =====================================================================
// Fused layer-1 tail: T3 (LDS-only, never hits HBM) + GEMM
// out1 = [x1|T1|T2|T3] @ Wcat(128,32) + b1.
// Block = 64 nodes; 2-node x 4-channel register tile per thread.
// LDS: xs[q][node] float4, q = 0..31 over dcat/4 (A:0-7 B:8-15 C:16-23 D:24-31),
// row stride 65 float4 (pad) -> conflict-free staging writes & k-loop reads.
// =====================================================================
__global__ __launch_bounds__(256) void k1_fused(const float* __restrict__ Xa,
    const float* __restrict__ Xb, const float* __restrict__ Xc,
    const int* __restrict__ src, const float* __restrict__ ew,
    const float* __restrict__ W1, const float* __restrict__ b1,
    float* __restrict__ out) {
  __shared__ float4 xs[32 * 65];   // 33.3 KB
  __shared__ float4 wsl[32 * 33];  // 16.9 KB  [c][qq]
  int node0 = blockIdx.x * 64;
  // ---- phase 1: stage x1/T1/T2 tiles (coalesced 1KB/instr) + weights ----
  for (int i = threadIdx.x; i < 512; i += 256) {
    int n = i >> 3, qa = i & 7;
    int rowbase = (node0 + n) * 32;
    xs[(0  + qa) * 65 + n] = *(const float4*)(Xa + rowbase + 4 * qa);
    xs[(8  + qa) * 65 + n] = *(const float4*)(Xb + rowbase + 4 * qa);
    xs[(16 + qa) * 65 + n] = *(const float4*)(Xc + rowbase + 4 * qa);
  }
  for (int i = threadIdx.x; i < 1024; i += 256) {
    int c = i >> 5, qq = i & 31;
    int k = qq >> 3, d = (qq & 7) * 4;
    const float* wp = W1 + k * 1024 + d * 32 + c;
    float4 w = { wp[0], wp[32], wp[64], wp[96] };
    wsl[c * 33 + qq] = w;
  }
  __syncthreads();
  // ---- phase 2: T3 for our 64 nodes (gather T2 from global), store to LDS D-region ----
#pragma unroll
  for (int r = 0; r < 8; ++r) {
    int i = r * 256 + threadIdx.x;     // 0..2047
    int n = i >> 5, c = i & 31;
    int node = node0 + n;
    const int4* s4 = (const int4*)(src + (size_t)node * DEG_);
    const float4* w4 = (const float4*)(ew + (size_t)node * DEG_);
    float acc = 0.f;
#pragma unroll
    for (int j = 0; j < 4; ++j) {
      int4 s = s4[j]; float4 w = w4[j];
      acc += w.x * Xc[s.x * 32 + c] + w.y * Xc[s.y * 32 + c]
           + w.z * Xc[s.z * 32 + c] + w.w * Xc[s.w * 32 + c];
    }
    float t1 = ((const float*)&xs[(8  + (c >> 2)) * 65 + n])[c & 3];
    float t2 = ((const float*)&xs[(16 + (c >> 2)) * 65 + n])[c & 3];
    float t3 = (5.f * t2 - acc - 2.f * t1) * (1.f / 3.f);
    ((float*)&xs[(24 + (c >> 2)) * 65 + n])[c & 3] = t3;
  }
  __syncthreads();
  // ---- phase 3: GEMM. thread = (n2 = tid&31, cg = tid>>5): nodes {n2, n2+32}, channels 4cg..4cg+3
  int n2 = threadIdx.x & 31, cg = threadIdx.x >> 5;
  float a0[4] = {0.f, 0.f, 0.f, 0.f};
  float a1[4] = {0.f, 0.f, 0.f, 0.f};
#pragma unroll 4
  for (int qq = 0; qq < 32; ++qq) {
    float4 xv0 = xs[qq * 65 + n2];
    float4 xv1 = xs[qq * 65 + n2 + 32];
#pragma unroll
    for (int j = 0; j < 4; ++j) {
      float4 wv = wsl[(4 * cg + j) * 33 + qq];   // wave-broadcast read
      a0[j] += xv0.x * wv.x + xv0.y * wv.y + xv0.z * wv.z + xv0.w * wv.w;
      a1[j] += xv1.x * wv.x + xv1.y * wv.y + xv1.z * wv.z + xv1.w * wv.w;
    }
  }
  float4 bv = ((const float4*)b1)[cg];
  float4 o0 = { a0[0] + bv.x, a0[1] + bv.y, a0[2] + bv.z, a0[3] + bv.w };
  float4 o1 = { a1[0] + bv.x, a1[1] + bv.y, a1[2] + bv.z, a1[3] + bv.w };
  *(float4*)(out + (node0 + n2) * 32 + 4 * cg) = o0;
  *(float4*)(out + (node0 + n2 + 32) * 32 + 4 * cg) = o1;
}

// per-channel sum/sumsq of a (N2,32) array (for layer-1 BN)
__global__ __launch_bounds__(256) void k_stats32(const float* __restrict__ X,
    double* sum, double* sq) {
  __shared__ double s1[256], s2[256];
  const long total = (long)N2_ * 32;
  double a = 0.0, b = 0.0;
  for (long idx = (long)blockIdx.x * 256 + threadIdx.x; idx < total; idx += (long)gridDim.x * 256) {
    double v = X[idx]; a += v; b += v * v;
  }
  s1[threadIdx.x] = a; s2[threadIdx.x] = b;
  __syncthreads();
  int c = threadIdx.x;
  if (c < 32) {
    double sa = 0.0, sb = 0.0;
    for (int j = c; j < 256; j += 32) { sa += s1[j]; sb += s2[j]; }
    atomicAdd(&sum[c], sa); atomicAdd(&sq[c], sb);
  }
}

__global__ void k1_params(const double* __restrict__ sum, const double* __restrict__ sq,
    const float* __restrict__ g1, const float* __restrict__ be1,
    float* __restrict__ scale1, float* __restrict__ shiftE1) {
  int c = threadIdx.x;
  if (c >= 32) return;
  double mean = sum[c] / (double)N2_;
  double var = sq[c] / (double)N2_ - mean * mean;
  double sc = (double)g1[c] / sqrt(var + EPS_);
  scale1[c] = (float)sc;
  shiftE1[c] = (float)((double)be1[c] - sc * mean);
}

// layer-2 matvecs: input is f(out1) with f = lrelu(scale1*v + shiftE1), applied on the fly
__global__ __launch_bounds__(256) void k2_mv_a(const float* __restrict__ X,
    const int* __restrict__ src, const float* __restrict__ ew,
    const float* __restrict__ scale1, const float* __restrict__ shiftE1,
    float* __restrict__ T1) {
  int gid = blockIdx.x * 256 + threadIdx.x;
  int i = gid >> 5, c = gid & 31;
  if (i >= N2_) return;
  float sc = scale1[c], sh = shiftE1[c];
  const int4* s4 = (const int4*)(src + (size_t)i * DEG_);
  const float4* w4 = (const float4*)(ew + (size_t)i * DEG_);
  float acc = 0.f;
#pragma unroll
  for (int j = 0; j < 4; ++j) {
    int4 s = s4[j]; float4 w = w4[j];
    acc += w.x * lrelu(sc * X[s.x * 32 + c] + sh) + w.y * lrelu(sc * X[s.y * 32 + c] + sh)
         + w.z * lrelu(sc * X[s.z * 32 + c] + sh) + w.w * lrelu(sc * X[s.w * 32 + c] + sh);
  }
  T1[i * 32 + c] = lrelu(sc * X[i * 32 + c] + sh) - acc;
}

__global__ __launch_bounds__(256) void k2_mv_b(const float* __restrict__ X,
    const float* __restrict__ T1, const int* __restrict__ src, const float* __restrict__ ew,
    const float* __restrict__ scale1, const float* __restrict__ shiftE1,
    float* __restrict__ T2) {
  int gid = blockIdx.x * 256 + threadIdx.x;
  int i = gid >> 5, c = gid & 31;
  if (i >= N2_) return;
  float sc = scale1[c], sh = shiftE1[c];
  const int4* s4 = (const int4*)(src + (size_t)i * DEG_);
  const float4* w4 = (const float4*)(ew + (size_t)i * DEG_);
  float acc = 0.f;
#pragma unroll
  for (int j = 0; j < 4; ++j) {
    int4 s = s4[j]; float4 w = w4[j];
    acc += w.x * T1[s.x * 32 + c] + w.y * T1[s.y * 32 + c]
         + w.z * T1[s.z * 32 + c] + w.w * T1[s.w * 32 + c];
  }
  T2[i * 32 + c] = (3.f * T1[i * 32 + c] - acc - lrelu(sc * X[i * 32 + c] + sh)) * 0.5f;
}

// T3 + projection to 1 channel (reduce over 32 lanes) + global sum/sumsq stats
__global__ __launch_bounds__(256) void k2_mv3out(const float* __restrict__ Xout1,
    const float* __restrict__ T1, const float* __restrict__ T2,
    const int* __restrict__ src, const float* __restrict__ ew,
    const float* __restrict__ W2, const float* __restrict__ b2,
    const float* __restrict__ scale1, const float* __restrict__ shiftE1,
    float* __restrict__ out2, double* st2) {
  __shared__ double sds[8], sss[8];
  int c = threadIdx.x & 31, g = threadIdx.x >> 5;
  float w0 = W2[c], w1 = W2[32 + c], w2c = W2[64 + c], w3 = W2[96 + c];
  float sc = scale1[c], sh = shiftE1[c];
  double accS = 0.0, accQ = 0.0;
  for (int nb = blockIdx.x; nb < NBLK8; nb += gridDim.x) {
    int i = nb * 8 + g;                 // always < N2_ (exact tiling)
    int base = i * 32;
    const int4* s4 = (const int4*)(src + (size_t)i * DEG_);
    const float4* w4 = (const float4*)(ew + (size_t)i * DEG_);
    float acc = 0.f;
#pragma unroll
    for (int j = 0; j < 4; ++j) {
      int4 s = s4[j]; float4 w = w4[j];
      acc += w.x * T2[s.x * 32 + c] + w.y * T2[s.y * 32 + c]
           + w.z * T2[s.z * 32 + c] + w.w * T2[s.w * 32 + c];
    }
    float t1r = T1[base + c], t2r = T2[base + c];
    float xr = lrelu(sc * Xout1[base + c] + sh);
    float t3 = (5.f * t2r - acc - 2.f * t1r) * (1.f / 3.f);
    float contrib = xr * w0 + t1r * w1 + t2r * w2c + t3 * w3;
    for (int o = 16; o; o >>= 1) contrib += __shfl_down(contrib, o, 32);
    if (c == 0) {
      float ov = contrib + b2[0];
      out2[i] = ov;
      accS += ov; accQ += (double)ov * (double)ov;
    }
  }
  if (c == 0) { sds[g] = accS; sss[g] = accQ; }
  __syncthreads();
  if (threadIdx.x == 0) {
    double a = 0.0, b = 0.0;
    for (int j = 0; j < 8; ++j) { a += sds[j]; b += sss[j]; }
    atomicAdd(&st2[0], a); atomicAdd(&st2[1], b);
  }
}

__global__ void k2_params(const double* __restrict__ st2, const float* __restrict__ g2,
    const float* __restrict__ be2, float* __restrict__ p /* [128]=scale2 [129]=shiftE2 */) {
  if (threadIdx.x != 0) return;
  double mean = st2[0] / (double)N2_;
  double var = st2[1] / (double)N2_ - mean * mean;
  double sc = (double)g2[0] / sqrt(var + EPS_);
  p[128] = (float)sc;
  p[129] = (float)((double)be2[0] - sc * mean);
}

// MLP: h1pre[b,c] = sum_r f2(out2[b*E2+r]) * lin1_W[r,c]   (256 blocks: 16 colgroups x 16 rsplits)
__global__ __launch_bounds__(256) void k3_gemm1(const float* __restrict__ out2,
    const float* __restrict__ lin1W, const float* __restrict__ p, float* h1pre) {
  float sc = p[128], sh = p[129];
  int cg = blockIdx.x & 15, rs = blockIdx.x >> 4;
  int c = cg * 16 + (threadIdx.x & 15);
  int bq = threadIdx.x >> 4;          // 0..15 -> 4 batches each
  int b0 = bq * 4;
  int r0 = rs * 281, r1 = min(r0 + 281, E2_);
  float a0 = 0.f, a1 = 0.f, a2 = 0.f, a3 = 0.f;
  for (int r = r0; r < r1; ++r) {
    float w = lin1W[r * 256 + c];
    a0 += lrelu(sc * out2[(b0 + 0) * E2_ + r] + sh) * w;
    a1 += lrelu(sc * out2[(b0 + 1) * E2_ + r] + sh) * w;
    a2 += lrelu(sc * out2[(b0 + 2) * E2_ + r] + sh) * w;
    a3 += lrelu(sc * out2[(b0 + 3) * E2_ + r] + sh) * w;
  }
  atomicAdd(&h1pre[(b0 + 0) * 256 + c], a0);
  atomicAdd(&h1pre[(b0 + 1) * 256 + c], a1);
  atomicAdd(&h1pre[(b0 + 2) * 256 + c], a2);
  atomicAdd(&h1pre[(b0 + 3) * 256 + c], a3);
}

// BN1 (bias cancels) + ReLU -> h1 (64,256). one block, thread = column.
__global__ __launch_bounds__(256) void k4_bn1(const float* __restrict__ h1pre,
    const float* __restrict__ g, const float* __restrict__ be, float* __restrict__ h1) {
  int c = threadIdx.x;
  float vs[64];
  double s = 0.0, q = 0.0;
  for (int b = 0; b < 64; ++b) { float v = h1pre[b * 256 + c]; vs[b] = v; s += v; q += (double)v * v; }
  double mean = s / 64.0, var = q / 64.0 - mean * mean;
  double scd = (double)g[c] / sqrt(var + EPS_);
  double shd = (double)be[c] - scd * mean;
  for (int b = 0; b < 64; ++b) {
    float y = (float)(scd * vs[b] + shd);
    h1[b * 256 + c] = y > 0.f ? y : 0.f;
  }
}

// gemm2: 128 blocks, block = output column
__global__ __launch_bounds__(256) void k5_gemm2(const float* __restrict__ h1,
    const float* __restrict__ lin2W, float* __restrict__ h2pre) {
  __shared__ float sred[256];
  int c = blockIdx.x;
  int b = threadIdx.x & 63, q = threadIdx.x >> 6;
  float acc = 0.f;
  for (int r = q; r < 256; r += 4) acc += h1[b * 256 + r] * lin2W[r * 128 + c];
  sred[threadIdx.x] = acc;
  __syncthreads();
  if (threadIdx.x < 64)
    h2pre[threadIdx.x * 128 + c] = sred[threadIdx.x] + sred[64 + threadIdx.x]
                                 + sred[128 + threadIdx.x] + sred[192 + threadIdx.x];
}

// BN2 + ReLU + final linear -> out[64]
__global__ __launch_bounds__(256) void k6_final(const float* __restrict__ h2pre,
    const float* __restrict__ g, const float* __restrict__ be,
    const float* __restrict__ W3, const float* __restrict__ b3, float* __restrict__ outp) {
  __shared__ float sh2[64 * 129];
  __shared__ float sred[256];
  int tid = threadIdx.x;
  if (tid < 128) {
    int c = tid;
    float vs[64];
    double s = 0.0, q = 0.0;
    for (int b = 0; b < 64; ++b) { float v = h2pre[b * 128 + c]; vs[b] = v; s += v; q += (double)v * v; }
    double mean = s / 64.0, var = q / 64.0 - mean * mean;
    double scd = (double)g[c] / sqrt(var + EPS_);
    double shd = (double)be[c] - scd * mean;
    for (int b = 0; b < 64; ++b) {
      float y = (float)(scd * vs[b] + shd);
      sh2[b * 129 + c] = y > 0.f ? y : 0.f;
    }
  }
  __syncthreads();
  int b = tid & 63, q = tid >> 6;
  float acc = 0.f;
  for (int r = q; r < 128; r += 4) acc += sh2[b * 129 + r] * W3[r];
  sred[tid] = acc;
  __syncthreads();
  if (tid < 64)
    outp[tid] = sred[tid] + sred[64 + tid] + sred[128 + tid] + sred[192 + tid] + b3[0];
}

// =====================================================================
extern "C" void kernel_launch(void* const* d_in, const int* in_sizes, int n_in,
                              void* d_out, int out_size, void* d_ws, size_t ws_size,
                              hipStream_t stream) {
  const float* x    = (const float*)d_in[0];
  const int*   ei1  = (const int*)d_in[1];     // src = ei1[0:NE1]
  const float* ew1  = (const float*)d_in[2];
  const int*   ei2  = (const int*)d_in[3];
  const float* ew2  = (const float*)d_in[4];
  const float* W0   = (const float*)d_in[5];
  // b0 (d_in[6]) cancels through BN exactly — unused
  const float* g0   = (const float*)d_in[7];
  const float* be0  = (const float*)d_in[8];
  const float* W1   = (const float*)d_in[9];
  const float* b1   = (const float*)d_in[10];
  const float* g1   = (const float*)d_in[11];
  const float* be1  = (const float*)d_in[12];
  const float* W2   = (const float*)d_in[13];
  const float* b2   = (const float*)d_in[14];
  const float* g2   = (const float*)d_in[15];
  const float* be2  = (const float*)d_in[16];
  const float* lin1W = (const float*)d_in[17];
  // lin1_b (18) cancels through BN
  const float* bn1g = (const float*)d_in[19];
  const float* bn1b = (const float*)d_in[20];
  const float* lin2W = (const float*)d_in[21];
  // lin2_b (22) cancels through BN
  const float* bn2g = (const float*)d_in[23];
  const float* bn2b = (const float*)d_in[24];
  const float* lin3W = (const float*)d_in[25];
  const float* lin3b = (const float*)d_in[26];

  char* ws = (char*)d_ws;
  double* stats  = (double*)ws;                 // [0..13] mom0, [14..45] s1sum, [46..77] s1sq, [78..79] st2
  float*  params = (float*)(ws + 1024);         // scale0[32] shiftE0[32] scale1[32] shiftE1[32] scale2 shiftE2
  float*  h1pre  = (float*)(ws + 4096);
  float*  h1     = (float*)(ws + 4096 + 65536);
  float*  h2pre  = (float*)(ws + 4096 + 131072);
  float*  big    = (float*)(ws + 262144);
  float* T1_0 = big;
  float* T2_0 = big + N1_;
  float* T3_0 = big + 2 * (size_t)N1_;
  float* bufA = big + 3 * (size_t)N1_;          // x1
  float* bufB = bufA + 32 * (size_t)N2_;        // T1
  float* bufC = bufB + 32 * (size_t)N2_;        // T2
  float* bufD = bufC + 32 * (size_t)N2_;        // out1 (T3 never materialized)
  float* out2 = bufD + 32 * (size_t)N2_;        // (N2,)

  hipMemsetAsync(stats, 0, 80 * sizeof(double), stream);
  hipMemsetAsync(h1pre, 0, 65536, stream);

  // ---- layer 0 ----
  k0_mv1<<<256, 256, 0, stream>>>(x, ei1, ew1, T1_0);
  k0_mv2<<<256, 256, 0, stream>>>(x, ei1, ew1, T1_0, T2_0);
  k0_mv3<<<256, 256, 0, stream>>>(x, ei1, ew1, T1_0, T2_0, T3_0, stats);
  k0_params<<<1, 32, 0, stream>>>(stats, W0, g0, be0, params, params + 32);
  k0_pool<<<MVGRID, 256, 0, stream>>>(x, T1_0, T2_0, T3_0, W0, params, params + 32, bufA);

  // ---- layer 1 ----
  k_mv_a<<<MVGRID, 256, 0, stream>>>(bufA, ei2, ew2, bufB);
  k_mv_b<<<MVGRID, 256, 0, stream>>>(bufA, bufB, ei2, ew2, bufC);
  k1_fused<<<GEMM_BLOCKS, 256, 0, stream>>>(bufA, bufB, bufC, ei2, ew2, W1, b1, bufD);
  k_stats32<<<2048, 256, 0, stream>>>(bufD, stats + 14, stats + 46);
  k1_params<<<1, 32, 0, stream>>>(stats + 14, stats + 46, g1, be1, params + 64, params + 96);

  // ---- layer 2 (input = f(out1), applied on the fly) ----
  k2_mv_a<<<MVGRID, 256, 0, stream>>>(bufD, ei2, ew2, params + 64, params + 96, bufB);
  k2_mv_b<<<MVGRID, 256, 0, stream>>>(bufD, bufB, ei2, ew2, params + 64, params + 96, bufC);
  k2_mv3out<<<2048, 256, 0, stream>>>(bufD, bufB, bufC, ei2, ew2, W2, b2,
                                      params + 64, params + 96, out2, stats + 78);
  k2_params<<<1, 64, 0, stream>>>(stats + 78, g2, be2, params);

  // ---- MLP head ----
  k3_gemm1<<<256, 256, 0, stream>>>(out2, lin1W, params, h1pre);
  k4_bn1<<<1, 256, 0, stream>>>(h1pre, bn1g, bn1b, h1);
  k5_gemm2<<<128, 256, 0, stream>>>(h1, lin2W, h2pre);
  k6_final<<<1, 256, 0, stream>>>(h2pre, bn2g, bn2b, lin3W, lin3b, (float*)d_out);
}

// Round 3
// 829.826 us; speedup vs baseline: 1.3000x; 1.1279x over previous
//
#include <hip/hip_runtime.h>
#include <cstdint>

#define SLOPE 0.33f

static constexpr int B_   = 64;
static constexpr int E1_  = 8978;
static constexpr int E2_  = 4489;
static constexpr int N1_  = B_ * E1_;      // 574592
static constexpr int N2_  = B_ * E2_;      // 287296
static constexpr int DEG_ = 16;
static constexpr int QTR_ = 2245;          // ceil(E1_/4)
static constexpr int MVGRID = (N2_ * 32) / 256;   // 35912 (exact)
static constexpr int NBLK8  = N2_ / 8;            // 35912 (exact)
static constexpr int GEMM_BLOCKS = N2_ / 64;      // 4489 (exact)
static constexpr double EPS_ = 1e-5;

__device__ __forceinline__ float lrelu(float v) { return v > 0.f ? v : SLOPE * v; }

// =====================================================================
// Layer 0: 1 channel. Per-graph x slab staged in LDS; edges of node g are
// [g*16, g*16+16) by construction (dst sorted). grid = 64 graphs * 4 quarters.
// =====================================================================
__global__ __launch_bounds__(256) void k0_mv1(const float* __restrict__ x,
    const int* __restrict__ src, const float* __restrict__ ew, float* __restrict__ T1) {
  __shared__ float sx[E1_];
  int g = blockIdx.x >> 2, q = blockIdx.x & 3;
  int gbase = g * E1_;
  for (int j = threadIdx.x; j < E1_; j += 256) sx[j] = x[gbase + j];
  __syncthreads();
  int start = q * QTR_, end = min(start + QTR_, E1_);
  for (int i = start + (int)threadIdx.x; i < end; i += 256) {
    int node = gbase + i;
    const int4* s4 = (const int4*)(src + (size_t)node * DEG_);
    const float4* w4 = (const float4*)(ew + (size_t)node * DEG_);
    float acc = 0.f;
#pragma unroll
    for (int j = 0; j < 4; ++j) {
      int4 s = s4[j]; float4 w = w4[j];
      acc += w.x * sx[s.x - gbase] + w.y * sx[s.y - gbase]
           + w.z * sx[s.z - gbase] + w.w * sx[s.w - gbase];
    }
    T1[node] = sx[i] - acc;   // T1 = x - L x
  }
}

__global__ __launch_bounds__(256) void k0_mv2(const float* __restrict__ x,
    const int* __restrict__ src, const float* __restrict__ ew,
    const float* __restrict__ T1, float* __restrict__ T2) {
  __shared__ float sT[E1_];
  int g = blockIdx.x >> 2, q = blockIdx.x & 3;
  int gbase = g * E1_;
  for (int j = threadIdx.x; j < E1_; j += 256) sT[j] = T1[gbase + j];
  __syncthreads();
  int start = q * QTR_, end = min(start + QTR_, E1_);
  for (int i = start + (int)threadIdx.x; i < end; i += 256) {
    int node = gbase + i;
    const int4* s4 = (const int4*)(src + (size_t)node * DEG_);
    const float4* w4 = (const float4*)(ew + (size_t)node * DEG_);
    float acc = 0.f;
#pragma unroll
    for (int j = 0; j < 4; ++j) {
      int4 s = s4[j]; float4 w = w4[j];
      acc += w.x * sT[s.x - gbase] + w.y * sT[s.y - gbase]
           + w.z * sT[s.z - gbase] + w.w * sT[s.w - gbase];
    }
    T2[node] = (3.f * sT[i] - acc - x[node]) * 0.5f;  // T2 = (3T1 - L T1 - T0)/2
  }
}

// T3 = (5T2 - L T2 - 2T1)/3, plus moment accumulation for layer-0 BN:
// mom[0..3] = sum T_k ; mom[4..13] = sum T_k*T_l upper-tri (00,01,02,03,11,12,13,22,23,33)
__global__ __launch_bounds__(256) void k0_mv3(const float* __restrict__ x,
    const int* __restrict__ src, const float* __restrict__ ew,
    const float* __restrict__ T1, const float* __restrict__ T2,
    float* __restrict__ T3, double* mom) {
  __shared__ float sT[E1_];
  __shared__ double sred[4 * 14];
  int g = blockIdx.x >> 2, q = blockIdx.x & 3;
  int gbase = g * E1_;
  for (int j = threadIdx.x; j < E1_; j += 256) sT[j] = T2[gbase + j];
  __syncthreads();
  double m[14];
#pragma unroll
  for (int j = 0; j < 14; ++j) m[j] = 0.0;
  int start = q * QTR_, end = min(start + QTR_, E1_);
  for (int i = start + (int)threadIdx.x; i < end; i += 256) {
    int node = gbase + i;
    const int4* s4 = (const int4*)(src + (size_t)node * DEG_);
    const float4* w4 = (const float4*)(ew + (size_t)node * DEG_);
    float acc = 0.f;
#pragma unroll
    for (int j = 0; j < 4; ++j) {
      int4 s = s4[j]; float4 w = w4[j];
      acc += w.x * sT[s.x - gbase] + w.y * sT[s.y - gbase]
           + w.z * sT[s.z - gbase] + w.w * sT[s.w - gbase];
    }
    float t1 = T1[node];
    float t2 = sT[i];
    float t3 = (5.f * t2 - acc - 2.f * t1) * (1.f / 3.f);
    T3[node] = t3;
    double d0 = x[node], d1 = t1, d2 = t2, d3 = t3;
    m[0] += d0; m[1] += d1; m[2] += d2; m[3] += d3;
    m[4] += d0 * d0; m[5] += d0 * d1; m[6] += d0 * d2; m[7] += d0 * d3;
    m[8] += d1 * d1; m[9] += d1 * d2; m[10] += d1 * d3;
    m[11] += d2 * d2; m[12] += d2 * d3; m[13] += d3 * d3;
  }
  int lane = threadIdx.x & 63, wid = threadIdx.x >> 6;
#pragma unroll
  for (int j = 0; j < 14; ++j) {
    double v = m[j];
    for (int o = 32; o; o >>= 1) v += __shfl_down(v, o);
    if (lane == 0) sred[wid * 14 + j] = v;
  }
  __syncthreads();
  if (threadIdx.x < 14) {
    double s = sred[threadIdx.x] + sred[14 + threadIdx.x] + sred[28 + threadIdx.x] + sred[42 + threadIdx.x];
    atomicAdd(&mom[threadIdx.x], s);
  }
}

// BN params for layer 0: out_c = dot_c + b0 ; bias cancels in BN exactly.
__global__ void k0_params(const double* __restrict__ mom, const float* __restrict__ W0,
    const float* __restrict__ g0, const float* __restrict__ be0,
    float* __restrict__ scale0, float* __restrict__ shiftE0) {
  int c = threadIdx.x;
  if (c >= 32) return;
  double inv = 1.0 / (double)N1_;
  double mm[4];
#pragma unroll
  for (int k = 0; k < 4; ++k) mm[k] = mom[k] * inv;
  double M[4][4];
  M[0][0] = mom[4] * inv;  M[0][1] = mom[5] * inv;  M[0][2] = mom[6] * inv;  M[0][3] = mom[7] * inv;
  M[1][1] = mom[8] * inv;  M[1][2] = mom[9] * inv;  M[1][3] = mom[10] * inv;
  M[2][2] = mom[11] * inv; M[2][3] = mom[12] * inv; M[3][3] = mom[13] * inv;
  M[1][0] = M[0][1]; M[2][0] = M[0][2]; M[3][0] = M[0][3];
  M[2][1] = M[1][2]; M[3][1] = M[1][3]; M[3][2] = M[2][3];
  double w[4];
#pragma unroll
  for (int k = 0; k < 4; ++k) w[k] = W0[k * 32 + c];
  double mean = 0.0;
#pragma unroll
  for (int k = 0; k < 4; ++k) mean += w[k] * mm[k];
  double e2 = 0.0;
#pragma unroll
  for (int k = 0; k < 4; ++k)
#pragma unroll
    for (int l = 0; l < 4; ++l) e2 += M[k][l] * w[k] * w[l];
  double var = e2 - mean * mean;
  double sc = (double)g0[c] / sqrt(var + EPS_);
  scale0[c] = (float)sc;
  shiftE0[c] = (float)((double)be0[c] - sc * mean);
}

// fused: project to 32ch + BN + LeakyReLU + Graclus pair-max pool -> x1 (N2,32)
__global__ __launch_bounds__(256) void k0_pool(const float* __restrict__ x,
    const float* __restrict__ T1, const float* __restrict__ T2, const float* __restrict__ T3,
    const float* __restrict__ W0, const float* __restrict__ scale0,
    const float* __restrict__ shiftE0, float* __restrict__ x1) {
  int gid = blockIdx.x * 256 + threadIdx.x;
  int grp = gid >> 5, c = gid & 31;
  if (grp >= N2_) return;
  int b = grp / E2_, j = grp - b * E2_;
  int ga = b * E1_ + 2 * j, gb = ga + 1;
  float w0 = W0[c], w1 = W0[32 + c], w2 = W0[64 + c], w3 = W0[96 + c];
  float da = x[ga] * w0 + T1[ga] * w1 + T2[ga] * w2 + T3[ga] * w3;
  float db = x[gb] * w0 + T1[gb] * w1 + T2[gb] * w2 + T3[gb] * w3;
  float sc = scale0[c], sh = shiftE0[c];
  float ya = lrelu(sc * da + sh), yb = lrelu(sc * db + sh);
  x1[grp * 32 + c] = fmaxf(ya, yb);
}

// =====================================================================
// 32-channel matvecs, thread = (node, channel); gathers are 128B row reads.
// =====================================================================
__global__ __launch_bounds__(256) void k_mv_a(const float* __restrict__ X,
    const int* __restrict__ src, const float* __restrict__ ew, float* __restrict__ T1) {
  int gid = blockIdx.x * 256 + threadIdx.x;
  int i = gid >> 5, c = gid & 31;
  if (i >= N2_) return;
  const int4* s4 = (const int4*)(src + (size_t)i * DEG_);
  const float4* w4 = (const float4*)(ew + (size_t)i * DEG_);
  float acc = 0.f;
#pragma unroll
  for (int j = 0; j < 4; ++j) {
    int4 s = s4[j]; float4 w = w4[j];
    acc += w.x * X[s.x * 32 + c] + w.y * X[s.y * 32 + c]
         + w.z * X[s.z * 32 + c] + w.w * X[s.w * 32 + c];
  }
  T1[i * 32 + c] = X[i * 32 + c] - acc;
}

__global__ __launch_bounds__(256) void k_mv_b(const float* __restrict__ X,
    const float* __restrict__ T1, const int* __restrict__ src,
    const float* __restrict__ ew, float* __restrict__ T2) {
  int gid = blockIdx.x * 256 + threadIdx.x;
  int i = gid >> 5, c = gid & 31;
  if (i >= N2_) return;
  const int4* s4 = (const int4*)(src + (size_t)i * DEG_);
  const float4* w4 = (const float4*)(ew + (size_t)i * DEG_);
  float acc = 0.f;
#pragma unroll
  for (int j = 0; j < 4; ++j) {
    int4 s = s4[j]; float4 w = w4[j];
    acc += w.x * T1[s.x * 32 + c] + w.y * T1[s.y * 32 + c]
         + w.z * T1[s.z * 32 + c] + w.w * T1[s.w * 32 + c];
  }
  T2[i * 32 + c] = (3.f * T1[i * 32 + c] - acc - X[i * 32 + c]) * 0.5f;
}

// =====================================================================
// Fused layer-1 tail: T3 (LDS-only, never hits HBM) + GEMM
// out1 = [x1|T1|T2|T3] @ Wcat(128,32) + b1.
// Block = 64 nodes; 2-node x 4-channel register tile per thread.
// =====================================================================
__global__ __launch_bounds__(256) void k1_fused(const float* __restrict__ Xa,
    const float* __restrict__ Xb, const float* __restrict__ Xc,
    const int* __restrict__ src, const float* __restrict__ ew,
    const float* __restrict__ W1, const float* __restrict__ b1,
    float* __restrict__ out) {
  __shared__ float4 xs[32 * 65];   // 33.3 KB
  __shared__ float4 wsl[32 * 33];  // 16.9 KB  [c][qq]
  int node0 = blockIdx.x * 64;
  // ---- phase 1: stage x1/T1/T2 tiles (coalesced 1KB/instr) + weights ----
  for (int i = threadIdx.x; i < 512; i += 256) {
    int n = i >> 3, qa = i & 7;
    int rowbase = (node0 + n) * 32;
    xs[(0  + qa) * 65 + n] = *(const float4*)(Xa + rowbase + 4 * qa);
    xs[(8  + qa) * 65 + n] = *(const float4*)(Xb + rowbase + 4 * qa);
    xs[(16 + qa) * 65 + n] = *(const float4*)(Xc + rowbase + 4 * qa);
  }
  for (int i = threadIdx.x; i < 1024; i += 256) {
    int c = i >> 5, qq = i & 31;
    int k = qq >> 3, d = (qq & 7) * 4;
    const float* wp = W1 + k * 1024 + d * 32 + c;
    float4 w = { wp[0], wp[32], wp[64], wp[96] };
    wsl[c * 33 + qq] = w;
  }
  __syncthreads();
  // ---- phase 2: T3 for our 64 nodes (gather T2 from global), store to LDS D-region ----
#pragma unroll
  for (int r = 0; r < 8; ++r) {
    int i = r * 256 + threadIdx.x;     // 0..2047
    int n = i >> 5, c = i & 31;
    int node = node0 + n;
    const int4* s4 = (const int4*)(src + (size_t)node * DEG_);
    const float4* w4 = (const float4*)(ew + (size_t)node * DEG_);
    float acc = 0.f;
#pragma unroll
    for (int j = 0; j < 4; ++j) {
      int4 s = s4[j]; float4 w = w4[j];
      acc += w.x * Xc[s.x * 32 + c] + w.y * Xc[s.y * 32 + c]
           + w.z * Xc[s.z * 32 + c] + w.w * Xc[s.w * 32 + c];
    }
    float t1 = ((const float*)&xs[(8  + (c >> 2)) * 65 + n])[c & 3];
    float t2 = ((const float*)&xs[(16 + (c >> 2)) * 65 + n])[c & 3];
    float t3 = (5.f * t2 - acc - 2.f * t1) * (1.f / 3.f);
    ((float*)&xs[(24 + (c >> 2)) * 65 + n])[c & 3] = t3;
  }
  __syncthreads();
  // ---- phase 3: GEMM. thread = (n2 = tid&31, cg = tid>>5): nodes {n2, n2+32}, channels 4cg..4cg+3
  int n2 = threadIdx.x & 31, cg = threadIdx.x >> 5;
  float a0[4] = {0.f, 0.f, 0.f, 0.f};
  float a1[4] = {0.f, 0.f, 0.f, 0.f};
#pragma unroll 4
  for (int qq = 0; qq < 32; ++qq) {
    float4 xv0 = xs[qq * 65 + n2];
    float4 xv1 = xs[qq * 65 + n2 + 32];
#pragma unroll
    for (int j = 0; j < 4; ++j) {
      float4 wv = wsl[(4 * cg + j) * 33 + qq];   // wave-broadcast read
      a0[j] += xv0.x * wv.x + xv0.y * wv.y + xv0.z * wv.z + xv0.w * wv.w;
      a1[j] += xv1.x * wv.x + xv1.y * wv.y + xv1.z * wv.z + xv1.w * wv.w;
    }
  }
  float4 bv = ((const float4*)b1)[cg];
  float4 o0 = { a0[0] + bv.x, a0[1] + bv.y, a0[2] + bv.z, a0[3] + bv.w };
  float4 o1 = { a1[0] + bv.x, a1[1] + bv.y, a1[2] + bv.z, a1[3] + bv.w };
  *(float4*)(out + (node0 + n2) * 32 + 4 * cg) = o0;
  *(float4*)(out + (node0 + n2 + 32) * 32 + 4 * cg) = o1;
}

// per-channel sum/sumsq of a (N2,32) array (for layer-1 BN)
__global__ __launch_bounds__(256) void k_stats32(const float* __restrict__ X,
    double* sum, double* sq) {
  __shared__ double s1[256], s2[256];
  const long total = (long)N2_ * 32;
  double a = 0.0, b = 0.0;
  for (long idx = (long)blockIdx.x * 256 + threadIdx.x; idx < total; idx += (long)gridDim.x * 256) {
    double v = X[idx]; a += v; b += v * v;
  }
  s1[threadIdx.x] = a; s2[threadIdx.x] = b;
  __syncthreads();
  int c = threadIdx.x;
  if (c < 32) {
    double sa = 0.0, sb = 0.0;
    for (int j = c; j < 256; j += 32) { sa += s1[j]; sb += s2[j]; }
    atomicAdd(&sum[c], sa); atomicAdd(&sq[c], sb);
  }
}

__global__ void k1_params(const double* __restrict__ sum, const double* __restrict__ sq,
    const float* __restrict__ g1, const float* __restrict__ be1,
    float* __restrict__ scale1, float* __restrict__ shiftE1) {
  int c = threadIdx.x;
  if (c >= 32) return;
  double mean = sum[c] / (double)N2_;
  double var = sq[c] / (double)N2_ - mean * mean;
  double sc = (double)g1[c] / sqrt(var + EPS_);
  scale1[c] = (float)sc;
  shiftE1[c] = (float)((double)be1[c] - sc * mean);
}

// layer-2 matvecs: input is f(out1) with f = lrelu(scale1*v + shiftE1), applied on the fly
__global__ __launch_bounds__(256) void k2_mv_a(const float* __restrict__ X,
    const int* __restrict__ src, const float* __restrict__ ew,
    const float* __restrict__ scale1, const float* __restrict__ shiftE1,
    float* __restrict__ T1) {
  int gid = blockIdx.x * 256 + threadIdx.x;
  int i = gid >> 5, c = gid & 31;
  if (i >= N2_) return;
  float sc = scale1[c], sh = shiftE1[c];
  const int4* s4 = (const int4*)(src + (size_t)i * DEG_);
  const float4* w4 = (const float4*)(ew + (size_t)i * DEG_);
  float acc = 0.f;
#pragma unroll
  for (int j = 0; j < 4; ++j) {
    int4 s = s4[j]; float4 w = w4[j];
    acc += w.x * lrelu(sc * X[s.x * 32 + c] + sh) + w.y * lrelu(sc * X[s.y * 32 + c] + sh)
         + w.z * lrelu(sc * X[s.z * 32 + c] + sh) + w.w * lrelu(sc * X[s.w * 32 + c] + sh);
  }
  T1[i * 32 + c] = lrelu(sc * X[i * 32 + c] + sh) - acc;
}

__global__ __launch_bounds__(256) void k2_mv_b(const float* __restrict__ X,
    const float* __restrict__ T1, const int* __restrict__ src, const float* __restrict__ ew,
    const float* __restrict__ scale1, const float* __restrict__ shiftE1,
    float* __restrict__ T2) {
  int gid = blockIdx.x * 256 + threadIdx.x;
  int i = gid >> 5, c = gid & 31;
  if (i >= N2_) return;
  float sc = scale1[c], sh = shiftE1[c];
  const int4* s4 = (const int4*)(src + (size_t)i * DEG_);
  const float4* w4 = (const float4*)(ew + (size_t)i * DEG_);
  float acc = 0.f;
#pragma unroll
  for (int j = 0; j < 4; ++j) {
    int4 s = s4[j]; float4 w = w4[j];
    acc += w.x * T1[s.x * 32 + c] + w.y * T1[s.y * 32 + c]
         + w.z * T1[s.z * 32 + c] + w.w * T1[s.w * 32 + c];
  }
  T2[i * 32 + c] = (3.f * T1[i * 32 + c] - acc - lrelu(sc * X[i * 32 + c] + sh)) * 0.5f;
}

// T3 + projection to 1 channel (reduce over 32 lanes) + global sum/sumsq stats
__global__ __launch_bounds__(256) void k2_mv3out(const float* __restrict__ Xout1,
    const float* __restrict__ T1, const float* __restrict__ T2,
    const int* __restrict__ src, const float* __restrict__ ew,
    const float* __restrict__ W2, const float* __restrict__ b2,
    const float* __restrict__ scale1, const float* __restrict__ shiftE1,
    float* __restrict__ out2, double* st2) {
  __shared__ double sds[8], sss[8];
  int c = threadIdx.x & 31, g = threadIdx.x >> 5;
  float w0 = W2[c], w1 = W2[32 + c], w2c = W2[64 + c], w3 = W2[96 + c];
  float sc = scale1[c], sh = shiftE1[c];
  double accS = 0.0, accQ = 0.0;
  for (int nb = blockIdx.x; nb < NBLK8; nb += gridDim.x) {
    int i = nb * 8 + g;                 // always < N2_ (exact tiling)
    int base = i * 32;
    const int4* s4 = (const int4*)(src + (size_t)i * DEG_);
    const float4* w4 = (const float4*)(ew + (size_t)i * DEG_);
    float acc = 0.f;
#pragma unroll
    for (int j = 0; j < 4; ++j) {
      int4 s = s4[j]; float4 w = w4[j];
      acc += w.x * T2[s.x * 32 + c] + w.y * T2[s.y * 32 + c]
           + w.z * T2[s.z * 32 + c] + w.w * T2[s.w * 32 + c];
    }
    float t1r = T1[base + c], t2r = T2[base + c];
    float xr = lrelu(sc * Xout1[base + c] + sh);
    float t3 = (5.f * t2r - acc - 2.f * t1r) * (1.f / 3.f);
    float contrib = xr * w0 + t1r * w1 + t2r * w2c + t3 * w3;
    for (int o = 16; o; o >>= 1) contrib += __shfl_down(contrib, o, 32);
    if (c == 0) {
      float ov = contrib + b2[0];
      out2[i] = ov;
      accS += ov; accQ += (double)ov * (double)ov;
    }
  }
  if (c == 0) { sds[g] = accS; sss[g] = accQ; }
  __syncthreads();
  if (threadIdx.x == 0) {
    double a = 0.0, b = 0.0;
    for (int j = 0; j < 8; ++j) { a += sds[j]; b += sss[j]; }
    atomicAdd(&st2[0], a); atomicAdd(&st2[1], b);
  }
}

__global__ void k2_params(const double* __restrict__ st2, const float* __restrict__ g2,
    const float* __restrict__ be2, float* __restrict__ p /* [128]=scale2 [129]=shiftE2 */) {
  if (threadIdx.x != 0) return;
  double mean = st2[0] / (double)N2_;
  double var = st2[1] / (double)N2_ - mean * mean;
  double sc = (double)g2[0] / sqrt(var + EPS_);
  p[128] = (float)sc;
  p[129] = (float)((double)be2[0] - sc * mean);
}

// MLP gemm1: h1pre[b,c] = sum_r f2(out2[b*E2+r]) * lin1_W[r,c]
// grid = 256 blocks = 16 batch-splits (4 batches) x 16 row-splits (281 rows).
// thread = column c (0..255): lin1W row reads are 1KB/wave coalesced; f2(out2)
// chunk staged in LDS, re-read as wave-broadcast ds_read_b128.
__global__ __launch_bounds__(256) void k3_gemm1(const float* __restrict__ out2,
    const float* __restrict__ lin1W, const float* __restrict__ p, float* h1pre) {
  __shared__ float f2v[4][284];   // 284 = 71*4 -> rows 16B-aligned
  float sc = p[128], sh = p[129];
  int bs = blockIdx.x & 15, rs = blockIdx.x >> 4;
  int b0 = bs * 4;
  int r0 = rs * 281;
  int nr = min(281, E2_ - r0);    // 281, last row-split 274
  int c = threadIdx.x;
#pragma unroll
  for (int b = 0; b < 4; ++b)
    for (int j = c; j < 284; j += 256)
      f2v[b][j] = (j < nr) ? lrelu(sc * out2[(b0 + b) * E2_ + r0 + j] + sh) : 0.f;
  __syncthreads();
  float acc0 = 0.f, acc1 = 0.f, acc2 = 0.f, acc3 = 0.f;
  int nr4 = nr & ~3;
  int j = 0;
  for (; j < nr4; j += 4) {
    const float* wp = lin1W + (size_t)(r0 + j) * 256 + c;
    float w0 = wp[0], w1 = wp[256], w2 = wp[512], w3 = wp[768];
    float4 f0 = *(const float4*)&f2v[0][j];
    float4 f1 = *(const float4*)&f2v[1][j];
    float4 f2_ = *(const float4*)&f2v[2][j];
    float4 f3 = *(const float4*)&f2v[3][j];
    acc0 += f0.x * w0 + f0.y * w1 + f0.z * w2 + f0.w * w3;
    acc1 += f1.x * w0 + f1.y * w1 + f1.z * w2 + f1.w * w3;
    acc2 += f2_.x * w0 + f2_.y * w1 + f2_.z * w2 + f2_.w * w3;
    acc3 += f3.x * w0 + f3.y * w1 + f3.z * w2 + f3.w * w3;
  }
  for (; j < nr; ++j) {
    float w = lin1W[(size_t)(r0 + j) * 256 + c];
    acc0 += f2v[0][j] * w;
    acc1 += f2v[1][j] * w;
    acc2 += f2v[2][j] * w;
    acc3 += f2v[3][j] * w;
  }
  atomicAdd(&h1pre[(b0 + 0) * 256 + c], acc0);
  atomicAdd(&h1pre[(b0 + 1) * 256 + c], acc1);
  atomicAdd(&h1pre[(b0 + 2) * 256 + c], acc2);
  atomicAdd(&h1pre[(b0 + 3) * 256 + c], acc3);
}

// BN1 (bias cancels) + ReLU -> h1 (64,256). one block, thread = column.
__global__ __launch_bounds__(256) void k4_bn1(const float* __restrict__ h1pre,
    const float* __restrict__ g, const float* __restrict__ be, float* __restrict__ h1) {
  int c = threadIdx.x;
  float vs[64];
  double s = 0.0, q = 0.0;
  for (int b = 0; b < 64; ++b) { float v = h1pre[b * 256 + c]; vs[b] = v; s += v; q += (double)v * v; }
  double mean = s / 64.0, var = q / 64.0 - mean * mean;
  double scd = (double)g[c] / sqrt(var + EPS_);
  double shd = (double)be[c] - scd * mean;
  for (int b = 0; b < 64; ++b) {
    float y = (float)(scd * vs[b] + shd);
    h1[b * 256 + c] = y > 0.f ? y : 0.f;
  }
}

// gemm2: 128 blocks, block = output column
__global__ __launch_bounds__(256) void k5_gemm2(const float* __restrict__ h1,
    const float* __restrict__ lin2W, float* __restrict__ h2pre) {
  __shared__ float sred[256];
  int c = blockIdx.x;
  int b = threadIdx.x & 63, q = threadIdx.x >> 6;
  float acc = 0.f;
  for (int r = q; r < 256; r += 4) acc += h1[b * 256 + r] * lin2W[r * 128 + c];
  sred[threadIdx.x] = acc;
  __syncthreads();
  if (threadIdx.x < 64)
    h2pre[threadIdx.x * 128 + c] = sred[threadIdx.x] + sred[64 + threadIdx.x]
                                 + sred[128 + threadIdx.x] + sred[192 + threadIdx.x];
}

// BN2 + ReLU + final linear -> out[64]
__global__ __launch_bounds__(256) void k6_final(const float* __restrict__ h2pre,
    const float* __restrict__ g, const float* __restrict__ be,
    const float* __restrict__ W3, const float* __restrict__ b3, float* __restrict__ outp) {
  __shared__ float sh2[64 * 129];
  __shared__ float sred[256];
  int tid = threadIdx.x;
  if (tid < 128) {
    int c = tid;
    float vs[64];
    double s = 0.0, q = 0.0;
    for (int b = 0; b < 64; ++b) { float v = h2pre[b * 128 + c]; vs[b] = v; s += v; q += (double)v * v; }
    double mean = s / 64.0, var = q / 64.0 - mean * mean;
    double scd = (double)g[c] / sqrt(var + EPS_);
    double shd = (double)be[c] - scd * mean;
    for (int b = 0; b < 64; ++b) {
      float y = (float)(scd * vs[b] + shd);
      sh2[b * 129 + c] = y > 0.f ? y : 0.f;
    }
  }
  __syncthreads();
  int b = tid & 63, q = tid >> 6;
  float acc = 0.f;
  for (int r = q; r < 128; r += 4) acc += sh2[b * 129 + r] * W3[r];
  sred[tid] = acc;
  __syncthreads();
  if (tid < 64)
    outp[tid] = sred[tid] + sred[64 + tid] + sred[128 + tid] + sred[192 + tid] + b3[0];
}

// =====================================================================
extern "C" void kernel_launch(void* const* d_in, const int* in_sizes, int n_in,
                              void* d_out, int out_size, void* d_ws, size_t ws_size,
                              hipStream_t stream) {
  const float* x    = (const float*)d_in[0];
  const int*   ei1  = (const int*)d_in[1];     // src = ei1[0:NE1]
  const float* ew1  = (const float*)d_in[2];
  const int*   ei2  = (const int*)d_in[3];
  const float* ew2  = (const float*)d_in[4];
  const float* W0   = (const float*)d_in[5];
  // b0 (d_in[6]) cancels through BN exactly — unused
  const float* g0   = (const float*)d_in[7];
  const float* be0  = (const float*)d_in[8];
  const float* W1   = (const float*)d_in[9];
  const float* b1   = (const float*)d_in[10];
  const float* g1   = (const float*)d_in[11];
  const float* be1  = (const float*)d_in[12];
  const float* W2   = (const float*)d_in[13];
  const float* b2   = (const float*)d_in[14];
  const float* g2   = (const float*)d_in[15];
  const float* be2  = (const float*)d_in[16];
  const float* lin1W = (const float*)d_in[17];
  // lin1_b (18) cancels through BN
  const float* bn1g = (const float*)d_in[19];
  const float* bn1b = (const float*)d_in[20];
  const float* lin2W = (const float*)d_in[21];
  // lin2_b (22) cancels through BN
  const float* bn2g = (const float*)d_in[23];
  const float* bn2b = (const float*)d_in[24];
  const float* lin3W = (const float*)d_in[25];
  const float* lin3b = (const float*)d_in[26];

  char* ws = (char*)d_ws;
  double* stats  = (double*)ws;                 // [0..13] mom0, [14..45] s1sum, [46..77] s1sq, [78..79] st2
  float*  params = (float*)(ws + 1024);         // scale0[32] shiftE0[32] scale1[32] shiftE1[32] scale2 shiftE2
  float*  h1pre  = (float*)(ws + 4096);
  float*  h1     = (float*)(ws + 4096 + 65536);
  float*  h2pre  = (float*)(ws + 4096 + 131072);
  float*  big    = (float*)(ws + 262144);
  float* T1_0 = big;
  float* T2_0 = big + N1_;
  float* T3_0 = big + 2 * (size_t)N1_;
  float* bufA = big + 3 * (size_t)N1_;          // x1
  float* bufB = bufA + 32 * (size_t)N2_;        // T1
  float* bufC = bufB + 32 * (size_t)N2_;        // T2
  float* bufD = bufC + 32 * (size_t)N2_;        // out1 (T3 never materialized)
  float* out2 = bufD + 32 * (size_t)N2_;        // (N2,)

  hipMemsetAsync(stats, 0, 80 * sizeof(double), stream);
  hipMemsetAsync(h1pre, 0, 65536, stream);

  // ---- layer 0 ----
  k0_mv1<<<256, 256, 0, stream>>>(x, ei1, ew1, T1_0);
  k0_mv2<<<256, 256, 0, stream>>>(x, ei1, ew1, T1_0, T2_0);
  k0_mv3<<<256, 256, 0, stream>>>(x, ei1, ew1, T1_0, T2_0, T3_0, stats);
  k0_params<<<1, 32, 0, stream>>>(stats, W0, g0, be0, params, params + 32);
  k0_pool<<<MVGRID, 256, 0, stream>>>(x, T1_0, T2_0, T3_0, W0, params, params + 32, bufA);

  // ---- layer 1 ----
  k_mv_a<<<MVGRID, 256, 0, stream>>>(bufA, ei2, ew2, bufB);
  k_mv_b<<<MVGRID, 256, 0, stream>>>(bufA, bufB, ei2, ew2, bufC);
  k1_fused<<<GEMM_BLOCKS, 256, 0, stream>>>(bufA, bufB, bufC, ei2, ew2, W1, b1, bufD);
  k_stats32<<<2048, 256, 0, stream>>>(bufD, stats + 14, stats + 46);
  k1_params<<<1, 32, 0, stream>>>(stats + 14, stats + 46, g1, be1, params + 64, params + 96);

  // ---- layer 2 (input = f(out1), applied on the fly) ----
  k2_mv_a<<<MVGRID, 256, 0, stream>>>(bufD, ei2, ew2, params + 64, params + 96, bufB);
  k2_mv_b<<<MVGRID, 256, 0, stream>>>(bufD, bufB, ei2, ew2, params + 64, params + 96, bufC);
  k2_mv3out<<<2048, 256, 0, stream>>>(bufD, bufB, bufC, ei2, ew2, W2, b2,
                                      params + 64, params + 96, out2, stats + 78);
  k2_params<<<1, 64, 0, stream>>>(stats + 78, g2, be2, params);

  // ---- MLP head ----
  k3_gemm1<<<256, 256, 0, stream>>>(out2, lin1W, params, h1pre);
  k4_bn1<<<1, 256, 0, stream>>>(h1pre, bn1g, bn1b, h1);
  k5_gemm2<<<128, 256, 0, stream>>>(h1, lin2W, h2pre);
  k6_final<<<1, 256, 0, stream>>>(h2pre, bn2g, bn2b, lin3W, lin3b, (float*)d_out);
}

// Round 4
// 769.875 us; speedup vs baseline: 1.4012x; 1.0779x over previous
//
#include <hip/hip_runtime.h>
#include <cstdint>

#define SLOPE 0.33f

static constexpr int B_   = 64;
static constexpr int E1_  = 8978;
static constexpr int E2_  = 4489;
static constexpr int N1_  = B_ * E1_;      // 574592
static constexpr int N2_  = B_ * E2_;      // 287296
static constexpr int DEG_ = 16;
static constexpr int QTR_ = 2245;          // ceil(E1_/4)
static constexpr int QTR2_ = 1123;         // ceil(E2_/4)
static constexpr int MVGRID = (N2_ * 32) / 256;   // 35912 (exact)
static constexpr int MVH_GRID = (N2_ * 8) / 256;  // 8978 (exact)
static constexpr double EPS_ = 1e-5;

__device__ __forceinline__ float lrelu(float v) { return v > 0.f ? v : SLOPE * v; }

// =====================================================================
// Layer 0: 1 channel. Per-graph x slab staged in LDS; edges of node g are
// [g*16, g*16+16) by construction (dst sorted). grid = 64 graphs * 4 quarters.
// =====================================================================
__global__ __launch_bounds__(256) void k0_mv1(const float* __restrict__ x,
    const int* __restrict__ src, const float* __restrict__ ew, float* __restrict__ T1) {
  __shared__ float sx[E1_];
  int g = blockIdx.x >> 2, q = blockIdx.x & 3;
  int gbase = g * E1_;
  for (int j = threadIdx.x; j < E1_; j += 256) sx[j] = x[gbase + j];
  __syncthreads();
  int start = q * QTR_, end = min(start + QTR_, E1_);
  for (int i = start + (int)threadIdx.x; i < end; i += 256) {
    int node = gbase + i;
    const int4* s4 = (const int4*)(src + (size_t)node * DEG_);
    const float4* w4 = (const float4*)(ew + (size_t)node * DEG_);
    float acc = 0.f;
#pragma unroll
    for (int j = 0; j < 4; ++j) {
      int4 s = s4[j]; float4 w = w4[j];
      acc += w.x * sx[s.x - gbase] + w.y * sx[s.y - gbase]
           + w.z * sx[s.z - gbase] + w.w * sx[s.w - gbase];
    }
    T1[node] = sx[i] - acc;   // T1 = x - L x
  }
}

__global__ __launch_bounds__(256) void k0_mv2(const float* __restrict__ x,
    const int* __restrict__ src, const float* __restrict__ ew,
    const float* __restrict__ T1, float* __restrict__ T2) {
  __shared__ float sT[E1_];
  int g = blockIdx.x >> 2, q = blockIdx.x & 3;
  int gbase = g * E1_;
  for (int j = threadIdx.x; j < E1_; j += 256) sT[j] = T1[gbase + j];
  __syncthreads();
  int start = q * QTR_, end = min(start + QTR_, E1_);
  for (int i = start + (int)threadIdx.x; i < end; i += 256) {
    int node = gbase + i;
    const int4* s4 = (const int4*)(src + (size_t)node * DEG_);
    const float4* w4 = (const float4*)(ew + (size_t)node * DEG_);
    float acc = 0.f;
#pragma unroll
    for (int j = 0; j < 4; ++j) {
      int4 s = s4[j]; float4 w = w4[j];
      acc += w.x * sT[s.x - gbase] + w.y * sT[s.y - gbase]
           + w.z * sT[s.z - gbase] + w.w * sT[s.w - gbase];
    }
    T2[node] = (3.f * sT[i] - acc - x[node]) * 0.5f;  // T2 = (3T1 - L T1 - T0)/2
  }
}

// T3 = (5T2 - L T2 - 2T1)/3, plus moment accumulation for layer-0 BN.
__global__ __launch_bounds__(256) void k0_mv3(const float* __restrict__ x,
    const int* __restrict__ src, const float* __restrict__ ew,
    const float* __restrict__ T1, const float* __restrict__ T2,
    float* __restrict__ T3, double* mom) {
  __shared__ float sT[E1_];
  __shared__ double sred[4 * 14];
  int g = blockIdx.x >> 2, q = blockIdx.x & 3;
  int gbase = g * E1_;
  for (int j = threadIdx.x; j < E1_; j += 256) sT[j] = T2[gbase + j];
  __syncthreads();
  double m[14];
#pragma unroll
  for (int j = 0; j < 14; ++j) m[j] = 0.0;
  int start = q * QTR_, end = min(start + QTR_, E1_);
  for (int i = start + (int)threadIdx.x; i < end; i += 256) {
    int node = gbase + i;
    const int4* s4 = (const int4*)(src + (size_t)node * DEG_);
    const float4* w4 = (const float4*)(ew + (size_t)node * DEG_);
    float acc = 0.f;
#pragma unroll
    for (int j = 0; j < 4; ++j) {
      int4 s = s4[j]; float4 w = w4[j];
      acc += w.x * sT[s.x - gbase] + w.y * sT[s.y - gbase]
           + w.z * sT[s.z - gbase] + w.w * sT[s.w - gbase];
    }
    float t1 = T1[node];
    float t2 = sT[i];
    float t3 = (5.f * t2 - acc - 2.f * t1) * (1.f / 3.f);
    T3[node] = t3;
    double d0 = x[node], d1 = t1, d2 = t2, d3 = t3;
    m[0] += d0; m[1] += d1; m[2] += d2; m[3] += d3;
    m[4] += d0 * d0; m[5] += d0 * d1; m[6] += d0 * d2; m[7] += d0 * d3;
    m[8] += d1 * d1; m[9] += d1 * d2; m[10] += d1 * d3;
    m[11] += d2 * d2; m[12] += d2 * d3; m[13] += d3 * d3;
  }
  int lane = threadIdx.x & 63, wid = threadIdx.x >> 6;
#pragma unroll
  for (int j = 0; j < 14; ++j) {
    double v = m[j];
    for (int o = 32; o; o >>= 1) v += __shfl_down(v, o);
    if (lane == 0) sred[wid * 14 + j] = v;
  }
  __syncthreads();
  if (threadIdx.x < 14) {
    double s = sred[threadIdx.x] + sred[14 + threadIdx.x] + sred[28 + threadIdx.x] + sred[42 + threadIdx.x];
    atomicAdd(&mom[threadIdx.x], s);
  }
}

// BN params for layer 0 (b0 cancels in BN exactly).
__global__ void k0_params(const double* __restrict__ mom, const float* __restrict__ W0,
    const float* __restrict__ g0, const float* __restrict__ be0,
    float* __restrict__ scale0, float* __restrict__ shiftE0) {
  int c = threadIdx.x;
  if (c >= 32) return;
  double inv = 1.0 / (double)N1_;
  double mm[4];
#pragma unroll
  for (int k = 0; k < 4; ++k) mm[k] = mom[k] * inv;
  double M[4][4];
  M[0][0] = mom[4] * inv;  M[0][1] = mom[5] * inv;  M[0][2] = mom[6] * inv;  M[0][3] = mom[7] * inv;
  M[1][1] = mom[8] * inv;  M[1][2] = mom[9] * inv;  M[1][3] = mom[10] * inv;
  M[2][2] = mom[11] * inv; M[2][3] = mom[12] * inv; M[3][3] = mom[13] * inv;
  M[1][0] = M[0][1]; M[2][0] = M[0][2]; M[3][0] = M[0][3];
  M[2][1] = M[1][2]; M[3][1] = M[1][3]; M[3][2] = M[2][3];
  double w[4];
#pragma unroll
  for (int k = 0; k < 4; ++k) w[k] = W0[k * 32 + c];
  double mean = 0.0;
#pragma unroll
  for (int k = 0; k < 4; ++k) mean += w[k] * mm[k];
  double e2 = 0.0;
#pragma unroll
  for (int k = 0; k < 4; ++k)
#pragma unroll
    for (int l = 0; l < 4; ++l) e2 += M[k][l] * w[k] * w[l];
  double var = e2 - mean * mean;
  double sc = (double)g0[c] / sqrt(var + EPS_);
  scale0[c] = (float)sc;
  shiftE0[c] = (float)((double)be0[c] - sc * mean);
}

// fused: project to 32ch + BN + LeakyReLU + Graclus pair-max pool -> x1 (N2,32)
__global__ __launch_bounds__(256) void k0_pool(const float* __restrict__ x,
    const float* __restrict__ T1, const float* __restrict__ T2, const float* __restrict__ T3,
    const float* __restrict__ W0, const float* __restrict__ scale0,
    const float* __restrict__ shiftE0, float* __restrict__ x1) {
  int gid = blockIdx.x * 256 + threadIdx.x;
  int grp = gid >> 5, c = gid & 31;
  if (grp >= N2_) return;
  int b = grp / E2_, j = grp - b * E2_;
  int ga = b * E1_ + 2 * j, gb = ga + 1;
  float w0 = W0[c], w1 = W0[32 + c], w2 = W0[64 + c], w3 = W0[96 + c];
  float da = x[ga] * w0 + T1[ga] * w1 + T2[ga] * w2 + T3[ga] * w3;
  float db = x[gb] * w0 + T1[gb] * w1 + T2[gb] * w2 + T3[gb] * w3;
  float sc = scale0[c], sh = shiftE0[c];
  float ya = lrelu(sc * da + sh), yb = lrelu(sc * db + sh);
  x1[grp * 32 + c] = fmaxf(ya, yb);
}

// =====================================================================
// Layer-1 Horner: out1 = P0 + L(P1 + L(P2 + L P3)), P_j = x1 @ Q_j where
// Q_j are fixed combos of W1[k] (Laguerre polynomial coefficients of L^j).
// =====================================================================
// k1_proj: one wave = 32 cols x 2 output arrays. Q columns in VGPRs, x1 row
// read as wave-uniform float4 broadcast loads. grid 1024 x 4 waves = 4096
// streams over N2 rows.
__global__ __launch_bounds__(256) void k1_proj(const float* __restrict__ X,
    const float* __restrict__ W1, float* __restrict__ outLo, float* __restrict__ outHi,
    float4 coefLo, float4 coefHi) {
  int lane = threadIdx.x & 63;
  int c = lane & 31, half = lane >> 5;
  int wid = threadIdx.x >> 6;
  int sid = blockIdx.x * 4 + wid;
  float4 cf = half ? coefHi : coefLo;
  float qv[32];
#pragma unroll
  for (int cp = 0; cp < 32; ++cp) {
    const float* wp = W1 + cp * 32 + c;
    qv[cp] = cf.x * wp[0] + cf.y * wp[1024] + cf.z * wp[2048] + cf.w * wp[3072];
  }
  float* dst = half ? outHi : outLo;
  for (int g = sid; g < N2_; g += 4096) {
    const float4* xr = (const float4*)(X + (size_t)g * 32);
    float acc = 0.f;
#pragma unroll
    for (int t = 0; t < 8; ++t) {
      float4 v = xr[t];
      acc += v.x * qv[4 * t] + v.y * qv[4 * t + 1] + v.z * qv[4 * t + 2] + v.w * qv[4 * t + 3];
    }
    dst[(size_t)g * 32 + c] = acc;
  }
}

// mv_h: O = S + L G  (32-channel). thread = (node, channel-quad):
// gathers are 8 rows x 128B = 1KB per instruction; edge data 8x redundant.
__global__ __launch_bounds__(256) void mv_h(const float* __restrict__ S,
    const float* __restrict__ G, const int* __restrict__ src,
    const float* __restrict__ ew, float* __restrict__ O) {
  int gid = blockIdx.x * 256 + threadIdx.x;
  int node = gid >> 3, c4 = gid & 7;
  const int4* s4 = (const int4*)(src + (size_t)node * DEG_);
  const float4* w4 = (const float4*)(ew + (size_t)node * DEG_);
  const float4* G4 = (const float4*)G;
  float4 acc = {0.f, 0.f, 0.f, 0.f};
#pragma unroll
  for (int j = 0; j < 4; ++j) {
    int4 s = s4[j]; float4 w = w4[j];
    float4 a = G4[(size_t)s.x * 8 + c4];
    float4 b = G4[(size_t)s.y * 8 + c4];
    float4 cc = G4[(size_t)s.z * 8 + c4];
    float4 d = G4[(size_t)s.w * 8 + c4];
    acc.x += w.x * a.x + w.y * b.x + w.z * cc.x + w.w * d.x;
    acc.y += w.x * a.y + w.y * b.y + w.z * cc.y + w.w * d.y;
    acc.z += w.x * a.z + w.y * b.z + w.z * cc.z + w.w * d.z;
    acc.w += w.x * a.w + w.y * b.w + w.z * cc.w + w.w * d.w;
  }
  float4 sv = ((const float4*)S)[(size_t)node * 8 + c4];
  float4 o = { sv.x + acc.x, sv.y + acc.y, sv.z + acc.z, sv.w + acc.w };
  ((float4*)O)[(size_t)node * 8 + c4] = o;
}

// per-channel sum/sumsq of a (N2,32) array (for layer-1 BN)
__global__ __launch_bounds__(256) void k_stats32(const float* __restrict__ X,
    double* sum, double* sq) {
  __shared__ double s1[256], s2[256];
  const long total = (long)N2_ * 32;
  double a = 0.0, b = 0.0;
  for (long idx = (long)blockIdx.x * 256 + threadIdx.x; idx < total; idx += (long)gridDim.x * 256) {
    double v = X[idx]; a += v; b += v * v;
  }
  s1[threadIdx.x] = a; s2[threadIdx.x] = b;
  __syncthreads();
  int c = threadIdx.x;
  if (c < 32) {
    double sa = 0.0, sb = 0.0;
    for (int j = c; j < 256; j += 32) { sa += s1[j]; sb += s2[j]; }
    atomicAdd(&sum[c], sa); atomicAdd(&sq[c], sb);
  }
}

__global__ void k1_params(const double* __restrict__ sum, const double* __restrict__ sq,
    const float* __restrict__ g1, const float* __restrict__ be1,
    float* __restrict__ scale1, float* __restrict__ shiftE1) {
  int c = threadIdx.x;
  if (c >= 32) return;
  double mean = sum[c] / (double)N2_;
  double var = sq[c] / (double)N2_ - mean * mean;
  double sc = (double)g1[c] / sqrt(var + EPS_);
  scale1[c] = (float)sc;
  shiftE1[c] = (float)((double)be1[c] - sc * mean);
}

// =====================================================================
// Layer-2 Horner on 1-channel fields: u_j = f(out1) q_j (q_j from W2),
// out2 = u0 + L(u1 + L(u2 + L u3)).  b2 cancels in BN2.
// =====================================================================
__global__ __launch_bounds__(256) void k2_proj(const float* __restrict__ X,
    const float* __restrict__ W2, const float* __restrict__ scale1,
    const float* __restrict__ shiftE1,
    float* __restrict__ u0, float* __restrict__ u1,
    float* __restrict__ u2, float* __restrict__ u3) {
  __shared__ float qv[4][32];
  __shared__ float fsc[32], fsh[32];
  int tid = threadIdx.x;
  if (tid < 128) {
    int cp = tid & 31, j = tid >> 5;
    float w0 = W2[cp], w1 = W2[32 + cp], w2 = W2[64 + cp], w3 = W2[96 + cp];
    float q;
    if (j == 0)      q = w0 + w1 + w2 + w3;
    else if (j == 1) q = -w1 - 2.f * w2 - 3.f * w3;
    else if (j == 2) q = 0.5f * w2 + 1.5f * w3;
    else             q = -w3 * (1.f / 6.f);
    qv[j][cp] = q;
  }
  if (tid < 32) { fsc[tid] = scale1[tid]; fsh[tid] = shiftE1[tid]; }
  __syncthreads();
  int node = blockIdx.x * 256 + tid;
  if (node >= N2_) return;
  const float4* xr = (const float4*)(X + (size_t)node * 32);
  float a0 = 0.f, a1 = 0.f, a2 = 0.f, a3 = 0.f;
#pragma unroll
  for (int t = 0; t < 8; ++t) {
    float4 v = xr[t];
    float f0 = lrelu(fsc[4 * t] * v.x + fsh[4 * t]);
    float f1 = lrelu(fsc[4 * t + 1] * v.y + fsh[4 * t + 1]);
    float f2_ = lrelu(fsc[4 * t + 2] * v.z + fsh[4 * t + 2]);
    float f3 = lrelu(fsc[4 * t + 3] * v.w + fsh[4 * t + 3]);
    a0 += f0 * qv[0][4 * t] + f1 * qv[0][4 * t + 1] + f2_ * qv[0][4 * t + 2] + f3 * qv[0][4 * t + 3];
    a1 += f0 * qv[1][4 * t] + f1 * qv[1][4 * t + 1] + f2_ * qv[1][4 * t + 2] + f3 * qv[1][4 * t + 3];
    a2 += f0 * qv[2][4 * t] + f1 * qv[2][4 * t + 1] + f2_ * qv[2][4 * t + 2] + f3 * qv[2][4 * t + 3];
    a3 += f0 * qv[3][4 * t] + f1 * qv[3][4 * t + 1] + f2_ * qv[3][4 * t + 2] + f3 * qv[3][4 * t + 3];
  }
  u0[node] = a0; u1[node] = a1; u2[node] = a2; u3[node] = a3;
}

// k2_step: zo = u + L z (1-channel), per-graph z slab in LDS.
// grid = 64 graphs x 4 quarters. do_stats!=0: also global sum/sumsq of zo.
__global__ __launch_bounds__(256) void k2_step(const float* __restrict__ z,
    const int* __restrict__ src, const float* __restrict__ ew,
    const float* __restrict__ u, float* __restrict__ zo,
    int do_stats, double* st2) {
  __shared__ float sz[E2_];
  __shared__ double sred[4][2];
  int g = blockIdx.x >> 2, q = blockIdx.x & 3;
  int gbase = g * E2_;
  for (int j = threadIdx.x; j < E2_; j += 256) sz[j] = z[gbase + j];
  __syncthreads();
  int start = q * QTR2_, end = min(start + QTR2_, E2_);
  double aS = 0.0, aQ = 0.0;
  for (int i = start + (int)threadIdx.x; i < end; i += 256) {
    int node = gbase + i;
    const int4* s4 = (const int4*)(src + (size_t)node * DEG_);
    const float4* w4 = (const float4*)(ew + (size_t)node * DEG_);
    float acc = 0.f;
#pragma unroll
    for (int j = 0; j < 4; ++j) {
      int4 s = s4[j]; float4 w = w4[j];
      acc += w.x * sz[s.x - gbase] + w.y * sz[s.y - gbase]
           + w.z * sz[s.z - gbase] + w.w * sz[s.w - gbase];
    }
    float val = u[node] + acc;
    zo[node] = val;
    if (do_stats) { aS += val; aQ += (double)val * (double)val; }
  }
  if (do_stats) {
    int lane = threadIdx.x & 63, wid = threadIdx.x >> 6;
    for (int o = 32; o; o >>= 1) { aS += __shfl_down(aS, o); aQ += __shfl_down(aQ, o); }
    if (lane == 0) { sred[wid][0] = aS; sred[wid][1] = aQ; }
    __syncthreads();
    if (threadIdx.x == 0) {
      double s = sred[0][0] + sred[1][0] + sred[2][0] + sred[3][0];
      double qq = sred[0][1] + sred[1][1] + sred[2][1] + sred[3][1];
      atomicAdd(&st2[0], s); atomicAdd(&st2[1], qq);
    }
  }
}

__global__ void k2_params(const double* __restrict__ st2, const float* __restrict__ g2,
    const float* __restrict__ be2, float* __restrict__ p /* [128]=scale2 [129]=shiftE2 */) {
  if (threadIdx.x != 0) return;
  double mean = st2[0] / (double)N2_;
  double var = st2[1] / (double)N2_ - mean * mean;
  double sc = (double)g2[0] / sqrt(var + EPS_);
  p[128] = (float)sc;
  p[129] = (float)((double)be2[0] - sc * mean);
}

// MLP gemm1: h1pre[b,c] = sum_r f2(out2[b*E2+r]) * lin1_W[r,c]
__global__ __launch_bounds__(256) void k3_gemm1(const float* __restrict__ out2,
    const float* __restrict__ lin1W, const float* __restrict__ p, float* h1pre) {
  __shared__ float f2v[4][284];
  float sc = p[128], sh = p[129];
  int bs = blockIdx.x & 15, rs = blockIdx.x >> 4;
  int b0 = bs * 4;
  int r0 = rs * 281;
  int nr = min(281, E2_ - r0);
  int c = threadIdx.x;
#pragma unroll
  for (int b = 0; b < 4; ++b)
    for (int j = c; j < 284; j += 256)
      f2v[b][j] = (j < nr) ? lrelu(sc * out2[(b0 + b) * E2_ + r0 + j] + sh) : 0.f;
  __syncthreads();
  float acc0 = 0.f, acc1 = 0.f, acc2 = 0.f, acc3 = 0.f;
  int nr4 = nr & ~3;
  int j = 0;
  for (; j < nr4; j += 4) {
    const float* wp = lin1W + (size_t)(r0 + j) * 256 + c;
    float w0 = wp[0], w1 = wp[256], w2 = wp[512], w3 = wp[768];
    float4 f0 = *(const float4*)&f2v[0][j];
    float4 f1 = *(const float4*)&f2v[1][j];
    float4 f2_ = *(const float4*)&f2v[2][j];
    float4 f3 = *(const float4*)&f2v[3][j];
    acc0 += f0.x * w0 + f0.y * w1 + f0.z * w2 + f0.w * w3;
    acc1 += f1.x * w0 + f1.y * w1 + f1.z * w2 + f1.w * w3;
    acc2 += f2_.x * w0 + f2_.y * w1 + f2_.z * w2 + f2_.w * w3;
    acc3 += f3.x * w0 + f3.y * w1 + f3.z * w2 + f3.w * w3;
  }
  for (; j < nr; ++j) {
    float w = lin1W[(size_t)(r0 + j) * 256 + c];
    acc0 += f2v[0][j] * w;
    acc1 += f2v[1][j] * w;
    acc2 += f2v[2][j] * w;
    acc3 += f2v[3][j] * w;
  }
  atomicAdd(&h1pre[(b0 + 0) * 256 + c], acc0);
  atomicAdd(&h1pre[(b0 + 1) * 256 + c], acc1);
  atomicAdd(&h1pre[(b0 + 2) * 256 + c], acc2);
  atomicAdd(&h1pre[(b0 + 3) * 256 + c], acc3);
}

// BN1 + ReLU -> h1 (64,256)
__global__ __launch_bounds__(256) void k4_bn1(const float* __restrict__ h1pre,
    const float* __restrict__ g, const float* __restrict__ be, float* __restrict__ h1) {
  int c = threadIdx.x;
  float vs[64];
  double s = 0.0, q = 0.0;
  for (int b = 0; b < 64; ++b) { float v = h1pre[b * 256 + c]; vs[b] = v; s += v; q += (double)v * v; }
  double mean = s / 64.0, var = q / 64.0 - mean * mean;
  double scd = (double)g[c] / sqrt(var + EPS_);
  double shd = (double)be[c] - scd * mean;
  for (int b = 0; b < 64; ++b) {
    float y = (float)(scd * vs[b] + shd);
    h1[b * 256 + c] = y > 0.f ? y : 0.f;
  }
}

// gemm2: 128 blocks, block = output column
__global__ __launch_bounds__(256) void k5_gemm2(const float* __restrict__ h1,
    const float* __restrict__ lin2W, float* __restrict__ h2pre) {
  __shared__ float sred[256];
  int c = blockIdx.x;
  int b = threadIdx.x & 63, q = threadIdx.x >> 6;
  float acc = 0.f;
  for (int r = q; r < 256; r += 4) acc += h1[b * 256 + r] * lin2W[r * 128 + c];
  sred[threadIdx.x] = acc;
  __syncthreads();
  if (threadIdx.x < 64)
    h2pre[threadIdx.x * 128 + c] = sred[threadIdx.x] + sred[64 + threadIdx.x]
                                 + sred[128 + threadIdx.x] + sred[192 + threadIdx.x];
}

// BN2 + ReLU + final linear -> out[64]
__global__ __launch_bounds__(256) void k6_final(const float* __restrict__ h2pre,
    const float* __restrict__ g, const float* __restrict__ be,
    const float* __restrict__ W3, const float* __restrict__ b3, float* __restrict__ outp) {
  __shared__ float sh2[64 * 129];
  __shared__ float sred[256];
  int tid = threadIdx.x;
  if (tid < 128) {
    int c = tid;
    float vs[64];
    double s = 0.0, q = 0.0;
    for (int b = 0; b < 64; ++b) { float v = h2pre[b * 128 + c]; vs[b] = v; s += v; q += (double)v * v; }
    double mean = s / 64.0, var = q / 64.0 - mean * mean;
    double scd = (double)g[c] / sqrt(var + EPS_);
    double shd = (double)be[c] - scd * mean;
    for (int b = 0; b < 64; ++b) {
      float y = (float)(scd * vs[b] + shd);
      sh2[b * 129 + c] = y > 0.f ? y : 0.f;
    }
  }
  __syncthreads();
  int b = tid & 63, q = tid >> 6;
  float acc = 0.f;
  for (int r = q; r < 128; r += 4) acc += sh2[b * 129 + r] * W3[r];
  sred[tid] = acc;
  __syncthreads();
  if (tid < 64)
    outp[tid] = sred[tid] + sred[64 + tid] + sred[128 + tid] + sred[192 + tid] + b3[0];
}

// =====================================================================
extern "C" void kernel_launch(void* const* d_in, const int* in_sizes, int n_in,
                              void* d_out, int out_size, void* d_ws, size_t ws_size,
                              hipStream_t stream) {
  const float* x    = (const float*)d_in[0];
  const int*   ei1  = (const int*)d_in[1];
  const float* ew1  = (const float*)d_in[2];
  const int*   ei2  = (const int*)d_in[3];
  const float* ew2  = (const float*)d_in[4];
  const float* W0   = (const float*)d_in[5];
  const float* g0   = (const float*)d_in[7];
  const float* be0  = (const float*)d_in[8];
  const float* W1   = (const float*)d_in[9];
  const float* g1   = (const float*)d_in[11];
  const float* be1  = (const float*)d_in[12];
  const float* W2   = (const float*)d_in[13];
  const float* g2   = (const float*)d_in[15];
  const float* be2  = (const float*)d_in[16];
  const float* lin1W = (const float*)d_in[17];
  const float* bn1g = (const float*)d_in[19];
  const float* bn1b = (const float*)d_in[20];
  const float* lin2W = (const float*)d_in[21];
  const float* bn2g = (const float*)d_in[23];
  const float* bn2b = (const float*)d_in[24];
  const float* lin3W = (const float*)d_in[25];
  const float* lin3b = (const float*)d_in[26];

  char* ws = (char*)d_ws;
  double* stats  = (double*)ws;                 // [0..13] mom0, [14..45] s1sum, [46..77] s1sq, [78..79] st2
  float*  params = (float*)(ws + 1024);         // scale0[32] shiftE0[32] scale1[32] shiftE1[32] ... [128..129]
  float*  h1pre  = (float*)(ws + 4096);
  float*  h1     = (float*)(ws + 4096 + 65536);
  float*  h2pre  = (float*)(ws + 4096 + 131072);
  // Treg: 3*N1 floats. Layer-0 T arrays live here; later overlaid by u/z/out2
  float*  Treg   = (float*)(ws + 262144);
  float* T1_0 = Treg;
  float* T2_0 = Treg + N1_;
  float* T3_0 = Treg + 2 * (size_t)N1_;
  float* u0   = Treg;                           // overlays (T dead after k0_pool)
  float* u1   = Treg + (size_t)N2_;
  float* u2   = Treg + 2 * (size_t)N2_;
  float* u3   = Treg + 3 * (size_t)N2_;
  float* zA   = Treg + 4 * (size_t)N2_;
  float* out2 = Treg + 5 * (size_t)N2_;         // 6*N2 <= 3*N1  ✓
  float*  big = (float*)(ws + 262144 + 3 * (size_t)N1_ * 4);
  float* bufA = big;                            // x1, later Z1
  float* bufB = bufA + 32 * (size_t)N2_;        // P3, later P1
  float* bufC = bufB + 32 * (size_t)N2_;        // P2, later P0
  float* bufD = bufC + 32 * (size_t)N2_;        // Z2, later out1

  hipMemsetAsync(stats, 0, 80 * sizeof(double), stream);
  hipMemsetAsync(h1pre, 0, 65536, stream);

  // ---- layer 0 ----
  k0_mv1<<<256, 256, 0, stream>>>(x, ei1, ew1, T1_0);
  k0_mv2<<<256, 256, 0, stream>>>(x, ei1, ew1, T1_0, T2_0);
  k0_mv3<<<256, 256, 0, stream>>>(x, ei1, ew1, T1_0, T2_0, T3_0, stats);
  k0_params<<<1, 32, 0, stream>>>(stats, W0, g0, be0, params, params + 32);
  k0_pool<<<MVGRID, 256, 0, stream>>>(x, T1_0, T2_0, T3_0, W0, params, params + 32, bufA);

  // ---- layer 1 (Horner) ----
  float4 cP3 = {0.f, 0.f, 0.f, -1.f / 6.f};
  float4 cP2 = {0.f, 0.f, 0.5f, 1.5f};
  float4 cP1 = {0.f, -1.f, -2.f, -3.f};
  float4 cP0 = {1.f, 1.f, 1.f, 1.f};
  k1_proj<<<1024, 256, 0, stream>>>(bufA, W1, bufB, bufC, cP3, cP2);   // B=P3, C=P2
  mv_h<<<MVH_GRID, 256, 0, stream>>>(bufC, bufB, ei2, ew2, bufD);      // D = Z2 = P2 + L P3
  k1_proj<<<1024, 256, 0, stream>>>(bufA, W1, bufB, bufC, cP1, cP0);   // B=P1, C=P0
  mv_h<<<MVH_GRID, 256, 0, stream>>>(bufB, bufD, ei2, ew2, bufA);      // A = Z1 = P1 + L Z2
  mv_h<<<MVH_GRID, 256, 0, stream>>>(bufC, bufA, ei2, ew2, bufD);      // D = out1 = P0 + L Z1
  k_stats32<<<2048, 256, 0, stream>>>(bufD, stats + 14, stats + 46);
  k1_params<<<1, 32, 0, stream>>>(stats + 14, stats + 46, g1, be1, params + 64, params + 96);

  // ---- layer 2 (Horner, 1-channel) ----
  k2_proj<<<(N2_ + 255) / 256, 256, 0, stream>>>(bufD, W2, params + 64, params + 96,
                                                 u0, u1, u2, u3);
  k2_step<<<256, 256, 0, stream>>>(u3, ei2, ew2, u2, zA, 0, nullptr);       // zA = u2 + L u3
  k2_step<<<256, 256, 0, stream>>>(zA, ei2, ew2, u1, u3, 0, nullptr);       // u3slot = u1 + L zA
  k2_step<<<256, 256, 0, stream>>>(u3, ei2, ew2, u0, out2, 1, stats + 78);  // out2 + stats
  k2_params<<<1, 64, 0, stream>>>(stats + 78, g2, be2, params);

  // ---- MLP head ----
  k3_gemm1<<<256, 256, 0, stream>>>(out2, lin1W, params, h1pre);
  k4_bn1<<<1, 256, 0, stream>>>(h1pre, bn1g, bn1b, h1);
  k5_gemm2<<<128, 256, 0, stream>>>(h1, lin2W, h2pre);
  k6_final<<<1, 256, 0, stream>>>(h2pre, bn2g, bn2b, lin3W, lin3b, (float*)d_out);
}

// Round 5
// 726.532 us; speedup vs baseline: 1.4848x; 1.0597x over previous
//
#include <hip/hip_runtime.h>
#include <cstdint>

#define SLOPE 0.33f

static constexpr int B_   = 64;
static constexpr int E1_  = 8978;
static constexpr int E2_  = 4489;
static constexpr int N1_  = B_ * E1_;      // 574592
static constexpr int N2_  = B_ * E2_;      // 287296
static constexpr int DEG_ = 16;
static constexpr int QTR_ = 2245;          // ceil(E1_/4)
static constexpr int QTR2_ = 1123;         // ceil(E2_/4)
static constexpr int MVGRID = (N2_ * 32) / 256;   // 35912 (exact)
static constexpr int MVH_GRID = (N2_ * 8) / 256;  // 8978 (exact)
static constexpr int PROJ_GRID = (N2_ + 511) / 512;  // 562
static constexpr double EPS_ = 1e-5;

__device__ __forceinline__ float lrelu(float v) { return v > 0.f ? v : SLOPE * v; }

// =====================================================================
// Layer 0: 1 channel. Per-graph x slab staged in LDS; edges of node g are
// [g*16, g*16+16) by construction (dst sorted). grid = 64 graphs * 4 quarters.
// =====================================================================
__global__ __launch_bounds__(256) void k0_mv1(const float* __restrict__ x,
    const int* __restrict__ src, const float* __restrict__ ew, float* __restrict__ T1) {
  __shared__ float sx[E1_];
  int g = blockIdx.x >> 2, q = blockIdx.x & 3;
  int gbase = g * E1_;
  for (int j = threadIdx.x; j < E1_; j += 256) sx[j] = x[gbase + j];
  __syncthreads();
  int start = q * QTR_, end = min(start + QTR_, E1_);
  for (int i = start + (int)threadIdx.x; i < end; i += 256) {
    int node = gbase + i;
    const int4* s4 = (const int4*)(src + (size_t)node * DEG_);
    const float4* w4 = (const float4*)(ew + (size_t)node * DEG_);
    float acc = 0.f;
#pragma unroll
    for (int j = 0; j < 4; ++j) {
      int4 s = s4[j]; float4 w = w4[j];
      acc += w.x * sx[s.x - gbase] + w.y * sx[s.y - gbase]
           + w.z * sx[s.z - gbase] + w.w * sx[s.w - gbase];
    }
    T1[node] = sx[i] - acc;   // T1 = x - L x
  }
}

__global__ __launch_bounds__(256) void k0_mv2(const float* __restrict__ x,
    const int* __restrict__ src, const float* __restrict__ ew,
    const float* __restrict__ T1, float* __restrict__ T2) {
  __shared__ float sT[E1_];
  int g = blockIdx.x >> 2, q = blockIdx.x & 3;
  int gbase = g * E1_;
  for (int j = threadIdx.x; j < E1_; j += 256) sT[j] = T1[gbase + j];
  __syncthreads();
  int start = q * QTR_, end = min(start + QTR_, E1_);
  for (int i = start + (int)threadIdx.x; i < end; i += 256) {
    int node = gbase + i;
    const int4* s4 = (const int4*)(src + (size_t)node * DEG_);
    const float4* w4 = (const float4*)(ew + (size_t)node * DEG_);
    float acc = 0.f;
#pragma unroll
    for (int j = 0; j < 4; ++j) {
      int4 s = s4[j]; float4 w = w4[j];
      acc += w.x * sT[s.x - gbase] + w.y * sT[s.y - gbase]
           + w.z * sT[s.z - gbase] + w.w * sT[s.w - gbase];
    }
    T2[node] = (3.f * sT[i] - acc - x[node]) * 0.5f;  // T2 = (3T1 - L T1 - T0)/2
  }
}

// T3 = (5T2 - L T2 - 2T1)/3, plus moment accumulation for layer-0 BN.
__global__ __launch_bounds__(256) void k0_mv3(const float* __restrict__ x,
    const int* __restrict__ src, const float* __restrict__ ew,
    const float* __restrict__ T1, const float* __restrict__ T2,
    float* __restrict__ T3, double* mom) {
  __shared__ float sT[E1_];
  __shared__ double sred[4 * 14];
  int g = blockIdx.x >> 2, q = blockIdx.x & 3;
  int gbase = g * E1_;
  for (int j = threadIdx.x; j < E1_; j += 256) sT[j] = T2[gbase + j];
  __syncthreads();
  double m[14];
#pragma unroll
  for (int j = 0; j < 14; ++j) m[j] = 0.0;
  int start = q * QTR_, end = min(start + QTR_, E1_);
  for (int i = start + (int)threadIdx.x; i < end; i += 256) {
    int node = gbase + i;
    const int4* s4 = (const int4*)(src + (size_t)node * DEG_);
    const float4* w4 = (const float4*)(ew + (size_t)node * DEG_);
    float acc = 0.f;
#pragma unroll
    for (int j = 0; j < 4; ++j) {
      int4 s = s4[j]; float4 w = w4[j];
      acc += w.x * sT[s.x - gbase] + w.y * sT[s.y - gbase]
           + w.z * sT[s.z - gbase] + w.w * sT[s.w - gbase];
    }
    float t1 = T1[node];
    float t2 = sT[i];
    float t3 = (5.f * t2 - acc - 2.f * t1) * (1.f / 3.f);
    T3[node] = t3;
    double d0 = x[node], d1 = t1, d2 = t2, d3 = t3;
    m[0] += d0; m[1] += d1; m[2] += d2; m[3] += d3;
    m[4] += d0 * d0; m[5] += d0 * d1; m[6] += d0 * d2; m[7] += d0 * d3;
    m[8] += d1 * d1; m[9] += d1 * d2; m[10] += d1 * d3;
    m[11] += d2 * d2; m[12] += d2 * d3; m[13] += d3 * d3;
  }
  int lane = threadIdx.x & 63, wid = threadIdx.x >> 6;
#pragma unroll
  for (int j = 0; j < 14; ++j) {
    double v = m[j];
    for (int o = 32; o; o >>= 1) v += __shfl_down(v, o);
    if (lane == 0) sred[wid * 14 + j] = v;
  }
  __syncthreads();
  if (threadIdx.x < 14) {
    double s = sred[threadIdx.x] + sred[14 + threadIdx.x] + sred[28 + threadIdx.x] + sred[42 + threadIdx.x];
    atomicAdd(&mom[threadIdx.x], s);
  }
}

// BN params for layer 0 (b0 cancels in BN exactly).
__global__ void k0_params(const double* __restrict__ mom, const float* __restrict__ W0,
    const float* __restrict__ g0, const float* __restrict__ be0,
    float* __restrict__ scale0, float* __restrict__ shiftE0) {
  int c = threadIdx.x;
  if (c >= 32) return;
  double inv = 1.0 / (double)N1_;
  double mm[4];
#pragma unroll
  for (int k = 0; k < 4; ++k) mm[k] = mom[k] * inv;
  double M[4][4];
  M[0][0] = mom[4] * inv;  M[0][1] = mom[5] * inv;  M[0][2] = mom[6] * inv;  M[0][3] = mom[7] * inv;
  M[1][1] = mom[8] * inv;  M[1][2] = mom[9] * inv;  M[1][3] = mom[10] * inv;
  M[2][2] = mom[11] * inv; M[2][3] = mom[12] * inv; M[3][3] = mom[13] * inv;
  M[1][0] = M[0][1]; M[2][0] = M[0][2]; M[3][0] = M[0][3];
  M[2][1] = M[1][2]; M[3][1] = M[1][3]; M[3][2] = M[2][3];
  double w[4];
#pragma unroll
  for (int k = 0; k < 4; ++k) w[k] = W0[k * 32 + c];
  double mean = 0.0;
#pragma unroll
  for (int k = 0; k < 4; ++k) mean += w[k] * mm[k];
  double e2 = 0.0;
#pragma unroll
  for (int k = 0; k < 4; ++k)
#pragma unroll
    for (int l = 0; l < 4; ++l) e2 += M[k][l] * w[k] * w[l];
  double var = e2 - mean * mean;
  double sc = (double)g0[c] / sqrt(var + EPS_);
  scale0[c] = (float)sc;
  shiftE0[c] = (float)((double)be0[c] - sc * mean);
}

// fused: project to 32ch + BN + LeakyReLU + Graclus pair-max pool -> x1 (N2,32)
__global__ __launch_bounds__(256) void k0_pool(const float* __restrict__ x,
    const float* __restrict__ T1, const float* __restrict__ T2, const float* __restrict__ T3,
    const float* __restrict__ W0, const float* __restrict__ scale0,
    const float* __restrict__ shiftE0, float* __restrict__ x1) {
  int gid = blockIdx.x * 256 + threadIdx.x;
  int grp = gid >> 5, c = gid & 31;
  if (grp >= N2_) return;
  int b = grp / E2_, j = grp - b * E2_;
  int ga = b * E1_ + 2 * j, gb = ga + 1;
  float w0 = W0[c], w1 = W0[32 + c], w2 = W0[64 + c], w3 = W0[96 + c];
  float da = x[ga] * w0 + T1[ga] * w1 + T2[ga] * w2 + T3[ga] * w3;
  float db = x[gb] * w0 + T1[gb] * w1 + T2[gb] * w2 + T3[gb] * w3;
  float sc = scale0[c], sh = shiftE0[c];
  float ya = lrelu(sc * da + sh), yb = lrelu(sc * db + sh);
  x1[grp * 32 + c] = fmaxf(ya, yb);
}

// =====================================================================
// Layer-1 Horner: out1 = P0 + L(P1 + L(P2 + L P3)), P_j = x1 @ Q_j where
// Q_j are fixed combos of W1[k] (Laguerre polynomial coefficients of L^j).
//
// k1_projall: single pass computing ALL FOUR P arrays.
// thread = 2 rows (x rows in VGPRs, coalesced-block float4 loads);
// Q (32x128 = 16KB) staged once per block in LDS, read as wave-uniform
// broadcast ds_read_b128 (1024 reads amortized over 8192 FMAs per lane).
// P0 written in-place over x1 (per-lane read-before-write; safe).
// =====================================================================
__global__ __launch_bounds__(256) void k1_projall(const float* X /* x1, aliases P0 */,
    const float* __restrict__ W1, float* __restrict__ P3, float* __restrict__ P2,
    float* __restrict__ P1, float* P0) {
  __shared__ float4 Wl[128 * 8];   // Wl[o*8+qq] = (Q[4qq..4qq+3][o]), o = j*32+c'
  // j order: 0->P3, 1->P2, 2->P1, 3->P0
  const float4 cfs[4] = { {0.f, 0.f, 0.f, -1.f / 6.f},
                          {0.f, 0.f, 0.5f, 1.5f},
                          {0.f, -1.f, -2.f, -3.f},
                          {1.f, 1.f, 1.f, 1.f} };
  for (int e = threadIdx.x; e < 1024; e += 256) {
    int o = e >> 3, qq = e & 7;
    int j = o >> 5, cp = o & 31;
    float4 cf = cfs[j];
    float4 w;
    {
      const float* wp = W1 + (4 * qq + 0) * 32 + cp;
      w.x = cf.x * wp[0] + cf.y * wp[1024] + cf.z * wp[2048] + cf.w * wp[3072];
    }
    {
      const float* wp = W1 + (4 * qq + 1) * 32 + cp;
      w.y = cf.x * wp[0] + cf.y * wp[1024] + cf.z * wp[2048] + cf.w * wp[3072];
    }
    {
      const float* wp = W1 + (4 * qq + 2) * 32 + cp;
      w.z = cf.x * wp[0] + cf.y * wp[1024] + cf.z * wp[2048] + cf.w * wp[3072];
    }
    {
      const float* wp = W1 + (4 * qq + 3) * 32 + cp;
      w.w = cf.x * wp[0] + cf.y * wp[1024] + cf.z * wp[2048] + cf.w * wp[3072];
    }
    Wl[e] = w;
  }
  __syncthreads();
  int rA = blockIdx.x * 512 + threadIdx.x;
  int rB = rA + 256;
  bool okA = rA < N2_, okB = rB < N2_;
  if (!okA) return;
  float4 xA[8], xB[8];
  {
    const float4* pa = (const float4*)(X + (size_t)rA * 32);
#pragma unroll
    for (int t = 0; t < 8; ++t) xA[t] = pa[t];
  }
  if (okB) {
    const float4* pb = (const float4*)(X + (size_t)rB * 32);
#pragma unroll
    for (int t = 0; t < 8; ++t) xB[t] = pb[t];
  } else {
#pragma unroll
    for (int t = 0; t < 8; ++t) xB[t] = {0.f, 0.f, 0.f, 0.f};
  }
  for (int oq = 0; oq < 32; ++oq) {
    float4 aA = {0.f, 0.f, 0.f, 0.f}, aB = {0.f, 0.f, 0.f, 0.f};
    const float4* wr = Wl + oq * 32;   // 4 outputs x 8 qq
#pragma unroll
    for (int qq = 0; qq < 8; ++qq) {
      float4 w0 = wr[0 * 8 + qq];
      float4 w1 = wr[1 * 8 + qq];
      float4 w2 = wr[2 * 8 + qq];
      float4 w3 = wr[3 * 8 + qq];
      float4 xa = xA[qq], xb = xB[qq];
      aA.x += xa.x * w0.x + xa.y * w0.y + xa.z * w0.z + xa.w * w0.w;
      aA.y += xa.x * w1.x + xa.y * w1.y + xa.z * w1.z + xa.w * w1.w;
      aA.z += xa.x * w2.x + xa.y * w2.y + xa.z * w2.z + xa.w * w2.w;
      aA.w += xa.x * w3.x + xa.y * w3.y + xa.z * w3.z + xa.w * w3.w;
      aB.x += xb.x * w0.x + xb.y * w0.y + xb.z * w0.z + xb.w * w0.w;
      aB.y += xb.x * w1.x + xb.y * w1.y + xb.z * w1.z + xb.w * w1.w;
      aB.z += xb.x * w2.x + xb.y * w2.y + xb.z * w2.z + xb.w * w2.w;
      aB.w += xb.x * w3.x + xb.y * w3.y + xb.z * w3.z + xb.w * w3.w;
    }
    float* dst = (oq < 8) ? P3 : (oq < 16) ? P2 : (oq < 24) ? P1 : P0;
    int o4 = (oq & 7) * 4;
    *(float4*)(dst + (size_t)rA * 32 + o4) = aA;
    if (okB) *(float4*)(dst + (size_t)rB * 32 + o4) = aB;
  }
}

// mv_h: O = S + L G  (32-channel). thread = (node, channel-quad):
// gathers are 8 rows x 128B = 1KB per instruction; edge data 8x redundant.
// S may alias O (each element read exactly once by its owning thread
// before that thread writes it) -> no __restrict__ on S/O.
__global__ __launch_bounds__(256) void mv_h(const float* S,
    const float* __restrict__ G, const int* __restrict__ src,
    const float* __restrict__ ew, float* O) {
  int gid = blockIdx.x * 256 + threadIdx.x;
  int node = gid >> 3, c4 = gid & 7;
  const int4* s4 = (const int4*)(src + (size_t)node * DEG_);
  const float4* w4 = (const float4*)(ew + (size_t)node * DEG_);
  const float4* G4 = (const float4*)G;
  float4 acc = {0.f, 0.f, 0.f, 0.f};
#pragma unroll
  for (int j = 0; j < 4; ++j) {
    int4 s = s4[j]; float4 w = w4[j];
    float4 a = G4[(size_t)s.x * 8 + c4];
    float4 b = G4[(size_t)s.y * 8 + c4];
    float4 cc = G4[(size_t)s.z * 8 + c4];
    float4 d = G4[(size_t)s.w * 8 + c4];
    acc.x += w.x * a.x + w.y * b.x + w.z * cc.x + w.w * d.x;
    acc.y += w.x * a.y + w.y * b.y + w.z * cc.y + w.w * d.y;
    acc.z += w.x * a.z + w.y * b.z + w.z * cc.z + w.w * d.z;
    acc.w += w.x * a.w + w.y * b.w + w.z * cc.w + w.w * d.w;
  }
  float4 sv = ((const float4*)S)[(size_t)node * 8 + c4];
  float4 o = { sv.x + acc.x, sv.y + acc.y, sv.z + acc.z, sv.w + acc.w };
  ((float4*)O)[(size_t)node * 8 + c4] = o;
}

// per-channel sum/sumsq of a (N2,32) array (for layer-1 BN)
__global__ __launch_bounds__(256) void k_stats32(const float* __restrict__ X,
    double* sum, double* sq) {
  __shared__ double s1[256], s2[256];
  const long total = (long)N2_ * 32;
  double a = 0.0, b = 0.0;
  for (long idx = (long)blockIdx.x * 256 + threadIdx.x; idx < total; idx += (long)gridDim.x * 256) {
    double v = X[idx]; a += v; b += v * v;
  }
  s1[threadIdx.x] = a; s2[threadIdx.x] = b;
  __syncthreads();
  int c = threadIdx.x;
  if (c < 32) {
    double sa = 0.0, sb = 0.0;
    for (int j = c; j < 256; j += 32) { sa += s1[j]; sb += s2[j]; }
    atomicAdd(&sum[c], sa); atomicAdd(&sq[c], sb);
  }
}

__global__ void k1_params(const double* __restrict__ sum, const double* __restrict__ sq,
    const float* __restrict__ g1, const float* __restrict__ be1,
    float* __restrict__ scale1, float* __restrict__ shiftE1) {
  int c = threadIdx.x;
  if (c >= 32) return;
  double mean = sum[c] / (double)N2_;
  double var = sq[c] / (double)N2_ - mean * mean;
  double sc = (double)g1[c] / sqrt(var + EPS_);
  scale1[c] = (float)sc;
  shiftE1[c] = (float)((double)be1[c] - sc * mean);
}

// =====================================================================
// Layer-2 Horner on 1-channel fields: u_j = f(out1) q_j (q_j from W2),
// out2 = u0 + L(u1 + L(u2 + L u3)).  b2 cancels in BN2.
// =====================================================================
__global__ __launch_bounds__(256) void k2_proj(const float* __restrict__ X,
    const float* __restrict__ W2, const float* __restrict__ scale1,
    const float* __restrict__ shiftE1,
    float* __restrict__ u0, float* __restrict__ u1,
    float* __restrict__ u2, float* __restrict__ u3) {
  __shared__ float qv[4][32];
  __shared__ float fsc[32], fsh[32];
  int tid = threadIdx.x;
  if (tid < 128) {
    int cp = tid & 31, j = tid >> 5;
    float w0 = W2[cp], w1 = W2[32 + cp], w2 = W2[64 + cp], w3 = W2[96 + cp];
    float q;
    if (j == 0)      q = w0 + w1 + w2 + w3;
    else if (j == 1) q = -w1 - 2.f * w2 - 3.f * w3;
    else if (j == 2) q = 0.5f * w2 + 1.5f * w3;
    else             q = -w3 * (1.f / 6.f);
    qv[j][cp] = q;
  }
  if (tid < 32) { fsc[tid] = scale1[tid]; fsh[tid] = shiftE1[tid]; }
  __syncthreads();
  int node = blockIdx.x * 256 + tid;
  if (node >= N2_) return;
  const float4* xr = (const float4*)(X + (size_t)node * 32);
  float a0 = 0.f, a1 = 0.f, a2 = 0.f, a3 = 0.f;
#pragma unroll
  for (int t = 0; t < 8; ++t) {
    float4 v = xr[t];
    float f0 = lrelu(fsc[4 * t] * v.x + fsh[4 * t]);
    float f1 = lrelu(fsc[4 * t + 1] * v.y + fsh[4 * t + 1]);
    float f2_ = lrelu(fsc[4 * t + 2] * v.z + fsh[4 * t + 2]);
    float f3 = lrelu(fsc[4 * t + 3] * v.w + fsh[4 * t + 3]);
    a0 += f0 * qv[0][4 * t] + f1 * qv[0][4 * t + 1] + f2_ * qv[0][4 * t + 2] + f3 * qv[0][4 * t + 3];
    a1 += f0 * qv[1][4 * t] + f1 * qv[1][4 * t + 1] + f2_ * qv[1][4 * t + 2] + f3 * qv[1][4 * t + 3];
    a2 += f0 * qv[2][4 * t] + f1 * qv[2][4 * t + 1] + f2_ * qv[2][4 * t + 2] + f3 * qv[2][4 * t + 3];
    a3 += f0 * qv[3][4 * t] + f1 * qv[3][4 * t + 1] + f2_ * qv[3][4 * t + 2] + f3 * qv[3][4 * t + 3];
  }
  u0[node] = a0; u1[node] = a1; u2[node] = a2; u3[node] = a3;
}

// k2_step: zo = u + L z (1-channel), per-graph z slab in LDS.
// grid = 64 graphs x 4 quarters. do_stats!=0: also global sum/sumsq of zo.
__global__ __launch_bounds__(256) void k2_step(const float* __restrict__ z,
    const int* __restrict__ src, const float* __restrict__ ew,
    const float* __restrict__ u, float* __restrict__ zo,
    int do_stats, double* st2) {
  __shared__ float sz[E2_];
  __shared__ double sred[4][2];
  int g = blockIdx.x >> 2, q = blockIdx.x & 3;
  int gbase = g * E2_;
  for (int j = threadIdx.x; j < E2_; j += 256) sz[j] = z[gbase + j];
  __syncthreads();
  int start = q * QTR2_, end = min(start + QTR2_, E2_);
  double aS = 0.0, aQ = 0.0;
  for (int i = start + (int)threadIdx.x; i < end; i += 256) {
    int node = gbase + i;
    const int4* s4 = (const int4*)(src + (size_t)node * DEG_);
    const float4* w4 = (const float4*)(ew + (size_t)node * DEG_);
    float acc = 0.f;
#pragma unroll
    for (int j = 0; j < 4; ++j) {
      int4 s = s4[j]; float4 w = w4[j];
      acc += w.x * sz[s.x - gbase] + w.y * sz[s.y - gbase]
           + w.z * sz[s.z - gbase] + w.w * sz[s.w - gbase];
    }
    float val = u[node] + acc;
    zo[node] = val;
    if (do_stats) { aS += val; aQ += (double)val * (double)val; }
  }
  if (do_stats) {
    int lane = threadIdx.x & 63, wid = threadIdx.x >> 6;
    for (int o = 32; o; o >>= 1) { aS += __shfl_down(aS, o); aQ += __shfl_down(aQ, o); }
    if (lane == 0) { sred[wid][0] = aS; sred[wid][1] = aQ; }
    __syncthreads();
    if (threadIdx.x == 0) {
      double s = sred[0][0] + sred[1][0] + sred[2][0] + sred[3][0];
      double qq = sred[0][1] + sred[1][1] + sred[2][1] + sred[3][1];
      atomicAdd(&st2[0], s); atomicAdd(&st2[1], qq);
    }
  }
}

__global__ void k2_params(const double* __restrict__ st2, const float* __restrict__ g2,
    const float* __restrict__ be2, float* __restrict__ p /* [128]=scale2 [129]=shiftE2 */) {
  if (threadIdx.x != 0) return;
  double mean = st2[0] / (double)N2_;
  double var = st2[1] / (double)N2_ - mean * mean;
  double sc = (double)g2[0] / sqrt(var + EPS_);
  p[128] = (float)sc;
  p[129] = (float)((double)be2[0] - sc * mean);
}

// MLP gemm1: h1pre[b,c] = sum_r f2(out2[b*E2+r]) * lin1_W[r,c]
__global__ __launch_bounds__(256) void k3_gemm1(const float* __restrict__ out2,
    const float* __restrict__ lin1W, const float* __restrict__ p, float* h1pre) {
  __shared__ float f2v[4][284];
  float sc = p[128], sh = p[129];
  int bs = blockIdx.x & 15, rs = blockIdx.x >> 4;
  int b0 = bs * 4;
  int r0 = rs * 281;
  int nr = min(281, E2_ - r0);
  int c = threadIdx.x;
#pragma unroll
  for (int b = 0; b < 4; ++b)
    for (int j = c; j < 284; j += 256)
      f2v[b][j] = (j < nr) ? lrelu(sc * out2[(b0 + b) * E2_ + r0 + j] + sh) : 0.f;
  __syncthreads();
  float acc0 = 0.f, acc1 = 0.f, acc2 = 0.f, acc3 = 0.f;
  int nr4 = nr & ~3;
  int j = 0;
  for (; j < nr4; j += 4) {
    const float* wp = lin1W + (size_t)(r0 + j) * 256 + c;
    float w0 = wp[0], w1 = wp[256], w2 = wp[512], w3 = wp[768];
    float4 f0 = *(const float4*)&f2v[0][j];
    float4 f1 = *(const float4*)&f2v[1][j];
    float4 f2_ = *(const float4*)&f2v[2][j];
    float4 f3 = *(const float4*)&f2v[3][j];
    acc0 += f0.x * w0 + f0.y * w1 + f0.z * w2 + f0.w * w3;
    acc1 += f1.x * w0 + f1.y * w1 + f1.z * w2 + f1.w * w3;
    acc2 += f2_.x * w0 + f2_.y * w1 + f2_.z * w2 + f2_.w * w3;
    acc3 += f3.x * w0 + f3.y * w1 + f3.z * w2 + f3.w * w3;
  }
  for (; j < nr; ++j) {
    float w = lin1W[(size_t)(r0 + j) * 256 + c];
    acc0 += f2v[0][j] * w;
    acc1 += f2v[1][j] * w;
    acc2 += f2v[2][j] * w;
    acc3 += f2v[3][j] * w;
  }
  atomicAdd(&h1pre[(b0 + 0) * 256 + c], acc0);
  atomicAdd(&h1pre[(b0 + 1) * 256 + c], acc1);
  atomicAdd(&h1pre[(b0 + 2) * 256 + c], acc2);
  atomicAdd(&h1pre[(b0 + 3) * 256 + c], acc3);
}

// BN1 + ReLU -> h1 (64,256)
__global__ __launch_bounds__(256) void k4_bn1(const float* __restrict__ h1pre,
    const float* __restrict__ g, const float* __restrict__ be, float* __restrict__ h1) {
  int c = threadIdx.x;
  float vs[64];
  double s = 0.0, q = 0.0;
  for (int b = 0; b < 64; ++b) { float v = h1pre[b * 256 + c]; vs[b] = v; s += v; q += (double)v * v; }
  double mean = s / 64.0, var = q / 64.0 - mean * mean;
  double scd = (double)g[c] / sqrt(var + EPS_);
  double shd = (double)be[c] - scd * mean;
  for (int b = 0; b < 64; ++b) {
    float y = (float)(scd * vs[b] + shd);
    h1[b * 256 + c] = y > 0.f ? y : 0.f;
  }
}

// gemm2: 128 blocks, block = output column
__global__ __launch_bounds__(256) void k5_gemm2(const float* __restrict__ h1,
    const float* __restrict__ lin2W, float* __restrict__ h2pre) {
  __shared__ float sred[256];
  int c = blockIdx.x;
  int b = threadIdx.x & 63, q = threadIdx.x >> 6;
  float acc = 0.f;
  for (int r = q; r < 256; r += 4) acc += h1[b * 256 + r] * lin2W[r * 128 + c];
  sred[threadIdx.x] = acc;
  __syncthreads();
  if (threadIdx.x < 64)
    h2pre[threadIdx.x * 128 + c] = sred[threadIdx.x] + sred[64 + threadIdx.x]
                                 + sred[128 + threadIdx.x] + sred[192 + threadIdx.x];
}

// BN2 + ReLU + final linear -> out[64]
__global__ __launch_bounds__(256) void k6_final(const float* __restrict__ h2pre,
    const float* __restrict__ g, const float* __restrict__ be,
    const float* __restrict__ W3, const float* __restrict__ b3, float* __restrict__ outp) {
  __shared__ float sh2[64 * 129];
  __shared__ float sred[256];
  int tid = threadIdx.x;
  if (tid < 128) {
    int c = tid;
    float vs[64];
    double s = 0.0, q = 0.0;
    for (int b = 0; b < 64; ++b) { float v = h2pre[b * 128 + c]; vs[b] = v; s += v; q += (double)v * v; }
    double mean = s / 64.0, var = q / 64.0 - mean * mean;
    double scd = (double)g[c] / sqrt(var + EPS_);
    double shd = (double)be[c] - scd * mean;
    for (int b = 0; b < 64; ++b) {
      float y = (float)(scd * vs[b] + shd);
      sh2[b * 129 + c] = y > 0.f ? y : 0.f;
    }
  }
  __syncthreads();
  int b = tid & 63, q = tid >> 6;
  float acc = 0.f;
  for (int r = q; r < 128; r += 4) acc += sh2[b * 129 + r] * W3[r];
  sred[tid] = acc;
  __syncthreads();
  if (tid < 64)
    outp[tid] = sred[tid] + sred[64 + tid] + sred[128 + tid] + sred[192 + tid] + b3[0];
}

// =====================================================================
extern "C" void kernel_launch(void* const* d_in, const int* in_sizes, int n_in,
                              void* d_out, int out_size, void* d_ws, size_t ws_size,
                              hipStream_t stream) {
  const float* x    = (const float*)d_in[0];
  const int*   ei1  = (const int*)d_in[1];
  const float* ew1  = (const float*)d_in[2];
  const int*   ei2  = (const int*)d_in[3];
  const float* ew2  = (const float*)d_in[4];
  const float* W0   = (const float*)d_in[5];
  const float* g0   = (const float*)d_in[7];
  const float* be0  = (const float*)d_in[8];
  const float* W1   = (const float*)d_in[9];
  const float* g1   = (const float*)d_in[11];
  const float* be1  = (const float*)d_in[12];
  const float* W2   = (const float*)d_in[13];
  const float* g2   = (const float*)d_in[15];
  const float* be2  = (const float*)d_in[16];
  const float* lin1W = (const float*)d_in[17];
  const float* bn1g = (const float*)d_in[19];
  const float* bn1b = (const float*)d_in[20];
  const float* lin2W = (const float*)d_in[21];
  const float* bn2g = (const float*)d_in[23];
  const float* bn2b = (const float*)d_in[24];
  const float* lin3W = (const float*)d_in[25];
  const float* lin3b = (const float*)d_in[26];

  char* ws = (char*)d_ws;
  double* stats  = (double*)ws;                 // [0..13] mom0, [14..45] s1sum, [46..77] s1sq, [78..79] st2
  float*  params = (float*)(ws + 1024);         // scale0[32] shiftE0[32] scale1[32] shiftE1[32] ... [128..129]
  float*  h1pre  = (float*)(ws + 4096);
  float*  h1     = (float*)(ws + 4096 + 65536);
  float*  h2pre  = (float*)(ws + 4096 + 131072);
  // Treg: 3*N1 floats. Layer-0 T arrays live here; later overlaid by u/z/out2
  float*  Treg   = (float*)(ws + 262144);
  float* T1_0 = Treg;
  float* T2_0 = Treg + N1_;
  float* T3_0 = Treg + 2 * (size_t)N1_;
  float* u0   = Treg;                           // overlays (T dead after k0_pool)
  float* u1   = Treg + (size_t)N2_;
  float* u2   = Treg + 2 * (size_t)N2_;
  float* u3   = Treg + 3 * (size_t)N2_;
  float* zA   = Treg + 4 * (size_t)N2_;
  float* out2 = Treg + 5 * (size_t)N2_;         // 6*N2 <= 3*N1  ✓
  float*  big = (float*)(ws + 262144 + 3 * (size_t)N1_ * 4);
  float* bufA = big;                            // x1 -> P0 -> out1
  float* bufB = bufA + 32 * (size_t)N2_;        // P3
  float* bufC = bufB + 32 * (size_t)N2_;        // P2 -> Z2
  float* bufD = bufC + 32 * (size_t)N2_;        // P1 -> Z1

  hipMemsetAsync(stats, 0, 80 * sizeof(double), stream);
  hipMemsetAsync(h1pre, 0, 65536, stream);

  // ---- layer 0 ----
  k0_mv1<<<256, 256, 0, stream>>>(x, ei1, ew1, T1_0);
  k0_mv2<<<256, 256, 0, stream>>>(x, ei1, ew1, T1_0, T2_0);
  k0_mv3<<<256, 256, 0, stream>>>(x, ei1, ew1, T1_0, T2_0, T3_0, stats);
  k0_params<<<1, 32, 0, stream>>>(stats, W0, g0, be0, params, params + 32);
  k0_pool<<<MVGRID, 256, 0, stream>>>(x, T1_0, T2_0, T3_0, W0, params, params + 32, bufA);

  // ---- layer 1 (Horner, single projection pass) ----
  k1_projall<<<PROJ_GRID, 256, 0, stream>>>(bufA, W1, bufB, bufC, bufD, bufA);
  mv_h<<<MVH_GRID, 256, 0, stream>>>(bufC, bufB, ei2, ew2, bufC);      // Z2 = P2 + L P3
  mv_h<<<MVH_GRID, 256, 0, stream>>>(bufD, bufC, ei2, ew2, bufD);      // Z1 = P1 + L Z2
  mv_h<<<MVH_GRID, 256, 0, stream>>>(bufA, bufD, ei2, ew2, bufA);      // out1 = P0 + L Z1
  k_stats32<<<2048, 256, 0, stream>>>(bufA, stats + 14, stats + 46);
  k1_params<<<1, 32, 0, stream>>>(stats + 14, stats + 46, g1, be1, params + 64, params + 96);

  // ---- layer 2 (Horner, 1-channel) ----
  k2_proj<<<(N2_ + 255) / 256, 256, 0, stream>>>(bufA, W2, params + 64, params + 96,
                                                 u0, u1, u2, u3);
  k2_step<<<256, 256, 0, stream>>>(u3, ei2, ew2, u2, zA, 0, nullptr);       // zA = u2 + L u3
  k2_step<<<256, 256, 0, stream>>>(zA, ei2, ew2, u1, u3, 0, nullptr);       // u3slot = u1 + L zA
  k2_step<<<256, 256, 0, stream>>>(u3, ei2, ew2, u0, out2, 1, stats + 78);  // out2 + stats
  k2_params<<<1, 64, 0, stream>>>(stats + 78, g2, be2, params);

  // ---- MLP head ----
  k3_gemm1<<<256, 256, 0, stream>>>(out2, lin1W, params, h1pre);
  k4_bn1<<<1, 256, 0, stream>>>(h1pre, bn1g, bn1b, h1);
  k5_gemm2<<<128, 256, 0, stream>>>(h1, lin2W, h2pre);
  k6_final<<<1, 256, 0, stream>>>(h2pre, bn2g, bn2b, lin3W, lin3b, (float*)d_out);
}

// Round 6
// 663.986 us; speedup vs baseline: 1.6246x; 1.0942x over previous
//
#include <hip/hip_runtime.h>
#include <cstdint>

#define SLOPE 0.33f

static constexpr int B_   = 64;
static constexpr int E1_  = 8978;
static constexpr int E2_  = 4489;
static constexpr int N1_  = B_ * E1_;      // 574592
static constexpr int N2_  = B_ * E2_;      // 287296
static constexpr int DEG_ = 16;
static constexpr int QTR_ = 2245;          // ceil(E1_/4)
static constexpr int QTR2_ = 1123;         // ceil(E2_/4)
static constexpr int MVGRID = (N2_ * 32) / 256;   // 35912 (exact)
static constexpr int HP_GRID = (N2_ / 2 * 8) / 256;  // 4489 (exact)
static constexpr double EPS_ = 1e-5;

__device__ __forceinline__ float lrelu(float v) { return v > 0.f ? v : SLOPE * v; }
__device__ __forceinline__ float dot4(float4 a, float4 b) {
  return a.x * b.x + a.y * b.y + a.z * b.z + a.w * b.w;
}

// =====================================================================
// Layer 0: 1 channel. Per-graph x slab staged in LDS; edges of node g are
// [g*16, g*16+16) by construction (dst sorted). grid = 64 graphs * 4 quarters.
// =====================================================================
__global__ __launch_bounds__(256) void k0_mv1(const float* __restrict__ x,
    const int* __restrict__ src, const float* __restrict__ ew, float* __restrict__ T1) {
  __shared__ float sx[E1_];
  int g = blockIdx.x >> 2, q = blockIdx.x & 3;
  int gbase = g * E1_;
  for (int j = threadIdx.x; j < E1_; j += 256) sx[j] = x[gbase + j];
  __syncthreads();
  int start = q * QTR_, end = min(start + QTR_, E1_);
  for (int i = start + (int)threadIdx.x; i < end; i += 256) {
    int node = gbase + i;
    const int4* s4 = (const int4*)(src + (size_t)node * DEG_);
    const float4* w4 = (const float4*)(ew + (size_t)node * DEG_);
    float acc = 0.f;
#pragma unroll
    for (int j = 0; j < 4; ++j) {
      int4 s = s4[j]; float4 w = w4[j];
      acc += w.x * sx[s.x - gbase] + w.y * sx[s.y - gbase]
           + w.z * sx[s.z - gbase] + w.w * sx[s.w - gbase];
    }
    T1[node] = sx[i] - acc;   // T1 = x - L x
  }
}

__global__ __launch_bounds__(256) void k0_mv2(const float* __restrict__ x,
    const int* __restrict__ src, const float* __restrict__ ew,
    const float* __restrict__ T1, float* __restrict__ T2) {
  __shared__ float sT[E1_];
  int g = blockIdx.x >> 2, q = blockIdx.x & 3;
  int gbase = g * E1_;
  for (int j = threadIdx.x; j < E1_; j += 256) sT[j] = T1[gbase + j];
  __syncthreads();
  int start = q * QTR_, end = min(start + QTR_, E1_);
  for (int i = start + (int)threadIdx.x; i < end; i += 256) {
    int node = gbase + i;
    const int4* s4 = (const int4*)(src + (size_t)node * DEG_);
    const float4* w4 = (const float4*)(ew + (size_t)node * DEG_);
    float acc = 0.f;
#pragma unroll
    for (int j = 0; j < 4; ++j) {
      int4 s = s4[j]; float4 w = w4[j];
      acc += w.x * sT[s.x - gbase] + w.y * sT[s.y - gbase]
           + w.z * sT[s.z - gbase] + w.w * sT[s.w - gbase];
    }
    T2[node] = (3.f * sT[i] - acc - x[node]) * 0.5f;  // T2 = (3T1 - L T1 - T0)/2
  }
}

// T3 = (5T2 - L T2 - 2T1)/3, plus moment accumulation for layer-0 BN.
__global__ __launch_bounds__(256) void k0_mv3(const float* __restrict__ x,
    const int* __restrict__ src, const float* __restrict__ ew,
    const float* __restrict__ T1, const float* __restrict__ T2,
    float* __restrict__ T3, double* mom) {
  __shared__ float sT[E1_];
  __shared__ double sred[4 * 14];
  int g = blockIdx.x >> 2, q = blockIdx.x & 3;
  int gbase = g * E1_;
  for (int j = threadIdx.x; j < E1_; j += 256) sT[j] = T2[gbase + j];
  __syncthreads();
  double m[14];
#pragma unroll
  for (int j = 0; j < 14; ++j) m[j] = 0.0;
  int start = q * QTR_, end = min(start + QTR_, E1_);
  for (int i = start + (int)threadIdx.x; i < end; i += 256) {
    int node = gbase + i;
    const int4* s4 = (const int4*)(src + (size_t)node * DEG_);
    const float4* w4 = (const float4*)(ew + (size_t)node * DEG_);
    float acc = 0.f;
#pragma unroll
    for (int j = 0; j < 4; ++j) {
      int4 s = s4[j]; float4 w = w4[j];
      acc += w.x * sT[s.x - gbase] + w.y * sT[s.y - gbase]
           + w.z * sT[s.z - gbase] + w.w * sT[s.w - gbase];
    }
    float t1 = T1[node];
    float t2 = sT[i];
    float t3 = (5.f * t2 - acc - 2.f * t1) * (1.f / 3.f);
    T3[node] = t3;
    double d0 = x[node], d1 = t1, d2 = t2, d3 = t3;
    m[0] += d0; m[1] += d1; m[2] += d2; m[3] += d3;
    m[4] += d0 * d0; m[5] += d0 * d1; m[6] += d0 * d2; m[7] += d0 * d3;
    m[8] += d1 * d1; m[9] += d1 * d2; m[10] += d1 * d3;
    m[11] += d2 * d2; m[12] += d2 * d3; m[13] += d3 * d3;
  }
  int lane = threadIdx.x & 63, wid = threadIdx.x >> 6;
#pragma unroll
  for (int j = 0; j < 14; ++j) {
    double v = m[j];
    for (int o = 32; o; o >>= 1) v += __shfl_down(v, o);
    if (lane == 0) sred[wid * 14 + j] = v;
  }
  __syncthreads();
  if (threadIdx.x < 14) {
    double s = sred[threadIdx.x] + sred[14 + threadIdx.x] + sred[28 + threadIdx.x] + sred[42 + threadIdx.x];
    atomicAdd(&mom[threadIdx.x], s);
  }
}

// BN params for layer 0 (b0 cancels in BN exactly).
__global__ void k0_params(const double* __restrict__ mom, const float* __restrict__ W0,
    const float* __restrict__ g0, const float* __restrict__ be0,
    float* __restrict__ scale0, float* __restrict__ shiftE0) {
  int c = threadIdx.x;
  if (c >= 32) return;
  double inv = 1.0 / (double)N1_;
  double mm[4];
#pragma unroll
  for (int k = 0; k < 4; ++k) mm[k] = mom[k] * inv;
  double M[4][4];
  M[0][0] = mom[4] * inv;  M[0][1] = mom[5] * inv;  M[0][2] = mom[6] * inv;  M[0][3] = mom[7] * inv;
  M[1][1] = mom[8] * inv;  M[1][2] = mom[9] * inv;  M[1][3] = mom[10] * inv;
  M[2][2] = mom[11] * inv; M[2][3] = mom[12] * inv; M[3][3] = mom[13] * inv;
  M[1][0] = M[0][1]; M[2][0] = M[0][2]; M[3][0] = M[0][3];
  M[2][1] = M[1][2]; M[3][1] = M[1][3]; M[3][2] = M[2][3];
  double w[4];
#pragma unroll
  for (int k = 0; k < 4; ++k) w[k] = W0[k * 32 + c];
  double mean = 0.0;
#pragma unroll
  for (int k = 0; k < 4; ++k) mean += w[k] * mm[k];
  double e2 = 0.0;
#pragma unroll
  for (int k = 0; k < 4; ++k)
#pragma unroll
    for (int l = 0; l < 4; ++l) e2 += M[k][l] * w[k] * w[l];
  double var = e2 - mean * mean;
  double sc = (double)g0[c] / sqrt(var + EPS_);
  scale0[c] = (float)sc;
  shiftE0[c] = (float)((double)be0[c] - sc * mean);
}

// fused: project to 32ch + BN + LeakyReLU + Graclus pair-max pool -> x1 (N2,32)
__global__ __launch_bounds__(256) void k0_pool(const float* __restrict__ x,
    const float* __restrict__ T1, const float* __restrict__ T2, const float* __restrict__ T3,
    const float* __restrict__ W0, const float* __restrict__ scale0,
    const float* __restrict__ shiftE0, float* __restrict__ x1) {
  int gid = blockIdx.x * 256 + threadIdx.x;
  int grp = gid >> 5, c = gid & 31;
  if (grp >= N2_) return;
  int b = grp / E2_, j = grp - b * E2_;
  int ga = b * E1_ + 2 * j, gb = ga + 1;
  float w0 = W0[c], w1 = W0[32 + c], w2 = W0[64 + c], w3 = W0[96 + c];
  float da = x[ga] * w0 + T1[ga] * w1 + T2[ga] * w2 + T3[ga] * w3;
  float db = x[gb] * w0 + T1[gb] * w1 + T2[gb] * w2 + T3[gb] * w3;
  float sc = scale0[c], sh = shiftE0[c];
  float ya = lrelu(sc * da + sh), yb = lrelu(sc * db + sh);
  x1[grp * 32 + c] = fmaxf(ya, yb);
}

// =====================================================================
// Layer-1 Horner with fused self-projection:
//   out1 = P0 + L(P1 + L(P2 + L P3)),  P_j = x1 @ Q_j,
//   Q_j = sum_K cf_j[K] * W1[K]  (Laguerre coeffs of L^j).
// Only P3 is ever materialized (it is gathered); P2/P1/P0 are self-row-only
// and computed on the fly inside each gather pass:
//   mv_hp: O[n] = x1[n] @ Q + (L G)[n]      (G == nullptr -> pure projection)
// thread = (node-pair, c4): Q (4.2KB, padded) in LDS, conflict-free phase
// reads; stores cover full 128B lines (no partial-line write inflation).
// =====================================================================
__global__ __launch_bounds__(256) void mv_hp(const float* __restrict__ X,
    const float* __restrict__ G, const int* __restrict__ src,
    const float* __restrict__ ew, const float* __restrict__ W1,
    float4 cf, float* __restrict__ O) {
  __shared__ float4 Q[8 * 33];   // [c4][t*4+k], row pad 33 -> phase conflict-free
  {
    int e = threadIdx.x;         // 256 entries, one per thread
    int c4 = e >> 5, r = e & 31;
    int t = r >> 2, k = r & 3;
    int out = c4 * 4 + k;
    const float* wp = W1 + (4 * t) * 32 + out;   // W1[K][inp][out]
    float4 w;
    w.x = cf.x * wp[0]  + cf.y * wp[1024]      + cf.z * wp[2048]      + cf.w * wp[3072];
    w.y = cf.x * wp[32] + cf.y * wp[1024 + 32] + cf.z * wp[2048 + 32] + cf.w * wp[3072 + 32];
    w.z = cf.x * wp[64] + cf.y * wp[1024 + 64] + cf.z * wp[2048 + 64] + cf.w * wp[3072 + 64];
    w.w = cf.x * wp[96] + cf.y * wp[1024 + 96] + cf.z * wp[2048 + 96] + cf.w * wp[3072 + 96];
    Q[c4 * 33 + r] = w;
  }
  __syncthreads();
  int pid = blockIdx.x * 256 + threadIdx.x;
  int c4 = pid & 7, npair = pid >> 3;
  int n0 = npair * 2, n1 = n0 + 1;
  const float4* p0 = (const float4*)(X + (size_t)n0 * 32);
  const float4* p1 = (const float4*)(X + (size_t)n1 * 32);
  float4 x0[8], x1r[8];
#pragma unroll
  for (int t = 0; t < 8; ++t) { x0[t] = p0[t]; x1r[t] = p1[t]; }
  float4 a0 = {0.f, 0.f, 0.f, 0.f}, a1 = {0.f, 0.f, 0.f, 0.f};
  const float4* Qc = Q + c4 * 33;
#pragma unroll
  for (int t = 0; t < 8; ++t) {
    float4 w0 = Qc[t * 4 + 0];
    float4 w1 = Qc[t * 4 + 1];
    float4 w2 = Qc[t * 4 + 2];
    float4 w3 = Qc[t * 4 + 3];
    float4 xv0 = x0[t], xv1 = x1r[t];
    a0.x += dot4(xv0, w0); a0.y += dot4(xv0, w1); a0.z += dot4(xv0, w2); a0.w += dot4(xv0, w3);
    a1.x += dot4(xv1, w0); a1.y += dot4(xv1, w1); a1.z += dot4(xv1, w2); a1.w += dot4(xv1, w3);
  }
  if (G != nullptr) {
    const float4* G4 = (const float4*)G;
    {
      const int4* s4 = (const int4*)(src + (size_t)n0 * DEG_);
      const float4* w4 = (const float4*)(ew + (size_t)n0 * DEG_);
#pragma unroll
      for (int j = 0; j < 4; ++j) {
        int4 s = s4[j]; float4 w = w4[j];
        float4 ga = G4[(size_t)s.x * 8 + c4];
        float4 gb = G4[(size_t)s.y * 8 + c4];
        float4 gc = G4[(size_t)s.z * 8 + c4];
        float4 gd = G4[(size_t)s.w * 8 + c4];
        a0.x += w.x * ga.x + w.y * gb.x + w.z * gc.x + w.w * gd.x;
        a0.y += w.x * ga.y + w.y * gb.y + w.z * gc.y + w.w * gd.y;
        a0.z += w.x * ga.z + w.y * gb.z + w.z * gc.z + w.w * gd.z;
        a0.w += w.x * ga.w + w.y * gb.w + w.z * gc.w + w.w * gd.w;
      }
    }
    {
      const int4* s4 = (const int4*)(src + (size_t)n1 * DEG_);
      const float4* w4 = (const float4*)(ew + (size_t)n1 * DEG_);
#pragma unroll
      for (int j = 0; j < 4; ++j) {
        int4 s = s4[j]; float4 w = w4[j];
        float4 ga = G4[(size_t)s.x * 8 + c4];
        float4 gb = G4[(size_t)s.y * 8 + c4];
        float4 gc = G4[(size_t)s.z * 8 + c4];
        float4 gd = G4[(size_t)s.w * 8 + c4];
        a1.x += w.x * ga.x + w.y * gb.x + w.z * gc.x + w.w * gd.x;
        a1.y += w.x * ga.y + w.y * gb.y + w.z * gc.y + w.w * gd.y;
        a1.z += w.x * ga.z + w.y * gb.z + w.z * gc.z + w.w * gd.z;
        a1.w += w.x * ga.w + w.y * gb.w + w.z * gc.w + w.w * gd.w;
      }
    }
  }
  *(float4*)(O + (size_t)n0 * 32 + c4 * 4) = a0;
  *(float4*)(O + (size_t)n1 * 32 + c4 * 4) = a1;
}

// per-channel sum/sumsq of a (N2,32) array (for layer-1 BN)
__global__ __launch_bounds__(256) void k_stats32(const float* __restrict__ X,
    double* sum, double* sq) {
  __shared__ double s1[256], s2[256];
  const long total = (long)N2_ * 32;
  double a = 0.0, b = 0.0;
  for (long idx = (long)blockIdx.x * 256 + threadIdx.x; idx < total; idx += (long)gridDim.x * 256) {
    double v = X[idx]; a += v; b += v * v;
  }
  s1[threadIdx.x] = a; s2[threadIdx.x] = b;
  __syncthreads();
  int c = threadIdx.x;
  if (c < 32) {
    double sa = 0.0, sb = 0.0;
    for (int j = c; j < 256; j += 32) { sa += s1[j]; sb += s2[j]; }
    atomicAdd(&sum[c], sa); atomicAdd(&sq[c], sb);
  }
}

__global__ void k1_params(const double* __restrict__ sum, const double* __restrict__ sq,
    const float* __restrict__ g1, const float* __restrict__ be1,
    float* __restrict__ scale1, float* __restrict__ shiftE1) {
  int c = threadIdx.x;
  if (c >= 32) return;
  double mean = sum[c] / (double)N2_;
  double var = sq[c] / (double)N2_ - mean * mean;
  double sc = (double)g1[c] / sqrt(var + EPS_);
  scale1[c] = (float)sc;
  shiftE1[c] = (float)((double)be1[c] - sc * mean);
}

// =====================================================================
// Layer-2 Horner on 1-channel fields: u_j = f(out1) q_j (q_j from W2),
// out2 = u0 + L(u1 + L(u2 + L u3)).  b2 cancels in BN2.
// =====================================================================
__global__ __launch_bounds__(256) void k2_proj(const float* __restrict__ X,
    const float* __restrict__ W2, const float* __restrict__ scale1,
    const float* __restrict__ shiftE1,
    float* __restrict__ u0, float* __restrict__ u1,
    float* __restrict__ u2, float* __restrict__ u3) {
  __shared__ float qv[4][32];
  __shared__ float fsc[32], fsh[32];
  int tid = threadIdx.x;
  if (tid < 128) {
    int cp = tid & 31, j = tid >> 5;
    float w0 = W2[cp], w1 = W2[32 + cp], w2 = W2[64 + cp], w3 = W2[96 + cp];
    float q;
    if (j == 0)      q = w0 + w1 + w2 + w3;
    else if (j == 1) q = -w1 - 2.f * w2 - 3.f * w3;
    else if (j == 2) q = 0.5f * w2 + 1.5f * w3;
    else             q = -w3 * (1.f / 6.f);
    qv[j][cp] = q;
  }
  if (tid < 32) { fsc[tid] = scale1[tid]; fsh[tid] = shiftE1[tid]; }
  __syncthreads();
  int node = blockIdx.x * 256 + tid;
  if (node >= N2_) return;
  const float4* xr = (const float4*)(X + (size_t)node * 32);
  float a0 = 0.f, a1 = 0.f, a2 = 0.f, a3 = 0.f;
#pragma unroll
  for (int t = 0; t < 8; ++t) {
    float4 v = xr[t];
    float f0 = lrelu(fsc[4 * t] * v.x + fsh[4 * t]);
    float f1 = lrelu(fsc[4 * t + 1] * v.y + fsh[4 * t + 1]);
    float f2_ = lrelu(fsc[4 * t + 2] * v.z + fsh[4 * t + 2]);
    float f3 = lrelu(fsc[4 * t + 3] * v.w + fsh[4 * t + 3]);
    a0 += f0 * qv[0][4 * t] + f1 * qv[0][4 * t + 1] + f2_ * qv[0][4 * t + 2] + f3 * qv[0][4 * t + 3];
    a1 += f0 * qv[1][4 * t] + f1 * qv[1][4 * t + 1] + f2_ * qv[1][4 * t + 2] + f3 * qv[1][4 * t + 3];
    a2 += f0 * qv[2][4 * t] + f1 * qv[2][4 * t + 1] + f2_ * qv[2][4 * t + 2] + f3 * qv[2][4 * t + 3];
    a3 += f0 * qv[3][4 * t] + f1 * qv[3][4 * t + 1] + f2_ * qv[3][4 * t + 2] + f3 * qv[3][4 * t + 3];
  }
  u0[node] = a0; u1[node] = a1; u2[node] = a2; u3[node] = a3;
}

// k2_step: zo = u + L z (1-channel), per-graph z slab in LDS.
// grid = 64 graphs x 4 quarters. do_stats!=0: also global sum/sumsq of zo.
__global__ __launch_bounds__(256) void k2_step(const float* __restrict__ z,
    const int* __restrict__ src, const float* __restrict__ ew,
    const float* __restrict__ u, float* __restrict__ zo,
    int do_stats, double* st2) {
  __shared__ float sz[E2_];
  __shared__ double sred[4][2];
  int g = blockIdx.x >> 2, q = blockIdx.x & 3;
  int gbase = g * E2_;
  for (int j = threadIdx.x; j < E2_; j += 256) sz[j] = z[gbase + j];
  __syncthreads();
  int start = q * QTR2_, end = min(start + QTR2_, E2_);
  double aS = 0.0, aQ = 0.0;
  for (int i = start + (int)threadIdx.x; i < end; i += 256) {
    int node = gbase + i;
    const int4* s4 = (const int4*)(src + (size_t)node * DEG_);
    const float4* w4 = (const float4*)(ew + (size_t)node * DEG_);
    float acc = 0.f;
#pragma unroll
    for (int j = 0; j < 4; ++j) {
      int4 s = s4[j]; float4 w = w4[j];
      acc += w.x * sz[s.x - gbase] + w.y * sz[s.y - gbase]
           + w.z * sz[s.z - gbase] + w.w * sz[s.w - gbase];
    }
    float val = u[node] + acc;
    zo[node] = val;
    if (do_stats) { aS += val; aQ += (double)val * (double)val; }
  }
  if (do_stats) {
    int lane = threadIdx.x & 63, wid = threadIdx.x >> 6;
    for (int o = 32; o; o >>= 1) { aS += __shfl_down(aS, o); aQ += __shfl_down(aQ, o); }
    if (lane == 0) { sred[wid][0] = aS; sred[wid][1] = aQ; }
    __syncthreads();
    if (threadIdx.x == 0) {
      double s = sred[0][0] + sred[1][0] + sred[2][0] + sred[3][0];
      double qq = sred[0][1] + sred[1][1] + sred[2][1] + sred[3][1];
      atomicAdd(&st2[0], s); atomicAdd(&st2[1], qq);
    }
  }
}

__global__ void k2_params(const double* __restrict__ st2, const float* __restrict__ g2,
    const float* __restrict__ be2, float* __restrict__ p /* [128]=scale2 [129]=shiftE2 */) {
  if (threadIdx.x != 0) return;
  double mean = st2[0] / (double)N2_;
  double var = st2[1] / (double)N2_ - mean * mean;
  double sc = (double)g2[0] / sqrt(var + EPS_);
  p[128] = (float)sc;
  p[129] = (float)((double)be2[0] - sc * mean);
}

// MLP gemm1: h1pre[b,c] = sum_r f2(out2[b*E2+r]) * lin1_W[r,c]
__global__ __launch_bounds__(256) void k3_gemm1(const float* __restrict__ out2,
    const float* __restrict__ lin1W, const float* __restrict__ p, float* h1pre) {
  __shared__ float f2v[4][284];
  float sc = p[128], sh = p[129];
  int bs = blockIdx.x & 15, rs = blockIdx.x >> 4;
  int b0 = bs * 4;
  int r0 = rs * 281;
  int nr = min(281, E2_ - r0);
  int c = threadIdx.x;
#pragma unroll
  for (int b = 0; b < 4; ++b)
    for (int j = c; j < 284; j += 256)
      f2v[b][j] = (j < nr) ? lrelu(sc * out2[(b0 + b) * E2_ + r0 + j] + sh) : 0.f;
  __syncthreads();
  float acc0 = 0.f, acc1 = 0.f, acc2 = 0.f, acc3 = 0.f;
  int nr4 = nr & ~3;
  int j = 0;
  for (; j < nr4; j += 4) {
    const float* wp = lin1W + (size_t)(r0 + j) * 256 + c;
    float w0 = wp[0], w1 = wp[256], w2 = wp[512], w3 = wp[768];
    float4 f0 = *(const float4*)&f2v[0][j];
    float4 f1 = *(const float4*)&f2v[1][j];
    float4 f2_ = *(const float4*)&f2v[2][j];
    float4 f3 = *(const float4*)&f2v[3][j];
    acc0 += f0.x * w0 + f0.y * w1 + f0.z * w2 + f0.w * w3;
    acc1 += f1.x * w0 + f1.y * w1 + f1.z * w2 + f1.w * w3;
    acc2 += f2_.x * w0 + f2_.y * w1 + f2_.z * w2 + f2_.w * w3;
    acc3 += f3.x * w0 + f3.y * w1 + f3.z * w2 + f3.w * w3;
  }
  for (; j < nr; ++j) {
    float w = lin1W[(size_t)(r0 + j) * 256 + c];
    acc0 += f2v[0][j] * w;
    acc1 += f2v[1][j] * w;
    acc2 += f2v[2][j] * w;
    acc3 += f2v[3][j] * w;
  }
  atomicAdd(&h1pre[(b0 + 0) * 256 + c], acc0);
  atomicAdd(&h1pre[(b0 + 1) * 256 + c], acc1);
  atomicAdd(&h1pre[(b0 + 2) * 256 + c], acc2);
  atomicAdd(&h1pre[(b0 + 3) * 256 + c], acc3);
}

// BN1 + ReLU -> h1 (64,256)
__global__ __launch_bounds__(256) void k4_bn1(const float* __restrict__ h1pre,
    const float* __restrict__ g, const float* __restrict__ be, float* __restrict__ h1) {
  int c = threadIdx.x;
  float vs[64];
  double s = 0.0, q = 0.0;
  for (int b = 0; b < 64; ++b) { float v = h1pre[b * 256 + c]; vs[b] = v; s += v; q += (double)v * v; }
  double mean = s / 64.0, var = q / 64.0 - mean * mean;
  double scd = (double)g[c] / sqrt(var + EPS_);
  double shd = (double)be[c] - scd * mean;
  for (int b = 0; b < 64; ++b) {
    float y = (float)(scd * vs[b] + shd);
    h1[b * 256 + c] = y > 0.f ? y : 0.f;
  }
}

// gemm2: 128 blocks, block = output column
__global__ __launch_bounds__(256) void k5_gemm2(const float* __restrict__ h1,
    const float* __restrict__ lin2W, float* __restrict__ h2pre) {
  __shared__ float sred[256];
  int c = blockIdx.x;
  int b = threadIdx.x & 63, q = threadIdx.x >> 6;
  float acc = 0.f;
  for (int r = q; r < 256; r += 4) acc += h1[b * 256 + r] * lin2W[r * 128 + c];
  sred[threadIdx.x] = acc;
  __syncthreads();
  if (threadIdx.x < 64)
    h2pre[threadIdx.x * 128 + c] = sred[threadIdx.x] + sred[64 + threadIdx.x]
                                 + sred[128 + threadIdx.x] + sred[192 + threadIdx.x];
}

// BN2 + ReLU + final linear -> out[64]
__global__ __launch_bounds__(256) void k6_final(const float* __restrict__ h2pre,
    const float* __restrict__ g, const float* __restrict__ be,
    const float* __restrict__ W3, const float* __restrict__ b3, float* __restrict__ outp) {
  __shared__ float sh2[64 * 129];
  __shared__ float sred[256];
  int tid = threadIdx.x;
  if (tid < 128) {
    int c = tid;
    float vs[64];
    double s = 0.0, q = 0.0;
    for (int b = 0; b < 64; ++b) { float v = h2pre[b * 128 + c]; vs[b] = v; s += v; q += (double)v * v; }
    double mean = s / 64.0, var = q / 64.0 - mean * mean;
    double scd = (double)g[c] / sqrt(var + EPS_);
    double shd = (double)be[c] - scd * mean;
    for (int b = 0; b < 64; ++b) {
      float y = (float)(scd * vs[b] + shd);
      sh2[b * 129 + c] = y > 0.f ? y : 0.f;
    }
  }
  __syncthreads();
  int b = tid & 63, q = tid >> 6;
  float acc = 0.f;
  for (int r = q; r < 128; r += 4) acc += sh2[b * 129 + r] * W3[r];
  sred[tid] = acc;
  __syncthreads();
  if (tid < 64)
    outp[tid] = sred[tid] + sred[64 + tid] + sred[128 + tid] + sred[192 + tid] + b3[0];
}

// =====================================================================
extern "C" void kernel_launch(void* const* d_in, const int* in_sizes, int n_in,
                              void* d_out, int out_size, void* d_ws, size_t ws_size,
                              hipStream_t stream) {
  const float* x    = (const float*)d_in[0];
  const int*   ei1  = (const int*)d_in[1];
  const float* ew1  = (const float*)d_in[2];
  const int*   ei2  = (const int*)d_in[3];
  const float* ew2  = (const float*)d_in[4];
  const float* W0   = (const float*)d_in[5];
  const float* g0   = (const float*)d_in[7];
  const float* be0  = (const float*)d_in[8];
  const float* W1   = (const float*)d_in[9];
  const float* g1   = (const float*)d_in[11];
  const float* be1  = (const float*)d_in[12];
  const float* W2   = (const float*)d_in[13];
  const float* g2   = (const float*)d_in[15];
  const float* be2  = (const float*)d_in[16];
  const float* lin1W = (const float*)d_in[17];
  const float* bn1g = (const float*)d_in[19];
  const float* bn1b = (const float*)d_in[20];
  const float* lin2W = (const float*)d_in[21];
  const float* bn2g = (const float*)d_in[23];
  const float* bn2b = (const float*)d_in[24];
  const float* lin3W = (const float*)d_in[25];
  const float* lin3b = (const float*)d_in[26];

  char* ws = (char*)d_ws;
  double* stats  = (double*)ws;                 // [0..13] mom0, [14..45] s1sum, [46..77] s1sq, [78..79] st2
  float*  params = (float*)(ws + 1024);         // scale0[32] shiftE0[32] scale1[32] shiftE1[32] ... [128..129]
  float*  h1pre  = (float*)(ws + 4096);
  float*  h1     = (float*)(ws + 4096 + 65536);
  float*  h2pre  = (float*)(ws + 4096 + 131072);
  // Treg: 3*N1 floats. Layer-0 T arrays live here; later overlaid by u/z/out2
  float*  Treg   = (float*)(ws + 262144);
  float* T1_0 = Treg;
  float* T2_0 = Treg + N1_;
  float* T3_0 = Treg + 2 * (size_t)N1_;
  float* u0   = Treg;                           // overlays (T dead after k0_pool)
  float* u1   = Treg + (size_t)N2_;
  float* u2   = Treg + 2 * (size_t)N2_;
  float* u3   = Treg + 3 * (size_t)N2_;
  float* zA   = Treg + 4 * (size_t)N2_;
  float* out2 = Treg + 5 * (size_t)N2_;         // 6*N2 <= 3*N1  ✓
  float*  big = (float*)(ws + 262144 + 3 * (size_t)N1_ * 4);
  float* bufA = big;                            // x1 (live through all of layer 1)
  float* bufB = bufA + 32 * (size_t)N2_;        // P3, later out1
  float* bufC = bufB + 32 * (size_t)N2_;        // Z2
  float* bufD = bufC + 32 * (size_t)N2_;        // Z1

  hipMemsetAsync(stats, 0, 80 * sizeof(double), stream);
  hipMemsetAsync(h1pre, 0, 65536, stream);

  // ---- layer 0 ----
  k0_mv1<<<256, 256, 0, stream>>>(x, ei1, ew1, T1_0);
  k0_mv2<<<256, 256, 0, stream>>>(x, ei1, ew1, T1_0, T2_0);
  k0_mv3<<<256, 256, 0, stream>>>(x, ei1, ew1, T1_0, T2_0, T3_0, stats);
  k0_params<<<1, 32, 0, stream>>>(stats, W0, g0, be0, params, params + 32);
  k0_pool<<<MVGRID, 256, 0, stream>>>(x, T1_0, T2_0, T3_0, W0, params, params + 32, bufA);

  // ---- layer 1 (Horner, fused self-projection; only P3 materialized) ----
  float4 cQ3 = {0.f, 0.f, 0.f, -1.f / 6.f};
  float4 cQ2 = {0.f, 0.f, 0.5f, 1.5f};
  float4 cQ1 = {0.f, -1.f, -2.f, -3.f};
  float4 cQ0 = {1.f, 1.f, 1.f, 1.f};
  mv_hp<<<HP_GRID, 256, 0, stream>>>(bufA, nullptr, ei2, ew2, W1, cQ3, bufB); // P3 = x1@Q3
  mv_hp<<<HP_GRID, 256, 0, stream>>>(bufA, bufB, ei2, ew2, W1, cQ2, bufC);    // Z2 = x1@Q2 + L P3
  mv_hp<<<HP_GRID, 256, 0, stream>>>(bufA, bufC, ei2, ew2, W1, cQ1, bufD);    // Z1 = x1@Q1 + L Z2
  mv_hp<<<HP_GRID, 256, 0, stream>>>(bufA, bufD, ei2, ew2, W1, cQ0, bufB);    // out1 = x1@Q0 + L Z1
  k_stats32<<<2048, 256, 0, stream>>>(bufB, stats + 14, stats + 46);
  k1_params<<<1, 32, 0, stream>>>(stats + 14, stats + 46, g1, be1, params + 64, params + 96);

  // ---- layer 2 (Horner, 1-channel) ----
  k2_proj<<<(N2_ + 255) / 256, 256, 0, stream>>>(bufB, W2, params + 64, params + 96,
                                                 u0, u1, u2, u3);
  k2_step<<<256, 256, 0, stream>>>(u3, ei2, ew2, u2, zA, 0, nullptr);       // zA = u2 + L u3
  k2_step<<<256, 256, 0, stream>>>(zA, ei2, ew2, u1, u3, 0, nullptr);       // u3slot = u1 + L zA
  k2_step<<<256, 256, 0, stream>>>(u3, ei2, ew2, u0, out2, 1, stats + 78);  // out2 + stats
  k2_params<<<1, 64, 0, stream>>>(stats + 78, g2, be2, params);

  // ---- MLP head ----
  k3_gemm1<<<256, 256, 0, stream>>>(out2, lin1W, params, h1pre);
  k4_bn1<<<1, 256, 0, stream>>>(h1pre, bn1g, bn1b, h1);
  k5_gemm2<<<128, 256, 0, stream>>>(h1, lin2W, h2pre);
  k6_final<<<1, 256, 0, stream>>>(h2pre, bn2g, bn2b, lin3W, lin3b, (float*)d_out);
}

// Round 7
// 621.401 us; speedup vs baseline: 1.7360x; 1.0685x over previous
//
#include <hip/hip_runtime.h>
#include <cstdint>

#define SLOPE 0.33f

static constexpr int B_   = 64;
static constexpr int E1_  = 8978;
static constexpr int E2_  = 4489;
static constexpr int N1_  = B_ * E1_;      // 574592
static constexpr int N2_  = B_ * E2_;      // 287296
static constexpr int DEG_ = 16;
static constexpr int QTR_ = 2245;          // ceil(E1_/4)
static constexpr int QTR2_ = 1123;         // ceil(E2_/4)
static constexpr int MVGRID = (N2_ * 32) / 256;   // 35912 (exact)
static constexpr int HP_BLOCKS = 4489;            // logical blocks (64 nodes each)
static constexpr int HP_PERXCD = 562;             // ceil(4489/8)
static constexpr int HP_GRID = HP_PERXCD * 8;     // 4496 launched (7 idle)
static constexpr double EPS_ = 1e-5;

__device__ __forceinline__ float lrelu(float v) { return v > 0.f ? v : SLOPE * v; }
__device__ __forceinline__ float dot4(float4 a, float4 b) {
  return a.x * b.x + a.y * b.y + a.z * b.z + a.w * b.w;
}

// =====================================================================
// Layer 0: 1 channel. Per-graph x slab staged in LDS; edges of node g are
// [g*16, g*16+16) by construction (dst sorted). grid = 64 graphs * 4 quarters.
// =====================================================================
__global__ __launch_bounds__(256) void k0_mv1(const float* __restrict__ x,
    const int* __restrict__ src, const float* __restrict__ ew, float* __restrict__ T1) {
  __shared__ float sx[E1_];
  int g = blockIdx.x >> 2, q = blockIdx.x & 3;
  int gbase = g * E1_;
  for (int j = threadIdx.x; j < E1_; j += 256) sx[j] = x[gbase + j];
  __syncthreads();
  int start = q * QTR_, end = min(start + QTR_, E1_);
  for (int i = start + (int)threadIdx.x; i < end; i += 256) {
    int node = gbase + i;
    const int4* s4 = (const int4*)(src + (size_t)node * DEG_);
    const float4* w4 = (const float4*)(ew + (size_t)node * DEG_);
    float acc = 0.f;
#pragma unroll
    for (int j = 0; j < 4; ++j) {
      int4 s = s4[j]; float4 w = w4[j];
      acc += w.x * sx[s.x - gbase] + w.y * sx[s.y - gbase]
           + w.z * sx[s.z - gbase] + w.w * sx[s.w - gbase];
    }
    T1[node] = sx[i] - acc;   // T1 = x - L x
  }
}

__global__ __launch_bounds__(256) void k0_mv2(const float* __restrict__ x,
    const int* __restrict__ src, const float* __restrict__ ew,
    const float* __restrict__ T1, float* __restrict__ T2) {
  __shared__ float sT[E1_];
  int g = blockIdx.x >> 2, q = blockIdx.x & 3;
  int gbase = g * E1_;
  for (int j = threadIdx.x; j < E1_; j += 256) sT[j] = T1[gbase + j];
  __syncthreads();
  int start = q * QTR_, end = min(start + QTR_, E1_);
  for (int i = start + (int)threadIdx.x; i < end; i += 256) {
    int node = gbase + i;
    const int4* s4 = (const int4*)(src + (size_t)node * DEG_);
    const float4* w4 = (const float4*)(ew + (size_t)node * DEG_);
    float acc = 0.f;
#pragma unroll
    for (int j = 0; j < 4; ++j) {
      int4 s = s4[j]; float4 w = w4[j];
      acc += w.x * sT[s.x - gbase] + w.y * sT[s.y - gbase]
           + w.z * sT[s.z - gbase] + w.w * sT[s.w - gbase];
    }
    T2[node] = (3.f * sT[i] - acc - x[node]) * 0.5f;  // T2 = (3T1 - L T1 - T0)/2
  }
}

// T3 = (5T2 - L T2 - 2T1)/3, plus moment accumulation for layer-0 BN.
__global__ __launch_bounds__(256) void k0_mv3(const float* __restrict__ x,
    const int* __restrict__ src, const float* __restrict__ ew,
    const float* __restrict__ T1, const float* __restrict__ T2,
    float* __restrict__ T3, double* mom) {
  __shared__ float sT[E1_];
  __shared__ double sred[4 * 14];
  int g = blockIdx.x >> 2, q = blockIdx.x & 3;
  int gbase = g * E1_;
  for (int j = threadIdx.x; j < E1_; j += 256) sT[j] = T2[gbase + j];
  __syncthreads();
  double m[14];
#pragma unroll
  for (int j = 0; j < 14; ++j) m[j] = 0.0;
  int start = q * QTR_, end = min(start + QTR_, E1_);
  for (int i = start + (int)threadIdx.x; i < end; i += 256) {
    int node = gbase + i;
    const int4* s4 = (const int4*)(src + (size_t)node * DEG_);
    const float4* w4 = (const float4*)(ew + (size_t)node * DEG_);
    float acc = 0.f;
#pragma unroll
    for (int j = 0; j < 4; ++j) {
      int4 s = s4[j]; float4 w = w4[j];
      acc += w.x * sT[s.x - gbase] + w.y * sT[s.y - gbase]
           + w.z * sT[s.z - gbase] + w.w * sT[s.w - gbase];
    }
    float t1 = T1[node];
    float t2 = sT[i];
    float t3 = (5.f * t2 - acc - 2.f * t1) * (1.f / 3.f);
    T3[node] = t3;
    double d0 = x[node], d1 = t1, d2 = t2, d3 = t3;
    m[0] += d0; m[1] += d1; m[2] += d2; m[3] += d3;
    m[4] += d0 * d0; m[5] += d0 * d1; m[6] += d0 * d2; m[7] += d0 * d3;
    m[8] += d1 * d1; m[9] += d1 * d2; m[10] += d1 * d3;
    m[11] += d2 * d2; m[12] += d2 * d3; m[13] += d3 * d3;
  }
  int lane = threadIdx.x & 63, wid = threadIdx.x >> 6;
#pragma unroll
  for (int j = 0; j < 14; ++j) {
    double v = m[j];
    for (int o = 32; o; o >>= 1) v += __shfl_down(v, o);
    if (lane == 0) sred[wid * 14 + j] = v;
  }
  __syncthreads();
  if (threadIdx.x < 14) {
    double s = sred[threadIdx.x] + sred[14 + threadIdx.x] + sred[28 + threadIdx.x] + sred[42 + threadIdx.x];
    atomicAdd(&mom[threadIdx.x], s);
  }
}

// BN params for layer 0 (b0 cancels in BN exactly).
__global__ void k0_params(const double* __restrict__ mom, const float* __restrict__ W0,
    const float* __restrict__ g0, const float* __restrict__ be0,
    float* __restrict__ scale0, float* __restrict__ shiftE0) {
  int c = threadIdx.x;
  if (c >= 32) return;
  double inv = 1.0 / (double)N1_;
  double mm[4];
#pragma unroll
  for (int k = 0; k < 4; ++k) mm[k] = mom[k] * inv;
  double M[4][4];
  M[0][0] = mom[4] * inv;  M[0][1] = mom[5] * inv;  M[0][2] = mom[6] * inv;  M[0][3] = mom[7] * inv;
  M[1][1] = mom[8] * inv;  M[1][2] = mom[9] * inv;  M[1][3] = mom[10] * inv;
  M[2][2] = mom[11] * inv; M[2][3] = mom[12] * inv; M[3][3] = mom[13] * inv;
  M[1][0] = M[0][1]; M[2][0] = M[0][2]; M[3][0] = M[0][3];
  M[2][1] = M[1][2]; M[3][1] = M[1][3]; M[3][2] = M[2][3];
  double w[4];
#pragma unroll
  for (int k = 0; k < 4; ++k) w[k] = W0[k * 32 + c];
  double mean = 0.0;
#pragma unroll
  for (int k = 0; k < 4; ++k) mean += w[k] * mm[k];
  double e2 = 0.0;
#pragma unroll
  for (int k = 0; k < 4; ++k)
#pragma unroll
    for (int l = 0; l < 4; ++l) e2 += M[k][l] * w[k] * w[l];
  double var = e2 - mean * mean;
  double sc = (double)g0[c] / sqrt(var + EPS_);
  scale0[c] = (float)sc;
  shiftE0[c] = (float)((double)be0[c] - sc * mean);
}

// fused: project to 32ch + BN + LeakyReLU + Graclus pair-max pool -> x1 (N2,32)
__global__ __launch_bounds__(256) void k0_pool(const float* __restrict__ x,
    const float* __restrict__ T1, const float* __restrict__ T2, const float* __restrict__ T3,
    const float* __restrict__ W0, const float* __restrict__ scale0,
    const float* __restrict__ shiftE0, float* __restrict__ x1) {
  int gid = blockIdx.x * 256 + threadIdx.x;
  int grp = gid >> 5, c = gid & 31;
  if (grp >= N2_) return;
  int b = grp / E2_, j = grp - b * E2_;
  int ga = b * E1_ + 2 * j, gb = ga + 1;
  float w0 = W0[c], w1 = W0[32 + c], w2 = W0[64 + c], w3 = W0[96 + c];
  float da = x[ga] * w0 + T1[ga] * w1 + T2[ga] * w2 + T3[ga] * w3;
  float db = x[gb] * w0 + T1[gb] * w1 + T2[gb] * w2 + T3[gb] * w3;
  float sc = scale0[c], sh = shiftE0[c];
  float ya = lrelu(sc * da + sh), yb = lrelu(sc * db + sh);
  x1[grp * 32 + c] = fmaxf(ya, yb);
}

// =====================================================================
// Layer-1 Horner with fused self-projection:
//   out1 = P0 + L(P1 + L(P2 + L P3)),  P_j = x1 @ Q_j.
// mv_hp: O[n] = x1[n] @ Q + (L G)[n]   (G == nullptr -> pure projection)
// XCD-aware swizzle: blocks with blockIdx%8==k dispatch to XCD k (round-
// robin heuristic); v = (b&7)*562 + (b>>3) gives XCD k the CONTIGUOUS
// logical-block range [562k, 562k+562) = ~8 whole graphs, so each graph's
// gather slab (574 KB) stays resident in ONE XCD's L2 instead of being
// re-fetched by all 8.
// =====================================================================
__global__ __launch_bounds__(256) void mv_hp(const float* __restrict__ X,
    const float* __restrict__ G, const int* __restrict__ src,
    const float* __restrict__ ew, const float* __restrict__ W1,
    float4 cf, float* __restrict__ O) {
  __shared__ float4 Q[8 * 33];   // [c4][t*4+k], row pad 33 -> phase conflict-free
  {
    int e = threadIdx.x;         // 256 entries, one per thread
    int c4 = e >> 5, r = e & 31;
    int t = r >> 2, k = r & 3;
    int out = c4 * 4 + k;
    const float* wp = W1 + (4 * t) * 32 + out;   // W1[K][inp][out]
    float4 w;
    w.x = cf.x * wp[0]  + cf.y * wp[1024]      + cf.z * wp[2048]      + cf.w * wp[3072];
    w.y = cf.x * wp[32] + cf.y * wp[1024 + 32] + cf.z * wp[2048 + 32] + cf.w * wp[3072 + 32];
    w.z = cf.x * wp[64] + cf.y * wp[1024 + 64] + cf.z * wp[2048 + 64] + cf.w * wp[3072 + 64];
    w.w = cf.x * wp[96] + cf.y * wp[1024 + 96] + cf.z * wp[2048 + 96] + cf.w * wp[3072 + 96];
    Q[c4 * 33 + r] = w;
  }
  __syncthreads();
  int v = (blockIdx.x & 7) * HP_PERXCD + (blockIdx.x >> 3);
  if (v >= HP_BLOCKS) return;
  int pid = v * 256 + threadIdx.x;
  int c4 = pid & 7, npair = pid >> 3;
  int n0 = npair * 2, n1 = n0 + 1;
  const float4* p0 = (const float4*)(X + (size_t)n0 * 32);
  const float4* p1 = (const float4*)(X + (size_t)n1 * 32);
  float4 x0[8], x1r[8];
#pragma unroll
  for (int t = 0; t < 8; ++t) { x0[t] = p0[t]; x1r[t] = p1[t]; }
  float4 a0 = {0.f, 0.f, 0.f, 0.f}, a1 = {0.f, 0.f, 0.f, 0.f};
  const float4* Qc = Q + c4 * 33;
#pragma unroll
  for (int t = 0; t < 8; ++t) {
    float4 w0 = Qc[t * 4 + 0];
    float4 w1 = Qc[t * 4 + 1];
    float4 w2 = Qc[t * 4 + 2];
    float4 w3 = Qc[t * 4 + 3];
    float4 xv0 = x0[t], xv1 = x1r[t];
    a0.x += dot4(xv0, w0); a0.y += dot4(xv0, w1); a0.z += dot4(xv0, w2); a0.w += dot4(xv0, w3);
    a1.x += dot4(xv1, w0); a1.y += dot4(xv1, w1); a1.z += dot4(xv1, w2); a1.w += dot4(xv1, w3);
  }
  if (G != nullptr) {
    const float4* G4 = (const float4*)G;
    {
      const int4* s4 = (const int4*)(src + (size_t)n0 * DEG_);
      const float4* w4 = (const float4*)(ew + (size_t)n0 * DEG_);
#pragma unroll
      for (int j = 0; j < 4; ++j) {
        int4 s = s4[j]; float4 w = w4[j];
        float4 ga = G4[(size_t)s.x * 8 + c4];
        float4 gb = G4[(size_t)s.y * 8 + c4];
        float4 gc = G4[(size_t)s.z * 8 + c4];
        float4 gd = G4[(size_t)s.w * 8 + c4];
        a0.x += w.x * ga.x + w.y * gb.x + w.z * gc.x + w.w * gd.x;
        a0.y += w.x * ga.y + w.y * gb.y + w.z * gc.y + w.w * gd.y;
        a0.z += w.x * ga.z + w.y * gb.z + w.z * gc.z + w.w * gd.z;
        a0.w += w.x * ga.w + w.y * gb.w + w.z * gc.w + w.w * gd.w;
      }
    }
    {
      const int4* s4 = (const int4*)(src + (size_t)n1 * DEG_);
      const float4* w4 = (const float4*)(ew + (size_t)n1 * DEG_);
#pragma unroll
      for (int j = 0; j < 4; ++j) {
        int4 s = s4[j]; float4 w = w4[j];
        float4 ga = G4[(size_t)s.x * 8 + c4];
        float4 gb = G4[(size_t)s.y * 8 + c4];
        float4 gc = G4[(size_t)s.z * 8 + c4];
        float4 gd = G4[(size_t)s.w * 8 + c4];
        a1.x += w.x * ga.x + w.y * gb.x + w.z * gc.x + w.w * gd.x;
        a1.y += w.x * ga.y + w.y * gb.y + w.z * gc.y + w.w * gd.y;
        a1.z += w.x * ga.z + w.y * gb.z + w.z * gc.z + w.w * gd.z;
        a1.w += w.x * ga.w + w.y * gb.w + w.z * gc.w + w.w * gd.w;
      }
    }
  }
  *(float4*)(O + (size_t)n0 * 32 + c4 * 4) = a0;
  *(float4*)(O + (size_t)n1 * 32 + c4 * 4) = a1;
}

// per-channel sum/sumsq of a (N2,32) array (for layer-1 BN)
__global__ __launch_bounds__(256) void k_stats32(const float* __restrict__ X,
    double* sum, double* sq) {
  __shared__ double s1[256], s2[256];
  const long total = (long)N2_ * 32;
  double a = 0.0, b = 0.0;
  for (long idx = (long)blockIdx.x * 256 + threadIdx.x; idx < total; idx += (long)gridDim.x * 256) {
    double v = X[idx]; a += v; b += v * v;
  }
  s1[threadIdx.x] = a; s2[threadIdx.x] = b;
  __syncthreads();
  int c = threadIdx.x;
  if (c < 32) {
    double sa = 0.0, sb = 0.0;
    for (int j = c; j < 256; j += 32) { sa += s1[j]; sb += s2[j]; }
    atomicAdd(&sum[c], sa); atomicAdd(&sq[c], sb);
  }
}

__global__ void k1_params(const double* __restrict__ sum, const double* __restrict__ sq,
    const float* __restrict__ g1, const float* __restrict__ be1,
    float* __restrict__ scale1, float* __restrict__ shiftE1) {
  int c = threadIdx.x;
  if (c >= 32) return;
  double mean = sum[c] / (double)N2_;
  double var = sq[c] / (double)N2_ - mean * mean;
  double sc = (double)g1[c] / sqrt(var + EPS_);
  scale1[c] = (float)sc;
  shiftE1[c] = (float)((double)be1[c] - sc * mean);
}

// =====================================================================
// Layer-2 Horner on 1-channel fields: u_j = f(out1) q_j (q_j from W2),
// out2 = u0 + L(u1 + L(u2 + L u3)).  b2 cancels in BN2.
// =====================================================================
__global__ __launch_bounds__(256) void k2_proj(const float* __restrict__ X,
    const float* __restrict__ W2, const float* __restrict__ scale1,
    const float* __restrict__ shiftE1,
    float* __restrict__ u0, float* __restrict__ u1,
    float* __restrict__ u2, float* __restrict__ u3) {
  __shared__ float qv[4][32];
  __shared__ float fsc[32], fsh[32];
  int tid = threadIdx.x;
  if (tid < 128) {
    int cp = tid & 31, j = tid >> 5;
    float w0 = W2[cp], w1 = W2[32 + cp], w2 = W2[64 + cp], w3 = W2[96 + cp];
    float q;
    if (j == 0)      q = w0 + w1 + w2 + w3;
    else if (j == 1) q = -w1 - 2.f * w2 - 3.f * w3;
    else if (j == 2) q = 0.5f * w2 + 1.5f * w3;
    else             q = -w3 * (1.f / 6.f);
    qv[j][cp] = q;
  }
  if (tid < 32) { fsc[tid] = scale1[tid]; fsh[tid] = shiftE1[tid]; }
  __syncthreads();
  int node = blockIdx.x * 256 + tid;
  if (node >= N2_) return;
  const float4* xr = (const float4*)(X + (size_t)node * 32);
  float a0 = 0.f, a1 = 0.f, a2 = 0.f, a3 = 0.f;
#pragma unroll
  for (int t = 0; t < 8; ++t) {
    float4 v = xr[t];
    float f0 = lrelu(fsc[4 * t] * v.x + fsh[4 * t]);
    float f1 = lrelu(fsc[4 * t + 1] * v.y + fsh[4 * t + 1]);
    float f2_ = lrelu(fsc[4 * t + 2] * v.z + fsh[4 * t + 2]);
    float f3 = lrelu(fsc[4 * t + 3] * v.w + fsh[4 * t + 3]);
    a0 += f0 * qv[0][4 * t] + f1 * qv[0][4 * t + 1] + f2_ * qv[0][4 * t + 2] + f3 * qv[0][4 * t + 3];
    a1 += f0 * qv[1][4 * t] + f1 * qv[1][4 * t + 1] + f2_ * qv[1][4 * t + 2] + f3 * qv[1][4 * t + 3];
    a2 += f0 * qv[2][4 * t] + f1 * qv[2][4 * t + 1] + f2_ * qv[2][4 * t + 2] + f3 * qv[2][4 * t + 3];
    a3 += f0 * qv[3][4 * t] + f1 * qv[3][4 * t + 1] + f2_ * qv[3][4 * t + 2] + f3 * qv[3][4 * t + 3];
  }
  u0[node] = a0; u1[node] = a1; u2[node] = a2; u3[node] = a3;
}

// k2_step: zo = u + L z (1-channel), per-graph z slab in LDS.
// grid = 64 graphs x 4 quarters. do_stats!=0: also global sum/sumsq of zo.
__global__ __launch_bounds__(256) void k2_step(const float* __restrict__ z,
    const int* __restrict__ src, const float* __restrict__ ew,
    const float* __restrict__ u, float* __restrict__ zo,
    int do_stats, double* st2) {
  __shared__ float sz[E2_];
  __shared__ double sred[4][2];
  int g = blockIdx.x >> 2, q = blockIdx.x & 3;
  int gbase = g * E2_;
  for (int j = threadIdx.x; j < E2_; j += 256) sz[j] = z[gbase + j];
  __syncthreads();
  int start = q * QTR2_, end = min(start + QTR2_, E2_);
  double aS = 0.0, aQ = 0.0;
  for (int i = start + (int)threadIdx.x; i < end; i += 256) {
    int node = gbase + i;
    const int4* s4 = (const int4*)(src + (size_t)node * DEG_);
    const float4* w4 = (const float4*)(ew + (size_t)node * DEG_);
    float acc = 0.f;
#pragma unroll
    for (int j = 0; j < 4; ++j) {
      int4 s = s4[j]; float4 w = w4[j];
      acc += w.x * sz[s.x - gbase] + w.y * sz[s.y - gbase]
           + w.z * sz[s.z - gbase] + w.w * sz[s.w - gbase];
    }
    float val = u[node] + acc;
    zo[node] = val;
    if (do_stats) { aS += val; aQ += (double)val * (double)val; }
  }
  if (do_stats) {
    int lane = threadIdx.x & 63, wid = threadIdx.x >> 6;
    for (int o = 32; o; o >>= 1) { aS += __shfl_down(aS, o); aQ += __shfl_down(aQ, o); }
    if (lane == 0) { sred[wid][0] = aS; sred[wid][1] = aQ; }
    __syncthreads();
    if (threadIdx.x == 0) {
      double s = sred[0][0] + sred[1][0] + sred[2][0] + sred[3][0];
      double qq = sred[0][1] + sred[1][1] + sred[2][1] + sred[3][1];
      atomicAdd(&st2[0], s); atomicAdd(&st2[1], qq);
    }
  }
}

__global__ void k2_params(const double* __restrict__ st2, const float* __restrict__ g2,
    const float* __restrict__ be2, float* __restrict__ p /* [128]=scale2 [129]=shiftE2 */) {
  if (threadIdx.x != 0) return;
  double mean = st2[0] / (double)N2_;
  double var = st2[1] / (double)N2_ - mean * mean;
  double sc = (double)g2[0] / sqrt(var + EPS_);
  p[128] = (float)sc;
  p[129] = (float)((double)be2[0] - sc * mean);
}

// MLP gemm1: h1pre[b,c] = sum_r f2(out2[b*E2+r]) * lin1_W[r,c]
__global__ __launch_bounds__(256) void k3_gemm1(const float* __restrict__ out2,
    const float* __restrict__ lin1W, const float* __restrict__ p, float* h1pre) {
  __shared__ float f2v[4][284];
  float sc = p[128], sh = p[129];
  int bs = blockIdx.x & 15, rs = blockIdx.x >> 4;
  int b0 = bs * 4;
  int r0 = rs * 281;
  int nr = min(281, E2_ - r0);
  int c = threadIdx.x;
#pragma unroll
  for (int b = 0; b < 4; ++b)
    for (int j = c; j < 284; j += 256)
      f2v[b][j] = (j < nr) ? lrelu(sc * out2[(b0 + b) * E2_ + r0 + j] + sh) : 0.f;
  __syncthreads();
  float acc0 = 0.f, acc1 = 0.f, acc2 = 0.f, acc3 = 0.f;
  int nr4 = nr & ~3;
  int j = 0;
  for (; j < nr4; j += 4) {
    const float* wp = lin1W + (size_t)(r0 + j) * 256 + c;
    float w0 = wp[0], w1 = wp[256], w2 = wp[512], w3 = wp[768];
    float4 f0 = *(const float4*)&f2v[0][j];
    float4 f1 = *(const float4*)&f2v[1][j];
    float4 f2_ = *(const float4*)&f2v[2][j];
    float4 f3 = *(const float4*)&f2v[3][j];
    acc0 += f0.x * w0 + f0.y * w1 + f0.z * w2 + f0.w * w3;
    acc1 += f1.x * w0 + f1.y * w1 + f1.z * w2 + f1.w * w3;
    acc2 += f2_.x * w0 + f2_.y * w1 + f2_.z * w2 + f2_.w * w3;
    acc3 += f3.x * w0 + f3.y * w1 + f3.z * w2 + f3.w * w3;
  }
  for (; j < nr; ++j) {
    float w = lin1W[(size_t)(r0 + j) * 256 + c];
    acc0 += f2v[0][j] * w;
    acc1 += f2v[1][j] * w;
    acc2 += f2v[2][j] * w;
    acc3 += f2v[3][j] * w;
  }
  atomicAdd(&h1pre[(b0 + 0) * 256 + c], acc0);
  atomicAdd(&h1pre[(b0 + 1) * 256 + c], acc1);
  atomicAdd(&h1pre[(b0 + 2) * 256 + c], acc2);
  atomicAdd(&h1pre[(b0 + 3) * 256 + c], acc3);
}

// BN1 + ReLU -> h1 (64,256)
__global__ __launch_bounds__(256) void k4_bn1(const float* __restrict__ h1pre,
    const float* __restrict__ g, const float* __restrict__ be, float* __restrict__ h1) {
  int c = threadIdx.x;
  float vs[64];
  double s = 0.0, q = 0.0;
  for (int b = 0; b < 64; ++b) { float v = h1pre[b * 256 + c]; vs[b] = v; s += v; q += (double)v * v; }
  double mean = s / 64.0, var = q / 64.0 - mean * mean;
  double scd = (double)g[c] / sqrt(var + EPS_);
  double shd = (double)be[c] - scd * mean;
  for (int b = 0; b < 64; ++b) {
    float y = (float)(scd * vs[b] + shd);
    h1[b * 256 + c] = y > 0.f ? y : 0.f;
  }
}

// gemm2: 128 blocks, block = output column
__global__ __launch_bounds__(256) void k5_gemm2(const float* __restrict__ h1,
    const float* __restrict__ lin2W, float* __restrict__ h2pre) {
  __shared__ float sred[256];
  int c = blockIdx.x;
  int b = threadIdx.x & 63, q = threadIdx.x >> 6;
  float acc = 0.f;
  for (int r = q; r < 256; r += 4) acc += h1[b * 256 + r] * lin2W[r * 128 + c];
  sred[threadIdx.x] = acc;
  __syncthreads();
  if (threadIdx.x < 64)
    h2pre[threadIdx.x * 128 + c] = sred[threadIdx.x] + sred[64 + threadIdx.x]
                                 + sred[128 + threadIdx.x] + sred[192 + threadIdx.x];
}

// BN2 + ReLU + final linear -> out[64]
__global__ __launch_bounds__(256) void k6_final(const float* __restrict__ h2pre,
    const float* __restrict__ g, const float* __restrict__ be,
    const float* __restrict__ W3, const float* __restrict__ b3, float* __restrict__ outp) {
  __shared__ float sh2[64 * 129];
  __shared__ float sred[256];
  int tid = threadIdx.x;
  if (tid < 128) {
    int c = tid;
    float vs[64];
    double s = 0.0, q = 0.0;
    for (int b = 0; b < 64; ++b) { float v = h2pre[b * 128 + c]; vs[b] = v; s += v; q += (double)v * v; }
    double mean = s / 64.0, var = q / 64.0 - mean * mean;
    double scd = (double)g[c] / sqrt(var + EPS_);
    double shd = (double)be[c] - scd * mean;
    for (int b = 0; b < 64; ++b) {
      float y = (float)(scd * vs[b] + shd);
      sh2[b * 129 + c] = y > 0.f ? y : 0.f;
    }
  }
  __syncthreads();
  int b = tid & 63, q = tid >> 6;
  float acc = 0.f;
  for (int r = q; r < 128; r += 4) acc += sh2[b * 129 + r] * W3[r];
  sred[tid] = acc;
  __syncthreads();
  if (tid < 64)
    outp[tid] = sred[tid] + sred[64 + tid] + sred[128 + tid] + sred[192 + tid] + b3[0];
}

// =====================================================================
extern "C" void kernel_launch(void* const* d_in, const int* in_sizes, int n_in,
                              void* d_out, int out_size, void* d_ws, size_t ws_size,
                              hipStream_t stream) {
  const float* x    = (const float*)d_in[0];
  const int*   ei1  = (const int*)d_in[1];
  const float* ew1  = (const float*)d_in[2];
  const int*   ei2  = (const int*)d_in[3];
  const float* ew2  = (const float*)d_in[4];
  const float* W0   = (const float*)d_in[5];
  const float* g0   = (const float*)d_in[7];
  const float* be0  = (const float*)d_in[8];
  const float* W1   = (const float*)d_in[9];
  const float* g1   = (const float*)d_in[11];
  const float* be1  = (const float*)d_in[12];
  const float* W2   = (const float*)d_in[13];
  const float* g2   = (const float*)d_in[15];
  const float* be2  = (const float*)d_in[16];
  const float* lin1W = (const float*)d_in[17];
  const float* bn1g = (const float*)d_in[19];
  const float* bn1b = (const float*)d_in[20];
  const float* lin2W = (const float*)d_in[21];
  const float* bn2g = (const float*)d_in[23];
  const float* bn2b = (const float*)d_in[24];
  const float* lin3W = (const float*)d_in[25];
  const float* lin3b = (const float*)d_in[26];

  char* ws = (char*)d_ws;
  double* stats  = (double*)ws;                 // [0..13] mom0, [14..45] s1sum, [46..77] s1sq, [78..79] st2
  float*  params = (float*)(ws + 1024);         // scale0[32] shiftE0[32] scale1[32] shiftE1[32] ... [128..129]
  float*  h1pre  = (float*)(ws + 4096);
  float*  h1     = (float*)(ws + 4096 + 65536);
  float*  h2pre  = (float*)(ws + 4096 + 131072);
  // Treg: 3*N1 floats. Layer-0 T arrays live here; later overlaid by u/z/out2
  float*  Treg   = (float*)(ws + 262144);
  float* T1_0 = Treg;
  float* T2_0 = Treg + N1_;
  float* T3_0 = Treg + 2 * (size_t)N1_;
  float* u0   = Treg;                           // overlays (T dead after k0_pool)
  float* u1   = Treg + (size_t)N2_;
  float* u2   = Treg + 2 * (size_t)N2_;
  float* u3   = Treg + 3 * (size_t)N2_;
  float* zA   = Treg + 4 * (size_t)N2_;
  float* out2 = Treg + 5 * (size_t)N2_;         // 6*N2 <= 3*N1  ✓
  float*  big = (float*)(ws + 262144 + 3 * (size_t)N1_ * 4);
  float* bufA = big;                            // x1 (live through all of layer 1)
  float* bufB = bufA + 32 * (size_t)N2_;        // P3, later out1
  float* bufC = bufB + 32 * (size_t)N2_;        // Z2
  float* bufD = bufC + 32 * (size_t)N2_;        // Z1

  hipMemsetAsync(stats, 0, 80 * sizeof(double), stream);
  hipMemsetAsync(h1pre, 0, 65536, stream);

  // ---- layer 0 ----
  k0_mv1<<<256, 256, 0, stream>>>(x, ei1, ew1, T1_0);
  k0_mv2<<<256, 256, 0, stream>>>(x, ei1, ew1, T1_0, T2_0);
  k0_mv3<<<256, 256, 0, stream>>>(x, ei1, ew1, T1_0, T2_0, T3_0, stats);
  k0_params<<<1, 32, 0, stream>>>(stats, W0, g0, be0, params, params + 32);
  k0_pool<<<MVGRID, 256, 0, stream>>>(x, T1_0, T2_0, T3_0, W0, params, params + 32, bufA);

  // ---- layer 1 (Horner, fused self-projection; only P3 materialized) ----
  float4 cQ3 = {0.f, 0.f, 0.f, -1.f / 6.f};
  float4 cQ2 = {0.f, 0.f, 0.5f, 1.5f};
  float4 cQ1 = {0.f, -1.f, -2.f, -3.f};
  float4 cQ0 = {1.f, 1.f, 1.f, 1.f};
  mv_hp<<<HP_GRID, 256, 0, stream>>>(bufA, nullptr, ei2, ew2, W1, cQ3, bufB); // P3 = x1@Q3
  mv_hp<<<HP_GRID, 256, 0, stream>>>(bufA, bufB, ei2, ew2, W1, cQ2, bufC);    // Z2 = x1@Q2 + L P3
  mv_hp<<<HP_GRID, 256, 0, stream>>>(bufA, bufC, ei2, ew2, W1, cQ1, bufD);    // Z1 = x1@Q1 + L Z2
  mv_hp<<<HP_GRID, 256, 0, stream>>>(bufA, bufD, ei2, ew2, W1, cQ0, bufB);    // out1 = x1@Q0 + L Z1
  k_stats32<<<2048, 256, 0, stream>>>(bufB, stats + 14, stats + 46);
  k1_params<<<1, 32, 0, stream>>>(stats + 14, stats + 46, g1, be1, params + 64, params + 96);

  // ---- layer 2 (Horner, 1-channel) ----
  k2_proj<<<(N2_ + 255) / 256, 256, 0, stream>>>(bufB, W2, params + 64, params + 96,
                                                 u0, u1, u2, u3);
  k2_step<<<256, 256, 0, stream>>>(u3, ei2, ew2, u2, zA, 0, nullptr);       // zA = u2 + L u3
  k2_step<<<256, 256, 0, stream>>>(zA, ei2, ew2, u1, u3, 0, nullptr);       // u3slot = u1 + L zA
  k2_step<<<256, 256, 0, stream>>>(u3, ei2, ew2, u0, out2, 1, stats + 78);  // out2 + stats
  k2_params<<<1, 64, 0, stream>>>(stats + 78, g2, be2, params);

  // ---- MLP head ----
  k3_gemm1<<<256, 256, 0, stream>>>(out2, lin1W, params, h1pre);
  k4_bn1<<<1, 256, 0, stream>>>(h1pre, bn1g, bn1b, h1);
  k5_gemm2<<<128, 256, 0, stream>>>(h1, lin2W, h2pre);
  k6_final<<<1, 256, 0, stream>>>(h2pre, bn2g, bn2b, lin3W, lin3b, (float*)d_out);
}